// Round 1
// 1182.484 us; speedup vs baseline: 1.0037x; 1.0037x over previous
//
#include <hip/hip_runtime.h>
#include <hip/hip_bf16.h>

using bf16 = __hip_bfloat16;

#define N_HOSTN 20000
#define N_FLOWN 200000
#define E_HFN   400000
#define E_RELN  800000
#define GG      64
#define HH      128
#define FIN     97
#define NCN     10

// CSR region block counts (256 threads/block)
#define NB_REL_E 3125   // 800000/256
#define NB_HF_E  1563   // ceil(400000/256)
#define NB_REL_N 782    // ceil(200000/256)
#define NB_F2H_N 79     // ceil(20000/256)
// class-partitioned placement: 2048-edge chunks x 8 classes
#define NCH_REL 391     // ceil(800000/2048)
#define NCH_HF  196     // ceil(400000/2048)
#define PLC_REL (NCH_REL*8)            // 3128
#define PLC_H2F (PLC_REL + NCH_HF*8)   // 4696
#define PLC_ALL (PLC_H2F + NCH_HF*8)   // 6264

static inline int cdiv(long long a, long long b){ return (int)((a + b - 1) / b); }

__device__ __forceinline__ float bf2f(unsigned short u){
    return __uint_as_float(((unsigned)u) << 16);
}
__device__ __forceinline__ unsigned short f2bf(float f){
    unsigned u = __float_as_uint(f);
    unsigned r = u + 0x7FFFu + ((u >> 16) & 1u);   // RNE
    return (unsigned short)(r >> 16);
}
__device__ __forceinline__ float loadf(const void* p, size_t i, int isbf){
    return isbf ? bf2f(((const unsigned short*)p)[i]) : ((const float*)p)[i];
}

// ---------------- dtype detection ----------------
__global__ void k_detect(const unsigned short* x, int* flag){
    __shared__ int bad;
    if (threadIdx.x == 0) bad = 0;
    __syncthreads();
    int b = 0;
    for (int i = threadIdx.x; i < 4096; i += 256) {
        unsigned e = (x[i] >> 7) & 0xFFu;
        if (e >= 0x90u) b++;
    }
    if (b) atomicAdd(&bad, b);
    __syncthreads();
    if (threadIdx.x == 0) *flag = (bad == 0) ? 1 : 0;   // 1 = bf16, 0 = f32
}

// ---------------- misc ----------------
__global__ void k_zero(float* p, size_t n){
    size_t i = (size_t)blockIdx.x * 256 + threadIdx.x;
    if (i < n) p[i] = 0.f;
}
__global__ void k_flag_us(unsigned short* out, int n, unsigned short val){
    int i = blockIdx.x * 256 + threadIdx.x;
    if (i < n) out[i] = val;
}
__global__ void k_gather_embed(const int* ids, const void* emb, float* out, const int* flagp){
    int i = blockIdx.x * 256 + threadIdx.x;
    if (i >= N_HOSTN * HH) return;
    int isbf = *flagp;
    int node = i >> 7, f = i & 127;
    out[i] = loadf(emb, (size_t)ids[node] * HH + f, isbf);
}
// flow_x [N,97] (flag dtype) -> bf16 padded [N,128]
__global__ void k_pad_cast(const void* x, unsigned short* o, const int* flagp){
    size_t i = (size_t)blockIdx.x * 256 + threadIdx.x;
    if (i >= (size_t)N_FLOWN * 128) return;
    int isbf = *flagp;
    int row = (int)(i >> 7), c = (int)i & 127;
    o[i] = (c < FIN) ? f2bf(loadf(x, (size_t)row * FIN + c, isbf)) : (unsigned short)0;
}

// ---------------- one-shot weight prep (833 blocks, region dispatch) ----------------
__global__ __launch_bounds__(256) void k_wprep_all(
    const void* Wr0_h2f, const void* br0_h2f, const void* Wo0_h2f,
    const void* Wr0_f2h, const void* br0_f2h, const void* Wo0_f2h,
    const void* Wr0_rel, const void* br0_rel, const void* Wo0_rel,
    const void* Wr_all, const void* br_all, const void* Wo_all,
    unsigned short* WBT0, unsigned short* WBT1, unsigned short* WBT2,
    float* w_h2f0, float* w_h2f1, float* w_h2f2,
    float* w_f2h0, float* w_f2h1, float* w_of2h0, float* w_of2h1,
    float* b_comb0, float* b_comb1, float* b_comb2, float* b_f2h0, float* b_f2h1,
    const int* flagp)
{
    const int bb = blockIdx.x, t = threadIdx.x;
    const int isbf = *flagp;
    if (bb < 384) {
        int layer = bb >> 7;
        int i = ((bb & 127) << 8) + t;   // 0..32767
        int nn = i >> 7, k = i & 127;
        float v = 0.f;
        if (layer == 0) {
            if (k < FIN) {
                if (nn < 128) v = loadf(Wo0_h2f, (size_t)k*128+nn, isbf) + loadf(Wo0_rel, (size_t)k*128+nn, isbf);
                else          v = loadf(Wr0_rel, (size_t)k*128+(nn-128), isbf);
            }
        } else {
            size_t oW = (size_t)((layer - 1) * 3) * 16384;
            if (nn < 128) v = loadf(Wo_all, oW + (size_t)k*128+nn, isbf)
                            + loadf(Wo_all, oW + 2*16384 + (size_t)k*128+nn, isbf);
            else          v = loadf(Wr_all, oW + 2*16384 + (size_t)k*128+(nn-128), isbf);
        }
        unsigned short* W = (layer == 0) ? WBT0 : ((layer == 1) ? WBT1 : WBT2);
        W[(size_t)nn*128 + k] = f2bf(v);
    } else if (bb < 576) {
        int r = bb - 384; int layer = r >> 6; int i = ((r & 63) << 8) + t;
        float v;
        if (layer == 0) v = loadf(Wr0_h2f, (size_t)i, isbf);
        else            v = loadf(Wr_all, (size_t)((layer-1)*3)*16384 + i, isbf);
        ((layer == 0) ? w_h2f0 : ((layer == 1) ? w_h2f1 : w_h2f2))[i] = v;
    } else if (bb < 640) {
        // w_f2h0 padded to [128][128]: rows k>=97 zero
        int i = ((bb - 576) << 8) + t;
        int k = i >> 7;
        w_f2h0[i] = (k < FIN) ? loadf(Wr0_f2h, (size_t)i, isbf) : 0.f;
    } else if (bb < 704) {
        int i = ((bb - 640) << 8) + t;
        w_f2h1[i] = loadf(Wr_all, (size_t)1*16384 + i, isbf);
    } else if (bb < 768) {
        int i = ((bb - 704) << 8) + t;
        w_of2h0[i] = loadf(Wo0_f2h, (size_t)i, isbf);
    } else if (bb < 832) {
        int i = ((bb - 768) << 8) + t;
        w_of2h1[i] = loadf(Wo_all, (size_t)1*16384 + i, isbf);
    } else {
        if (t < 128) {
            b_comb0[t] = loadf(br0_h2f, t, isbf) + loadf(br0_rel, t, isbf);
            b_comb1[t] = loadf(br_all, 0*128 + t, isbf) + loadf(br_all, 2*128 + t, isbf);
            b_comb2[t] = loadf(br_all, 3*128 + t, isbf) + loadf(br_all, 5*128 + t, isbf);
            b_f2h0[t]  = loadf(br0_f2h, t, isbf);
            b_f2h1[t]  = loadf(br_all, 1*128 + t, isbf);
        }
    }
}

// ---------------- CSR build (3-region batched) ----------------
__global__ void k_zero3(int* c0, int* c1, int* c2){
    int bb = blockIdx.x, t = threadIdx.x;
    int* c; int n; int base;
    if (bb < NB_REL_N)              { c = c0; n = N_FLOWN; base = bb; }
    else if (bb < 2*NB_REL_N)       { c = c1; n = N_FLOWN; base = bb - NB_REL_N; }
    else                            { c = c2; n = N_HOSTN; base = bb - 2*NB_REL_N; }
    int i = base * 256 + t;
    if (i < n) c[i] = 0;
}
__global__ void k_hist3(const int* d0, const int* d1, const int* d2,
                        int* c0, int* c1, int* c2){
    int bb = blockIdx.x, t = threadIdx.x;
    const int* dst; int* cnt; int E; int base;
    if (bb < NB_REL_E)                   { dst = d0; cnt = c0; E = E_RELN; base = bb; }
    else if (bb < NB_REL_E + NB_HF_E)    { dst = d1; cnt = c1; E = E_HFN;  base = bb - NB_REL_E; }
    else                                 { dst = d2; cnt = c2; E = E_HFN;  base = bb - NB_REL_E - NB_HF_E; }
    int e = base * 256 + t;
    if (e < E) atomicAdd(&cnt[dst[e]], 1);
}
__global__ __launch_bounds__(256) void k_scan1_3(
    const int* c0, int* rp0, int* bs0,
    const int* c1, int* rp1, int* bs1,
    const int* c2, int* rp2, int* bs2)
{
    __shared__ int s[256];
    int bb = blockIdx.x, t = threadIdx.x;
    const int* cnt; int* rp; int* bsum; int n; int base;
    if (bb < NB_REL_N)            { cnt = c0; rp = rp0; bsum = bs0; n = N_FLOWN; base = bb; }
    else if (bb < 2*NB_REL_N)     { cnt = c1; rp = rp1; bsum = bs1; n = N_FLOWN; base = bb - NB_REL_N; }
    else                          { cnt = c2; rp = rp2; bsum = bs2; n = N_HOSTN; base = bb - 2*NB_REL_N; }
    int i = base * 256 + t;
    int v = (i < n) ? cnt[i] : 0;
    s[t] = v; __syncthreads();
    for (int off = 1; off < 256; off <<= 1) {
        int x = (t >= off) ? s[t - off] : 0;
        __syncthreads();
        s[t] += x;
        __syncthreads();
    }
    if (i < n) rp[i] = s[t] - v;
    if (t == 255) bsum[base] = s[255];
}
__global__ __launch_bounds__(256) void k_scan2_3(int* bs0, int* bs1, int* bs2){
    __shared__ int s[256];
    __shared__ int carry;
    int t = threadIdx.x;
    int* bsum; int nb;
    if (blockIdx.x == 0)      { bsum = bs0; nb = NB_REL_N; }
    else if (blockIdx.x == 1) { bsum = bs1; nb = NB_REL_N; }
    else                      { bsum = bs2; nb = NB_F2H_N; }
    if (t == 0) carry = 0;
    __syncthreads();
    for (int base = 0; base < nb; base += 256) {
        int i = base + t;
        int v = (i < nb) ? bsum[i] : 0;
        s[t] = v; __syncthreads();
        for (int off = 1; off < 256; off <<= 1) {
            int x = (t >= off) ? s[t - off] : 0;
            __syncthreads();
            s[t] += x;
            __syncthreads();
        }
        int excl = s[t] - v + carry;
        if (i < nb) bsum[i] = excl;
        __syncthreads();
        if (t == 255) carry += s[255];
        __syncthreads();
    }
}
__global__ void k_scan3_3(int* rp0, const int* bs0, int* w0,
                          int* rp1, const int* bs1, int* w1,
                          int* rp2, const int* bs2, int* w2)
{
    int bb = blockIdx.x, t = threadIdx.x;
    int* rp; const int* bsum; int* wr; int n, E, base;
    if (bb < NB_REL_N)        { rp = rp0; bsum = bs0; wr = w0; n = N_FLOWN; E = E_RELN; base = bb; }
    else if (bb < 2*NB_REL_N) { rp = rp1; bsum = bs1; wr = w1; n = N_FLOWN; E = E_HFN;  base = bb - NB_REL_N; }
    else                      { rp = rp2; bsum = bs2; wr = w2; n = N_HOSTN; E = E_HFN;  base = bb - 2*NB_REL_N; }
    int i = base * 256 + t;
    if (i < n) { int v = rp[i] + bsum[base]; rp[i] = v; wr[i] = v; }
    if (i == 0) rp[n] = E;
}
// class-partitioned placement: class = blockIdx%8 (round-robins onto XCDs);
// each ei/wr line belongs to one dst class -> single-XCD writes (heuristic).
__global__ __launch_bounds__(256) void k_place3c(
    const int* s0, const int* d0, int* w0, int* e0,
    const int* s1, const int* d1, int* w1, int* e1,
    const int* s2, const int* d2, int* w2, int* e2)
{
    const int bb = blockIdx.x;
    const int *src, *dst; int *wr, *ei; int E, divc, rb;
    if (bb < PLC_REL)      { src=s0; dst=d0; wr=w0; ei=e0; E=E_RELN; divc=25000; rb=bb; }
    else if (bb < PLC_H2F) { src=s1; dst=d1; wr=w1; ei=e1; E=E_HFN;  divc=25000; rb=bb-PLC_REL; }
    else                   { src=s2; dst=d2; wr=w2; ei=e2; E=E_HFN;  divc=2500;  rb=bb-PLC_H2F; }
    const int cls  = rb & 7;
    const int base = (rb >> 3) * 2048;
    const int t = threadIdx.x;
    #pragma unroll
    for (int i = 0; i < 8; ++i) {
        const int e = base + t + i * 256;
        if (e < E) {
            const int d = dst[e];
            if (d / divc == cls) {
                const int pos = atomicAdd(&wr[d], 1);
                ei[pos] = src[e];
            }
        }
    }
}

// ---------------- host-sized VALU GEMM: Y[M,128] (+)= X[M,K]@W[K,128]+b ---------
__global__ __launch_bounds__(256) void k_gemm128(
    const void* X, int xmode, const float* W, const float* bias,
    void* Y, int ybf, int M, int K, int accum, int dorelu, const int* flagp)
{
    const int isbf = (xmode == 2) ? *flagp : xmode;
    const int tid  = threadIdx.x;
    const int row0 = blockIdx.x * 16;
    __shared__ float sX[16][130];
    const int total = 16 * K;
    for (int i = tid; i < total; i += 256) {
        int r = i / K, c = i - r * K;
        int gr = row0 + r;
        sX[r][c] = (gr < M) ? loadf(X, (size_t)gr * K + c, isbf) : 0.f;
    }
    __syncthreads();

    const int c4 = (tid & 31) * 4;
    const int rb = tid >> 5;
    float a0x=0,a0y=0,a0z=0,a0w=0, a1x=0,a1y=0,a1z=0,a1w=0;
    #pragma unroll 4
    for (int k = 0; k < K; ++k) {
        const float4 w = *(const float4*)(W + (size_t)k * 128 + c4);
        const float x0 = sX[rb][k];
        const float x1 = sX[rb + 8][k];
        a0x = fmaf(x0, w.x, a0x); a0y = fmaf(x0, w.y, a0y);
        a0z = fmaf(x0, w.z, a0z); a0w = fmaf(x0, w.w, a0w);
        a1x = fmaf(x1, w.x, a1x); a1y = fmaf(x1, w.y, a1y);
        a1z = fmaf(x1, w.z, a1z); a1w = fmaf(x1, w.w, a1w);
    }
    float bx=0, by=0, bz=0, bw=0;
    if (bias) { const float4 b = *(const float4*)(bias + c4); bx=b.x; by=b.y; bz=b.z; bw=b.w; }

    #pragma unroll
    for (int h = 0; h < 2; ++h) {
        const int rr = row0 + rb + (h ? 8 : 0);
        if (rr >= M) continue;
        float v0 = (h?a1x:a0x)+bx, v1 = (h?a1y:a0y)+by;
        float v2 = (h?a1z:a0z)+bz, v3 = (h?a1w:a0w)+bw;
        if (ybf) {
            unsigned short* p = (unsigned short*)Y + (size_t)rr * 128 + c4;
            ushort4 o; o.x=f2bf(v0); o.y=f2bf(v1); o.z=f2bf(v2); o.w=f2bf(v3);
            *(ushort4*)p = o;
        } else {
            float* p = (float*)Y + (size_t)rr * 128 + c4;
            if (accum) { v0+=p[0]; v1+=p[1]; v2+=p[2]; v3+=p[3]; }
            if (dorelu) { v0=fmaxf(v0,0.f); v1=fmaxf(v1,0.f); v2=fmaxf(v2,0.f); v3=fmaxf(v3,0.f); }
            float4 o; o.x=v0; o.y=v1; o.z=v2; o.w=v3;
            *(float4*)p = o;
        }
    }
}

// ---------------- fused dual-input host GEMM: Y = relu(X1@W1 + X2@W2 + b) ------
__global__ __launch_bounds__(256) void k_gemm2in(
    const float* __restrict__ X1, const float* __restrict__ X2,
    const float* __restrict__ W1, const float* __restrict__ W2,
    const float* __restrict__ bias, float* __restrict__ Y, int M)
{
    const int tid  = threadIdx.x;
    const int row0 = blockIdx.x * 16;
    __shared__ float sX1[16][130];
    __shared__ float sX2[16][130];
    for (int i = tid; i < 16 * 128; i += 256) {
        int r = i >> 7, c = i & 127;
        int gr = row0 + r;
        sX1[r][c] = (gr < M) ? X1[(size_t)gr * 128 + c] : 0.f;
        sX2[r][c] = (gr < M) ? X2[(size_t)gr * 128 + c] : 0.f;
    }
    __syncthreads();

    const int c4 = (tid & 31) * 4;
    const int rb = tid >> 5;
    float a0x=0,a0y=0,a0z=0,a0w=0, a1x=0,a1y=0,a1z=0,a1w=0;
    #pragma unroll 4
    for (int k = 0; k < 128; ++k) {
        const float4 w = *(const float4*)(W1 + (size_t)k * 128 + c4);
        const float x0 = sX1[rb][k];
        const float x1 = sX1[rb + 8][k];
        a0x = fmaf(x0, w.x, a0x); a0y = fmaf(x0, w.y, a0y);
        a0z = fmaf(x0, w.z, a0z); a0w = fmaf(x0, w.w, a0w);
        a1x = fmaf(x1, w.x, a1x); a1y = fmaf(x1, w.y, a1y);
        a1z = fmaf(x1, w.z, a1z); a1w = fmaf(x1, w.w, a1w);
    }
    #pragma unroll 4
    for (int k = 0; k < 128; ++k) {
        const float4 w = *(const float4*)(W2 + (size_t)k * 128 + c4);
        const float x0 = sX2[rb][k];
        const float x1 = sX2[rb + 8][k];
        a0x = fmaf(x0, w.x, a0x); a0y = fmaf(x0, w.y, a0y);
        a0z = fmaf(x0, w.z, a0z); a0w = fmaf(x0, w.w, a0w);
        a1x = fmaf(x1, w.x, a1x); a1y = fmaf(x1, w.y, a1y);
        a1z = fmaf(x1, w.z, a1z); a1w = fmaf(x1, w.w, a1w);
    }
    const float4 b = *(const float4*)(bias + c4);
    #pragma unroll
    for (int h = 0; h < 2; ++h) {
        const int rr = row0 + rb + (h ? 8 : 0);
        if (rr >= M) continue;
        float4 o;
        o.x = fmaxf((h?a1x:a0x) + b.x, 0.f);
        o.y = fmaxf((h?a1y:a0y) + b.y, 0.f);
        o.z = fmaxf((h?a1z:a0z) + b.z, 0.f);
        o.w = fmaxf((h?a1w:a0w) + b.w, 0.f);
        *(float4*)(Y + (size_t)rr * 128 + c4) = o;
    }
}

// ---------------- MFMA dual flow GEMM: both outputs bf16, no bias ----------------
// CHANGED: operands swapped (mfma(b, a) == old-D^T). Both operand fragment layouts
// of mfma_f32_16x16x32_bf16 are identical (lane&15 = row, lane>>4 = k-quad), so the
// swap is free; the transposed D layout puts 4 CONSECUTIVE output columns in one
// lane's 4 acc regs -> epilogue becomes 8 ushort4 stores/lane instead of 32 scalar
// 2B stores/lane (old epilogue was ~2x the MFMA time in store issue + 32B-segment
// coalescing).
typedef __attribute__((ext_vector_type(8))) short bfrag;
typedef __attribute__((ext_vector_type(4))) float f32x4;

__global__ __launch_bounds__(256) void k_gemm_mfma(
    const unsigned short* __restrict__ Abf, const unsigned short* __restrict__ WBT,
    unsigned short* __restrict__ Y1, unsigned short* __restrict__ Y2, int M)
{
    const int tid  = threadIdx.x;
    const int wave = tid >> 6;
    const int lane = tid & 63;
    const int quad = lane >> 4;
    const int l16  = lane & 15;
    const int m0   = blockIdx.x * 32;

    __shared__ unsigned short sA[32 * 128];   // 8 KB, XOR-swizzled 16B units

    {
        const uint4* gsrc = (const uint4*)(Abf + (size_t)m0 * 128);
        uint4* sdst = (uint4*)sA;
        #pragma unroll
        for (int p = 0; p < 2; ++p) {
            int g = tid + p * 256;
            int row = g >> 4, u = g & 15;
            sdst[row * 16 + (u ^ (row & 15))] = gsrc[g];
        }
    }
    __syncthreads();

    f32x4 acc[2][4] = {};
    const int nbase = wave * 64;

    #pragma unroll
    for (int c = 0; c < 4; ++c) {
        const int un = (c * 4 + quad) ^ l16;
        bfrag a0 = *(const bfrag*)(sA + ((size_t)(l16)      * 128 + un * 8));
        bfrag a1 = *(const bfrag*)(sA + ((size_t)(16 + l16) * 128 + un * 8));
        #pragma unroll
        for (int j = 0; j < 4; ++j) {
            const bfrag b = *(const bfrag*)(WBT + (size_t)(nbase + j * 16 + l16) * 128
                                                 + c * 32 + quad * 8);
            // swapped operand order: D' = D^T -> row = n-dim, col = m-dim
            acc[0][j] = __builtin_amdgcn_mfma_f32_16x16x32_bf16(b, a0, acc[0][j], 0, 0, 0);
            acc[1][j] = __builtin_amdgcn_mfma_f32_16x16x32_bf16(b, a1, acc[1][j], 0, 0, 0);
        }
    }

    unsigned short* Yd = (nbase < 128) ? Y1 : Y2;
    const int colb = nbase & 127;
    // D' layout: col(lane&15) = X-row m (within 16-block i), row(quad*4+r) = WBT-row n
    #pragma unroll
    for (int i = 0; i < 2; ++i) {
        const int row = m0 + i * 16 + l16;
        #pragma unroll
        for (int j = 0; j < 4; ++j) {
            const int col = colb + j * 16 + quad * 4;
            ushort4 o;
            o.x = f2bf(acc[i][j][0]); o.y = f2bf(acc[i][j][1]);
            o.z = f2bf(acc[i][j][2]); o.w = f2bf(acc[i][j][3]);
            *(ushort4*)(Yd + (size_t)row * 128 + col) = o;
        }
    }
}

// ---------------- CSR gather-aggregation (all-bf16, 4 dst/block) ----------------
// CHANGED: wave split into two 32-lane halves; each half processes alternating
// edges with ushort4 (8B/lane) gathers -> one wave VMEM instruction now fetches
// TWO 256B rows (512B) instead of one; index-load + address VALU per edge halved.
// Final cross-half combine via __shfl_xor(.,32), half 0 stores ushort4.
// Xout[d] = relu?( root[d] + bias + sum_rel Zrel[s] + sum_h2f Zh2f[s] )
__global__ __launch_bounds__(256) void k_agg_flow(
    const unsigned short* __restrict__ Zrel, const unsigned short* __restrict__ Zh2f,
    const int* __restrict__ rp_rel, const int* __restrict__ ei_rel,
    const int* __restrict__ rp_h2f, const int* __restrict__ ei_h2f,
    const unsigned short* __restrict__ root, const float* __restrict__ bias,
    unsigned short* __restrict__ Xout, int do_relu)
{
    const int wave = threadIdx.x >> 6;
    const int lane = threadIdx.x & 63;
    const int half = lane >> 5;     // 0/1: which edge-parity this lane works on
    const int l32  = lane & 31;
    const int d = blockIdx.x * 4 + wave;
    const int f4 = l32 * 4;         // 4 features per lane

    // issue all row-pointer loads up front (independent)
    const int r0 = rp_rel[d], r1 = rp_rel[d + 1];
    const int h0 = rp_h2f[d], h1 = rp_h2f[d + 1];

    // root + bias issued early, only needed by half 0
    ushort4 rv = {0, 0, 0, 0};
    float4  bv = {0.f, 0.f, 0.f, 0.f};
    if (half == 0) {
        rv = *(const ushort4*)(root + (size_t)d * 128 + f4);
        bv = *(const float4*)(bias + f4);
    }

    float a0 = 0.f, a1 = 0.f, a2 = 0.f, a3 = 0.f;

    auto run = [&](const unsigned short* __restrict__ Z, const int* __restrict__ ei,
                   int b0, int b1) {
        int e = b0 + half;
        int rem = b1 - b0 - half;        // may be -1 when degree==0 and half==1
        int cnt = (rem + 1) >> 1;        // edges this half owns (0 when rem<=0... rem=-1 -> 0)
        while (cnt >= 4) {
            const int s0 = ei[e];
            const int s1 = ei[e + 2];
            const int s2 = ei[e + 4];
            const int s3 = ei[e + 6];
            const ushort4 z0 = *(const ushort4*)(Z + (size_t)s0 * 128 + f4);
            const ushort4 z1 = *(const ushort4*)(Z + (size_t)s1 * 128 + f4);
            const ushort4 z2 = *(const ushort4*)(Z + (size_t)s2 * 128 + f4);
            const ushort4 z3 = *(const ushort4*)(Z + (size_t)s3 * 128 + f4);
            a0 += (bf2f(z0.x) + bf2f(z1.x)) + (bf2f(z2.x) + bf2f(z3.x));
            a1 += (bf2f(z0.y) + bf2f(z1.y)) + (bf2f(z2.y) + bf2f(z3.y));
            a2 += (bf2f(z0.z) + bf2f(z1.z)) + (bf2f(z2.z) + bf2f(z3.z));
            a3 += (bf2f(z0.w) + bf2f(z1.w)) + (bf2f(z2.w) + bf2f(z3.w));
            e += 8; cnt -= 4;
        }
        if (cnt & 2) {
            const int s0 = ei[e];
            const int s1 = ei[e + 2];
            const ushort4 z0 = *(const ushort4*)(Z + (size_t)s0 * 128 + f4);
            const ushort4 z1 = *(const ushort4*)(Z + (size_t)s1 * 128 + f4);
            a0 += bf2f(z0.x) + bf2f(z1.x);
            a1 += bf2f(z0.y) + bf2f(z1.y);
            a2 += bf2f(z0.z) + bf2f(z1.z);
            a3 += bf2f(z0.w) + bf2f(z1.w);
            e += 4;
        }
        if (cnt & 1) {
            const int s0 = ei[e];
            const ushort4 z0 = *(const ushort4*)(Z + (size_t)s0 * 128 + f4);
            a0 += bf2f(z0.x); a1 += bf2f(z0.y); a2 += bf2f(z0.z); a3 += bf2f(z0.w);
        }
    };
    run(Zrel, ei_rel, r0, r1);
    run(Zh2f, ei_h2f, h0, h1);

    // combine the two halves (partner lane = lane ^ 32 holds same features)
    a0 += __shfl_xor(a0, 32, 64);
    a1 += __shfl_xor(a1, 32, 64);
    a2 += __shfl_xor(a2, 32, 64);
    a3 += __shfl_xor(a3, 32, 64);

    if (half == 0) {
        float v0 = a0 + bf2f(rv.x) + bv.x;
        float v1 = a1 + bf2f(rv.y) + bv.y;
        float v2 = a2 + bf2f(rv.z) + bv.z;
        float v3 = a3 + bf2f(rv.w) + bv.w;
        if (do_relu) {
            v0 = fmaxf(v0, 0.f); v1 = fmaxf(v1, 0.f);
            v2 = fmaxf(v2, 0.f); v3 = fmaxf(v3, 0.f);
        }
        ushort4 o;
        o.x = f2bf(v0); o.y = f2bf(v1); o.z = f2bf(v2); o.w = f2bf(v3);
        *(ushort4*)(Xout + (size_t)d * 128 + f4) = o;
    }
}

// host dst: out[d][0:128] = sum f2h Zbf[src][0:128]
// CHANGED: the 2 waves now split the edge list (alternating parity) with ushort2
// loads (one wave instruction per edge instead of two scalar-ushort instructions),
// chunk-4 for ILP, LDS combine across waves.
__global__ __launch_bounds__(128) void k_agg_host(
    const unsigned short* __restrict__ Z, const int* __restrict__ rp,
    const int* __restrict__ ei, float* __restrict__ out)
{
    const int d = blockIdx.x;
    const int t = threadIdx.x;
    const int w = t >> 6;          // wave 0/1 = edge parity
    const int lane = t & 63;
    const int f2 = lane * 2;       // 2 features per lane
    __shared__ float sh[128];

    const int b0 = rp[d], b1 = rp[d + 1];
    float a0 = 0.f, a1 = 0.f;

    int e = b0 + w;
    int rem = b1 - b0 - w;
    int cnt = (rem + 1) >> 1;
    while (cnt >= 4) {
        const int s0 = ei[e];
        const int s1 = ei[e + 2];
        const int s2 = ei[e + 4];
        const int s3 = ei[e + 6];
        const ushort2 z0 = *(const ushort2*)(Z + (size_t)s0 * 128 + f2);
        const ushort2 z1 = *(const ushort2*)(Z + (size_t)s1 * 128 + f2);
        const ushort2 z2 = *(const ushort2*)(Z + (size_t)s2 * 128 + f2);
        const ushort2 z3 = *(const ushort2*)(Z + (size_t)s3 * 128 + f2);
        a0 += (bf2f(z0.x) + bf2f(z1.x)) + (bf2f(z2.x) + bf2f(z3.x));
        a1 += (bf2f(z0.y) + bf2f(z1.y)) + (bf2f(z2.y) + bf2f(z3.y));
        e += 8; cnt -= 4;
    }
    if (cnt & 2) {
        const int s0 = ei[e];
        const int s1 = ei[e + 2];
        const ushort2 z0 = *(const ushort2*)(Z + (size_t)s0 * 128 + f2);
        const ushort2 z1 = *(const ushort2*)(Z + (size_t)s1 * 128 + f2);
        a0 += bf2f(z0.x) + bf2f(z1.x);
        a1 += bf2f(z0.y) + bf2f(z1.y);
        e += 4;
    }
    if (cnt & 1) {
        const int s0 = ei[e];
        const ushort2 z0 = *(const ushort2*)(Z + (size_t)s0 * 128 + f2);
        a0 += bf2f(z0.x); a1 += bf2f(z0.y);
    }

    if (w == 1) { sh[f2] = a0; sh[f2 + 1] = a1; }
    __syncthreads();
    if (w == 0) {
        float2 o;
        o.x = a0 + sh[f2];
        o.y = a1 + sh[f2 + 1];
        *(float2*)(out + (size_t)d * 128 + f2) = o;
    }
}

// ---------------- pooling over sorted batch (bf16 input) ----------------
#define PCHUNK 128
__global__ __launch_bounds__(128) void k_pool2(const unsigned short* xf, const int* batch,
                                               unsigned* bits){
    const int t = threadIdx.x;
    const int i0 = blockIdx.x * PCHUNK;
    const int iend = min(i0 + PCHUNK, N_FLOWN);
    if (i0 >= N_FLOWN) return;
    float cur = -3.4e38f;
    int curg = batch[i0];
    for (int i = i0; i < iend; ++i) {
        int g = batch[i];
        if (g != curg) {
            unsigned u = __float_as_uint(cur);
            unsigned ord = (u & 0x80000000u) ? ~u : (u | 0x80000000u);
            atomicMax(&bits[(size_t)curg * 128 + t], ord);
            cur = -3.4e38f; curg = g;
        }
        cur = fmaxf(cur, bf2f(xf[(size_t)i * 128 + t]));
    }
    unsigned u = __float_as_uint(cur);
    unsigned ord = (u & 0x80000000u) ? ~u : (u | 0x80000000u);
    atomicMax(&bits[(size_t)curg * 128 + t], ord);
}

// ---------------- classifier ----------------
__global__ __launch_bounds__(128) void k_classifier(
    const unsigned* bits,
    const void* Wc1, const void* bc1, const void* Wc2, const void* bc2,
    const void* Wc3, const void* bc3, void* out, const int* flagp)
{
    const int g = blockIdx.x, t = threadIdx.x;
    const int isbf = *flagp;
    __shared__ float sp[128], sh1[64], sh2[128];
    {
        unsigned ord = bits[(size_t)g * HH + t];
        unsigned u = (ord & 0x80000000u) ? (ord & 0x7FFFFFFFu) : ~ord;
        sp[t] = __uint_as_float(u);
    }
    __syncthreads();
    if (t < 64) {
        float a = loadf(bc1, t, isbf);
        #pragma unroll 4
        for (int k = 0; k < 128; ++k) a = fmaf(sp[k], loadf(Wc1, k * 64 + t, isbf), a);
        sh1[t] = fmaxf(a, 0.f);
    }
    __syncthreads();
    {
        float a = loadf(bc2, t, isbf);
        #pragma unroll 4
        for (int k = 0; k < 64; ++k) a = fmaf(sh1[k], loadf(Wc2, k * 128 + t, isbf), a);
        sh2[t] = fmaxf(a, 0.f);
    }
    __syncthreads();
    if (t < NCN) {
        float a = loadf(bc3, t, isbf);
        #pragma unroll 4
        for (int k = 0; k < 128; ++k) a = fmaf(sh2[k], loadf(Wc3, k * NCN + t, isbf), a);
        if (isbf) ((unsigned short*)out)[(size_t)g * NCN + t] = f2bf(a);
        else      ((float*)out)[(size_t)g * NCN + t] = a;
    }
}

extern "C" void kernel_launch(void* const* d_in, const int* in_sizes, int n_in,
                              void* d_out, int out_size, void* d_ws, size_t ws_size,
                              hipStream_t stream)
{
    const int*  host_ids   = (const int*) d_in[0];
    const void* flow_x     = d_in[1];
    const int*  h2f_src    = (const int*) d_in[2];
    const int*  h2f_dst    = (const int*) d_in[3];
    const int*  f2h_src    = (const int*) d_in[4];
    const int*  f2h_dst    = (const int*) d_in[5];
    const int*  rel_src    = (const int*) d_in[6];
    const int*  rel_dst    = (const int*) d_in[7];
    const int*  flow_batch = (const int*) d_in[8];
    const void* host_embed = d_in[9];
    const void* Wr0_h2f = d_in[10]; const void* br0_h2f = d_in[11]; const void* Wo0_h2f = d_in[12];
    const void* Wr0_f2h = d_in[13]; const void* br0_f2h = d_in[14]; const void* Wo0_f2h = d_in[15];
    const void* Wr0_rel = d_in[16]; const void* br0_rel = d_in[17]; const void* Wo0_rel = d_in[18];
    const void* Wr_all  = d_in[19];
    const void* br_all  = d_in[20];
    const void* Wo_all  = d_in[21];
    const void* Wc1 = d_in[22]; const void* bc1 = d_in[23];
    const void* Wc2 = d_in[24]; const void* bc2 = d_in[25];
    const void* Wc3 = d_in[26]; const void* bc3 = d_in[27];

    // -------- workspace (~200 MB) --------
    size_t off = 0;
    auto alloc = [&](size_t bytes) -> char* {
        char* p = (char*)d_ws + off;
        off += (bytes + 255) & ~(size_t)255;
        return p;
    };
    unsigned short* F1bf  = (unsigned short*)alloc((size_t)N_FLOWN * HH * 2);  // state
    unsigned short* Froot = (unsigned short*)alloc((size_t)N_FLOWN * HH * 2);  // root term
    unsigned short* F2bf  = (unsigned short*)alloc((size_t)N_FLOWN * HH * 2);  // z_rel
    float* HA = (float*)alloc((size_t)N_HOSTN * HH * 4);
    float* HB = (float*)alloc((size_t)N_HOSTN * HH * 4);
    unsigned short* HCbf = (unsigned short*)alloc((size_t)N_HOSTN * HH * 2);   // z_h
    float* HD = (float*)alloc((size_t)N_HOSTN * HH * 4);
    unsigned short* WBT0 = (unsigned short*)alloc(256 * 128 * 2);
    unsigned short* WBT1 = (unsigned short*)alloc(256 * 128 * 2);
    unsigned short* WBT2 = (unsigned short*)alloc(256 * 128 * 2);
    float* w_h2f0  = (float*)alloc(128 * 128 * 4);
    float* w_h2f1  = (float*)alloc(128 * 128 * 4);
    float* w_h2f2  = (float*)alloc(128 * 128 * 4);
    float* w_f2h0  = (float*)alloc(128 * 128 * 4);
    float* w_f2h1  = (float*)alloc(128 * 128 * 4);
    float* w_of2h0 = (float*)alloc(128 * 128 * 4);
    float* w_of2h1 = (float*)alloc(128 * 128 * 4);
    float* b_comb0 = (float*)alloc(128 * 4);
    float* b_comb1 = (float*)alloc(128 * 4);
    float* b_comb2 = (float*)alloc(128 * 4);
    float* b_f2h0  = (float*)alloc(128 * 4);
    float* b_f2h1  = (float*)alloc(128 * 4);
    unsigned* poolbits = (unsigned*)alloc(GG * HH * 4);
    int* flagp = (int*)alloc(256);
    int* rp_rel = (int*)alloc((N_FLOWN + 1) * 4);
    int* ei_rel = (int*)alloc((size_t)E_RELN * 4);
    int* rp_h2f = (int*)alloc((N_FLOWN + 1) * 4);
    int* ei_h2f = (int*)alloc((size_t)E_HFN * 4);
    int* rp_f2h = (int*)alloc((N_HOSTN + 1) * 4);
    int* ei_f2h = (int*)alloc((size_t)E_HFN * 4);
    int* wr_rel = (int*)alloc((size_t)N_FLOWN * 4);
    int* wr_h2f = (int*)alloc((size_t)N_FLOWN * 4);
    int* wr_f2h = (int*)alloc((size_t)N_HOSTN * 4);
    int* bs0 = (int*)alloc(1024 * 4);
    int* bs1 = (int*)alloc(1024 * 4);
    int* bs2 = (int*)alloc(256 * 4);

    const int T = 256;
    #define GRID1(n) dim3(cdiv((long long)(n), T)), dim3(T), 0, stream

    if (off > ws_size) {
        k_flag_us<<<GRID1(out_size)>>>((unsigned short*)d_out, out_size, (unsigned short)0x4000);
        return;
    }

    k_detect<<<dim3(1), dim3(256), 0, stream>>>((const unsigned short*)flow_x, flagp);

    // -------- CSR builds (batched, 6 launches) --------
    k_zero3 <<<dim3(2*NB_REL_N + NB_F2H_N), dim3(256), 0, stream>>>(wr_rel, wr_h2f, wr_f2h);
    k_hist3 <<<dim3(NB_REL_E + 2*NB_HF_E), dim3(256), 0, stream>>>(rel_dst, h2f_dst, f2h_dst,
                                                                    wr_rel, wr_h2f, wr_f2h);
    k_scan1_3<<<dim3(2*NB_REL_N + NB_F2H_N), dim3(256), 0, stream>>>(
        wr_rel, rp_rel, bs0, wr_h2f, rp_h2f, bs1, wr_f2h, rp_f2h, bs2);
    k_scan2_3<<<dim3(3), dim3(256), 0, stream>>>(bs0, bs1, bs2);
    k_scan3_3<<<dim3(2*NB_REL_N + NB_F2H_N), dim3(256), 0, stream>>>(
        rp_rel, bs0, wr_rel, rp_h2f, bs1, wr_h2f, rp_f2h, bs2, wr_f2h);
    k_place3c<<<dim3(PLC_ALL), dim3(256), 0, stream>>>(
        rel_src, rel_dst, wr_rel, ei_rel,
        h2f_src, h2f_dst, wr_h2f, ei_h2f,
        f2h_src, f2h_dst, wr_f2h, ei_f2h);

    // -------- weight prep (1 launch) --------
    k_wprep_all<<<dim3(833), dim3(256), 0, stream>>>(
        Wr0_h2f, br0_h2f, Wo0_h2f, Wr0_f2h, br0_f2h, Wo0_f2h, Wr0_rel, br0_rel, Wo0_rel,
        Wr_all, br_all, Wo_all,
        WBT0, WBT1, WBT2, w_h2f0, w_h2f1, w_h2f2,
        w_f2h0, w_f2h1, w_of2h0, w_of2h1,
        b_comb0, b_comb1, b_comb2, b_f2h0, b_f2h1, flagp);

    // ================= layer 0 =================
    k_gather_embed<<<GRID1(N_HOSTN * HH)>>>(host_ids, host_embed, HA, flagp);
    k_pad_cast<<<GRID1((size_t)N_FLOWN * 128)>>>(flow_x, F1bf, flagp);
    // host path: gather bf16 input features (K padded to 128); fused dual GEMM + relu
    k_agg_host<<<dim3(N_HOSTN), dim3(128), 0, stream>>>(F1bf, rp_f2h, ei_f2h, HD);
    k_gemm2in<<<dim3(cdiv(N_HOSTN,16)), dim3(256), 0, stream>>>(HD, HA, w_f2h0, w_of2h0, b_f2h0, HB, N_HOSTN);
    // flow path
    k_gemm128<<<dim3(cdiv(N_HOSTN,16)), dim3(256), 0, stream>>>(HA, 0, w_h2f0, nullptr, HCbf, 1, N_HOSTN, 128, 0, 0, flagp);
    k_gemm_mfma<<<dim3(N_FLOWN/32), dim3(256), 0, stream>>>(F1bf, WBT0, Froot, F2bf, N_FLOWN);
    k_agg_flow<<<dim3(N_FLOWN/4), dim3(256), 0, stream>>>(F2bf, HCbf, rp_rel, ei_rel, rp_h2f, ei_h2f,
                                                          Froot, b_comb0, F1bf, 1);

    // ================= stacked layer 0 =================
    k_agg_host<<<dim3(N_HOSTN), dim3(128), 0, stream>>>(F1bf, rp_f2h, ei_f2h, HD);
    k_gemm128<<<dim3(cdiv(N_HOSTN,16)), dim3(256), 0, stream>>>(HB, 0, w_h2f1, nullptr, HCbf, 1, N_HOSTN, 128, 0, 0, flagp);
    k_gemm_mfma<<<dim3(N_FLOWN/32), dim3(256), 0, stream>>>(F1bf, WBT1, Froot, F2bf, N_FLOWN);
    k_agg_flow<<<dim3(N_FLOWN/4), dim3(256), 0, stream>>>(F2bf, HCbf, rp_rel, ei_rel, rp_h2f, ei_h2f,
                                                          Froot, b_comb1, F1bf, 1);
    k_gemm2in<<<dim3(cdiv(N_HOSTN,16)), dim3(256), 0, stream>>>(HD, HB, w_f2h1, w_of2h1, b_f2h1, HA, N_HOSTN);

    // ================= stacked layer 1 (last; no host update, no relu) =================
    k_gemm128<<<dim3(cdiv(N_HOSTN,16)), dim3(256), 0, stream>>>(HA, 0, w_h2f2, nullptr, HCbf, 1, N_HOSTN, 128, 0, 0, flagp);
    k_gemm_mfma<<<dim3(N_FLOWN/32), dim3(256), 0, stream>>>(F1bf, WBT2, Froot, F2bf, N_FLOWN);
    k_agg_flow<<<dim3(N_FLOWN/4), dim3(256), 0, stream>>>(F2bf, HCbf, rp_rel, ei_rel, rp_h2f, ei_h2f,
                                                          Froot, b_comb2, F1bf, 0);

    // ================= pool + classifier =================
    k_zero<<<GRID1(GG * HH)>>>((float*)poolbits, (size_t)GG * HH);
    k_pool2<<<dim3(cdiv(N_FLOWN, PCHUNK)), dim3(128), 0, stream>>>(F1bf, flow_batch, poolbits);
    k_classifier<<<dim3(GG), dim3(128), 0, stream>>>(poolbits, Wc1, bc1, Wc2, bc2, Wc3, bc3,
                                                     d_out, flagp);
    #undef GRID1
}

// Round 2
// 1141.151 us; speedup vs baseline: 1.0401x; 1.0362x over previous
//
#include <hip/hip_runtime.h>
#include <hip/hip_bf16.h>

using bf16 = __hip_bfloat16;

#define N_HOSTN 20000
#define N_FLOWN 200000
#define E_HFN   400000
#define E_RELN  800000
#define E_CMBN  1200000  // rel + h2f combined
#define GG      64
#define HH      128
#define FIN     97
#define NCN     10

// CSR region block counts (256 threads/block)
#define NB_REL_E 3125   // 800000/256
#define NB_HF_E  1563   // ceil(400000/256)
#define NB_CMB_N 782    // ceil(200000/256)
#define NB_F2H_N 79     // ceil(20000/256)
// class-partitioned placement: 2048-edge chunks x 8 classes
#define NCH_REL 391     // ceil(800000/2048)
#define NCH_HF  196     // ceil(400000/2048)
#define PLC_REL (NCH_REL*8)            // 3128
#define PLC_H2F (PLC_REL + NCH_HF*8)   // 4696
#define PLC_ALL (PLC_H2F + NCH_HF*8)   // 6264

static inline int cdiv(long long a, long long b){ return (int)((a + b - 1) / b); }

__device__ __forceinline__ float bf2f(unsigned short u){
    return __uint_as_float(((unsigned)u) << 16);
}
__device__ __forceinline__ unsigned short f2bf(float f){
    unsigned u = __float_as_uint(f);
    unsigned r = u + 0x7FFFu + ((u >> 16) & 1u);   // RNE
    return (unsigned short)(r >> 16);
}
__device__ __forceinline__ float loadf(const void* p, size_t i, int isbf){
    return isbf ? bf2f(((const unsigned short*)p)[i]) : ((const float*)p)[i];
}
// unpack 8 bf16 (uint4) and accumulate into 8 f32
__device__ __forceinline__ void acc8(float* a, uint4 z){
    a[0] += __uint_as_float(z.x << 16);
    a[1] += __uint_as_float(z.x & 0xFFFF0000u);
    a[2] += __uint_as_float(z.y << 16);
    a[3] += __uint_as_float(z.y & 0xFFFF0000u);
    a[4] += __uint_as_float(z.z << 16);
    a[5] += __uint_as_float(z.z & 0xFFFF0000u);
    a[6] += __uint_as_float(z.w << 16);
    a[7] += __uint_as_float(z.w & 0xFFFF0000u);
}

// ---------------- dtype detection ----------------
__global__ void k_detect(const unsigned short* x, int* flag){
    __shared__ int bad;
    if (threadIdx.x == 0) bad = 0;
    __syncthreads();
    int b = 0;
    for (int i = threadIdx.x; i < 4096; i += 256) {
        unsigned e = (x[i] >> 7) & 0xFFu;
        if (e >= 0x90u) b++;
    }
    if (b) atomicAdd(&bad, b);
    __syncthreads();
    if (threadIdx.x == 0) *flag = (bad == 0) ? 1 : 0;   // 1 = bf16, 0 = f32
}

// ---------------- misc ----------------
__global__ void k_zero(float* p, size_t n){
    size_t i = (size_t)blockIdx.x * 256 + threadIdx.x;
    if (i < n) p[i] = 0.f;
}
__global__ void k_flag_us(unsigned short* out, int n, unsigned short val){
    int i = blockIdx.x * 256 + threadIdx.x;
    if (i < n) out[i] = val;
}
__global__ void k_gather_embed(const int* ids, const void* emb, float* out, const int* flagp){
    int i = blockIdx.x * 256 + threadIdx.x;
    if (i >= N_HOSTN * HH) return;
    int isbf = *flagp;
    int node = i >> 7, f = i & 127;
    out[i] = loadf(emb, (size_t)ids[node] * HH + f, isbf);
}
// flow_x [N,97] (flag dtype) -> bf16 padded [N,128]
__global__ void k_pad_cast(const void* x, unsigned short* o, const int* flagp){
    size_t i = (size_t)blockIdx.x * 256 + threadIdx.x;
    if (i >= (size_t)N_FLOWN * 128) return;
    int isbf = *flagp;
    int row = (int)(i >> 7), c = (int)i & 127;
    o[i] = (c < FIN) ? f2bf(loadf(x, (size_t)row * FIN + c, isbf)) : (unsigned short)0;
}

// ---------------- one-shot weight prep (833 blocks, region dispatch) ----------------
__global__ __launch_bounds__(256) void k_wprep_all(
    const void* Wr0_h2f, const void* br0_h2f, const void* Wo0_h2f,
    const void* Wr0_f2h, const void* br0_f2h, const void* Wo0_f2h,
    const void* Wr0_rel, const void* br0_rel, const void* Wo0_rel,
    const void* Wr_all, const void* br_all, const void* Wo_all,
    unsigned short* WBT0, unsigned short* WBT1, unsigned short* WBT2,
    float* w_h2f0, float* w_h2f1, float* w_h2f2,
    float* w_f2h0, float* w_f2h1, float* w_of2h0, float* w_of2h1,
    float* b_comb0, float* b_comb1, float* b_comb2, float* b_f2h0, float* b_f2h1,
    const int* flagp)
{
    const int bb = blockIdx.x, t = threadIdx.x;
    const int isbf = *flagp;
    if (bb < 384) {
        int layer = bb >> 7;
        int i = ((bb & 127) << 8) + t;   // 0..32767
        int nn = i >> 7, k = i & 127;
        float v = 0.f;
        if (layer == 0) {
            if (k < FIN) {
                if (nn < 128) v = loadf(Wo0_h2f, (size_t)k*128+nn, isbf) + loadf(Wo0_rel, (size_t)k*128+nn, isbf);
                else          v = loadf(Wr0_rel, (size_t)k*128+(nn-128), isbf);
            }
        } else {
            size_t oW = (size_t)((layer - 1) * 3) * 16384;
            if (nn < 128) v = loadf(Wo_all, oW + (size_t)k*128+nn, isbf)
                            + loadf(Wo_all, oW + 2*16384 + (size_t)k*128+nn, isbf);
            else          v = loadf(Wr_all, oW + 2*16384 + (size_t)k*128+(nn-128), isbf);
        }
        unsigned short* W = (layer == 0) ? WBT0 : ((layer == 1) ? WBT1 : WBT2);
        W[(size_t)nn*128 + k] = f2bf(v);
    } else if (bb < 576) {
        int r = bb - 384; int layer = r >> 6; int i = ((r & 63) << 8) + t;
        float v;
        if (layer == 0) v = loadf(Wr0_h2f, (size_t)i, isbf);
        else            v = loadf(Wr_all, (size_t)((layer-1)*3)*16384 + i, isbf);
        ((layer == 0) ? w_h2f0 : ((layer == 1) ? w_h2f1 : w_h2f2))[i] = v;
    } else if (bb < 640) {
        // w_f2h0 padded to [128][128]: rows k>=97 zero
        int i = ((bb - 576) << 8) + t;
        int k = i >> 7;
        w_f2h0[i] = (k < FIN) ? loadf(Wr0_f2h, (size_t)i, isbf) : 0.f;
    } else if (bb < 704) {
        int i = ((bb - 640) << 8) + t;
        w_f2h1[i] = loadf(Wr_all, (size_t)1*16384 + i, isbf);
    } else if (bb < 768) {
        int i = ((bb - 704) << 8) + t;
        w_of2h0[i] = loadf(Wo0_f2h, (size_t)i, isbf);
    } else if (bb < 832) {
        int i = ((bb - 768) << 8) + t;
        w_of2h1[i] = loadf(Wo_all, (size_t)1*16384 + i, isbf);
    } else {
        if (t < 128) {
            b_comb0[t] = loadf(br0_h2f, t, isbf) + loadf(br0_rel, t, isbf);
            b_comb1[t] = loadf(br_all, 0*128 + t, isbf) + loadf(br_all, 2*128 + t, isbf);
            b_comb2[t] = loadf(br_all, 3*128 + t, isbf) + loadf(br_all, 5*128 + t, isbf);
            b_f2h0[t]  = loadf(br0_f2h, t, isbf);
            b_f2h1[t]  = loadf(br_all, 1*128 + t, isbf);
        }
    }
}

// ---------------- CSR build (combined flow CSR + f2h CSR) ----------------
__global__ void k_zero2(int* c0, int* c1){
    int bb = blockIdx.x, t = threadIdx.x;
    if (bb < NB_CMB_N) { int i = bb * 256 + t; if (i < N_FLOWN) c0[i] = 0; }
    else               { int i = (bb - NB_CMB_N) * 256 + t; if (i < N_HOSTN) c1[i] = 0; }
}
// rel and h2f edges both count into c_cmb; f2h into c_f2h
__global__ void k_hist3(const int* drel, const int* dh2f, const int* df2h,
                        int* c_cmb, int* c_f2h){
    int bb = blockIdx.x, t = threadIdx.x;
    const int* dst; int* cnt; int E; int base;
    if (bb < NB_REL_E)                   { dst = drel; cnt = c_cmb; E = E_RELN; base = bb; }
    else if (bb < NB_REL_E + NB_HF_E)    { dst = dh2f; cnt = c_cmb; E = E_HFN;  base = bb - NB_REL_E; }
    else                                 { dst = df2h; cnt = c_f2h; E = E_HFN;  base = bb - NB_REL_E - NB_HF_E; }
    int e = base * 256 + t;
    if (e < E) atomicAdd(&cnt[dst[e]], 1);
}
__global__ __launch_bounds__(256) void k_scan1_2(
    const int* c0, int* rp0, int* bs0,
    const int* c1, int* rp1, int* bs1)
{
    __shared__ int s[256];
    int bb = blockIdx.x, t = threadIdx.x;
    const int* cnt; int* rp; int* bsum; int n; int base;
    if (bb < NB_CMB_N) { cnt = c0; rp = rp0; bsum = bs0; n = N_FLOWN; base = bb; }
    else               { cnt = c1; rp = rp1; bsum = bs1; n = N_HOSTN; base = bb - NB_CMB_N; }
    int i = base * 256 + t;
    int v = (i < n) ? cnt[i] : 0;
    s[t] = v; __syncthreads();
    for (int off = 1; off < 256; off <<= 1) {
        int x = (t >= off) ? s[t - off] : 0;
        __syncthreads();
        s[t] += x;
        __syncthreads();
    }
    if (i < n) rp[i] = s[t] - v;
    if (t == 255) bsum[base] = s[255];
}
__global__ __launch_bounds__(256) void k_scan2_2(int* bs0, int* bs1){
    __shared__ int s[256];
    __shared__ int carry;
    int t = threadIdx.x;
    int* bsum; int nb;
    if (blockIdx.x == 0) { bsum = bs0; nb = NB_CMB_N; }
    else                 { bsum = bs1; nb = NB_F2H_N; }
    if (t == 0) carry = 0;
    __syncthreads();
    for (int base = 0; base < nb; base += 256) {
        int i = base + t;
        int v = (i < nb) ? bsum[i] : 0;
        s[t] = v; __syncthreads();
        for (int off = 1; off < 256; off <<= 1) {
            int x = (t >= off) ? s[t - off] : 0;
            __syncthreads();
            s[t] += x;
            __syncthreads();
        }
        int excl = s[t] - v + carry;
        if (i < nb) bsum[i] = excl;
        __syncthreads();
        if (t == 255) carry += s[255];
        __syncthreads();
    }
}
__global__ void k_scan3_2(int* rp0, const int* bs0, int* w0,
                          int* rp1, const int* bs1, int* w1)
{
    int bb = blockIdx.x, t = threadIdx.x;
    int* rp; const int* bsum; int* wr; int n, E, base;
    if (bb < NB_CMB_N) { rp = rp0; bsum = bs0; wr = w0; n = N_FLOWN; E = E_CMBN; base = bb; }
    else               { rp = rp1; bsum = bs1; wr = w1; n = N_HOSTN; E = E_HFN;  base = bb - NB_CMB_N; }
    int i = base * 256 + t;
    if (i < n) { int v = rp[i] + bsum[base]; rp[i] = v; wr[i] = v; }
    if (i == 0) rp[n] = E;
}
// class-partitioned placement: class = blockIdx%8 (round-robins onto XCDs);
// rel + h2f both place into the combined flow CSR; h2f srcs get +N_FLOWN so
// the gather reads the host rows appended after the flow rows in ZALL.
__global__ __launch_bounds__(256) void k_place3c(
    const int* s0, const int* d0,
    const int* s1, const int* d1,
    const int* s2, const int* d2,
    int* w_cmb, int* e_cmb, int* w_f2h, int* e_f2h)
{
    const int bb = blockIdx.x;
    const int *src, *dst; int *wr, *ei; int E, divc, rb, soff;
    if (bb < PLC_REL)      { src=s0; dst=d0; wr=w_cmb; ei=e_cmb; E=E_RELN; divc=25000; rb=bb;          soff=0; }
    else if (bb < PLC_H2F) { src=s1; dst=d1; wr=w_cmb; ei=e_cmb; E=E_HFN;  divc=25000; rb=bb-PLC_REL;  soff=N_FLOWN; }
    else                   { src=s2; dst=d2; wr=w_f2h; ei=e_f2h; E=E_HFN;  divc=2500;  rb=bb-PLC_H2F;  soff=0; }
    const int cls  = rb & 7;
    const int base = (rb >> 3) * 2048;
    const int t = threadIdx.x;
    #pragma unroll
    for (int i = 0; i < 8; ++i) {
        const int e = base + t + i * 256;
        if (e < E) {
            const int d = dst[e];
            if (d / divc == cls) {
                const int pos = atomicAdd(&wr[d], 1);
                ei[pos] = src[e] + soff;
            }
        }
    }
}

// ---------------- host-sized VALU GEMM: Y[M,128] (+)= X[M,K]@W[K,128]+b ---------
__global__ __launch_bounds__(256) void k_gemm128(
    const void* X, int xmode, const float* W, const float* bias,
    void* Y, int ybf, int M, int K, int accum, int dorelu, const int* flagp)
{
    const int isbf = (xmode == 2) ? *flagp : xmode;
    const int tid  = threadIdx.x;
    const int row0 = blockIdx.x * 16;
    __shared__ float sX[16][130];
    const int total = 16 * K;
    for (int i = tid; i < total; i += 256) {
        int r = i / K, c = i - r * K;
        int gr = row0 + r;
        sX[r][c] = (gr < M) ? loadf(X, (size_t)gr * K + c, isbf) : 0.f;
    }
    __syncthreads();

    const int c4 = (tid & 31) * 4;
    const int rb = tid >> 5;
    float a0x=0,a0y=0,a0z=0,a0w=0, a1x=0,a1y=0,a1z=0,a1w=0;
    #pragma unroll 4
    for (int k = 0; k < K; ++k) {
        const float4 w = *(const float4*)(W + (size_t)k * 128 + c4);
        const float x0 = sX[rb][k];
        const float x1 = sX[rb + 8][k];
        a0x = fmaf(x0, w.x, a0x); a0y = fmaf(x0, w.y, a0y);
        a0z = fmaf(x0, w.z, a0z); a0w = fmaf(x0, w.w, a0w);
        a1x = fmaf(x1, w.x, a1x); a1y = fmaf(x1, w.y, a1y);
        a1z = fmaf(x1, w.z, a1z); a1w = fmaf(x1, w.w, a1w);
    }
    float bx=0, by=0, bz=0, bw=0;
    if (bias) { const float4 b = *(const float4*)(bias + c4); bx=b.x; by=b.y; bz=b.z; bw=b.w; }

    #pragma unroll
    for (int h = 0; h < 2; ++h) {
        const int rr = row0 + rb + (h ? 8 : 0);
        if (rr >= M) continue;
        float v0 = (h?a1x:a0x)+bx, v1 = (h?a1y:a0y)+by;
        float v2 = (h?a1z:a0z)+bz, v3 = (h?a1w:a0w)+bw;
        if (ybf) {
            unsigned short* p = (unsigned short*)Y + (size_t)rr * 128 + c4;
            ushort4 o; o.x=f2bf(v0); o.y=f2bf(v1); o.z=f2bf(v2); o.w=f2bf(v3);
            *(ushort4*)p = o;
        } else {
            float* p = (float*)Y + (size_t)rr * 128 + c4;
            if (accum) { v0+=p[0]; v1+=p[1]; v2+=p[2]; v3+=p[3]; }
            if (dorelu) { v0=fmaxf(v0,0.f); v1=fmaxf(v1,0.f); v2=fmaxf(v2,0.f); v3=fmaxf(v3,0.f); }
            float4 o; o.x=v0; o.y=v1; o.z=v2; o.w=v3;
            *(float4*)p = o;
        }
    }
}

// ---------------- fused dual-input host GEMM: Y = relu(X1@W1 + X2@W2 + b) ------
__global__ __launch_bounds__(256) void k_gemm2in(
    const float* __restrict__ X1, const float* __restrict__ X2,
    const float* __restrict__ W1, const float* __restrict__ W2,
    const float* __restrict__ bias, float* __restrict__ Y, int M)
{
    const int tid  = threadIdx.x;
    const int row0 = blockIdx.x * 16;
    __shared__ float sX1[16][130];
    __shared__ float sX2[16][130];
    for (int i = tid; i < 16 * 128; i += 256) {
        int r = i >> 7, c = i & 127;
        int gr = row0 + r;
        sX1[r][c] = (gr < M) ? X1[(size_t)gr * 128 + c] : 0.f;
        sX2[r][c] = (gr < M) ? X2[(size_t)gr * 128 + c] : 0.f;
    }
    __syncthreads();

    const int c4 = (tid & 31) * 4;
    const int rb = tid >> 5;
    float a0x=0,a0y=0,a0z=0,a0w=0, a1x=0,a1y=0,a1z=0,a1w=0;
    #pragma unroll 4
    for (int k = 0; k < 128; ++k) {
        const float4 w = *(const float4*)(W1 + (size_t)k * 128 + c4);
        const float x0 = sX1[rb][k];
        const float x1 = sX1[rb + 8][k];
        a0x = fmaf(x0, w.x, a0x); a0y = fmaf(x0, w.y, a0y);
        a0z = fmaf(x0, w.z, a0z); a0w = fmaf(x0, w.w, a0w);
        a1x = fmaf(x1, w.x, a1x); a1y = fmaf(x1, w.y, a1y);
        a1z = fmaf(x1, w.z, a1z); a1w = fmaf(x1, w.w, a1w);
    }
    #pragma unroll 4
    for (int k = 0; k < 128; ++k) {
        const float4 w = *(const float4*)(W2 + (size_t)k * 128 + c4);
        const float x0 = sX2[rb][k];
        const float x1 = sX2[rb + 8][k];
        a0x = fmaf(x0, w.x, a0x); a0y = fmaf(x0, w.y, a0y);
        a0z = fmaf(x0, w.z, a0z); a0w = fmaf(x0, w.w, a0w);
        a1x = fmaf(x1, w.x, a1x); a1y = fmaf(x1, w.y, a1y);
        a1z = fmaf(x1, w.z, a1z); a1w = fmaf(x1, w.w, a1w);
    }
    const float4 b = *(const float4*)(bias + c4);
    #pragma unroll
    for (int h = 0; h < 2; ++h) {
        const int rr = row0 + rb + (h ? 8 : 0);
        if (rr >= M) continue;
        float4 o;
        o.x = fmaxf((h?a1x:a0x) + b.x, 0.f);
        o.y = fmaxf((h?a1y:a0y) + b.y, 0.f);
        o.z = fmaxf((h?a1z:a0z) + b.z, 0.f);
        o.w = fmaxf((h?a1w:a0w) + b.w, 0.f);
        *(float4*)(Y + (size_t)rr * 128 + c4) = o;
    }
}

// ---------------- MFMA dual flow GEMM: both outputs bf16, no bias ----------------
// Operands swapped (mfma(b, a) == D^T) so each lane's 4 acc regs are 4 CONSECUTIVE
// output columns -> 8 ushort4 stores/lane epilogue.
typedef __attribute__((ext_vector_type(8))) short bfrag;
typedef __attribute__((ext_vector_type(4))) float f32x4;

__global__ __launch_bounds__(256) void k_gemm_mfma(
    const unsigned short* __restrict__ Abf, const unsigned short* __restrict__ WBT,
    unsigned short* __restrict__ Y1, unsigned short* __restrict__ Y2, int M)
{
    const int tid  = threadIdx.x;
    const int wave = tid >> 6;
    const int lane = tid & 63;
    const int quad = lane >> 4;
    const int l16  = lane & 15;
    const int m0   = blockIdx.x * 32;

    __shared__ unsigned short sA[32 * 128];   // 8 KB, XOR-swizzled 16B units

    {
        const uint4* gsrc = (const uint4*)(Abf + (size_t)m0 * 128);
        uint4* sdst = (uint4*)sA;
        #pragma unroll
        for (int p = 0; p < 2; ++p) {
            int g = tid + p * 256;
            int row = g >> 4, u = g & 15;
            sdst[row * 16 + (u ^ (row & 15))] = gsrc[g];
        }
    }
    __syncthreads();

    f32x4 acc[2][4] = {};
    const int nbase = wave * 64;

    #pragma unroll
    for (int c = 0; c < 4; ++c) {
        const int un = (c * 4 + quad) ^ l16;
        bfrag a0 = *(const bfrag*)(sA + ((size_t)(l16)      * 128 + un * 8));
        bfrag a1 = *(const bfrag*)(sA + ((size_t)(16 + l16) * 128 + un * 8));
        #pragma unroll
        for (int j = 0; j < 4; ++j) {
            const bfrag b = *(const bfrag*)(WBT + (size_t)(nbase + j * 16 + l16) * 128
                                                 + c * 32 + quad * 8);
            acc[0][j] = __builtin_amdgcn_mfma_f32_16x16x32_bf16(b, a0, acc[0][j], 0, 0, 0);
            acc[1][j] = __builtin_amdgcn_mfma_f32_16x16x32_bf16(b, a1, acc[1][j], 0, 0, 0);
        }
    }

    unsigned short* Yd = (nbase < 128) ? Y1 : Y2;
    const int colb = nbase & 127;
    #pragma unroll
    for (int i = 0; i < 2; ++i) {
        const int row = m0 + i * 16 + l16;
        #pragma unroll
        for (int j = 0; j < 4; ++j) {
            const int col = colb + j * 16 + quad * 4;
            ushort4 o;
            o.x = f2bf(acc[i][j][0]); o.y = f2bf(acc[i][j][1]);
            o.z = f2bf(acc[i][j][2]); o.w = f2bf(acc[i][j][3]);
            *(ushort4*)(Yd + (size_t)row * 128 + col) = o;
        }
    }
}

// ---------------- combined CSR gather-aggregation (flow dsts) ----------------
// ONE merged CSR (rel + h2f): removes a full dependent ei->gather chain per wave.
// 4-way edge split: quarter q owns edges e = b0+q, b0+q+4, ...; each lane gathers
// uint4 = 8 bf16, so ONE wave gather instruction fetches 4 edge rows (1 KiB).
// Cross-quarter combine: shfl_xor 16 then 32; quarter 0 adds root+bias, stores.
__global__ __launch_bounds__(256) void k_agg_flow(
    const unsigned short* __restrict__ Z,
    const int* __restrict__ rp, const int* __restrict__ ei,
    const unsigned short* __restrict__ root, const float* __restrict__ bias,
    unsigned short* __restrict__ Xout, int do_relu)
{
    const int wave = threadIdx.x >> 6;
    const int lane = threadIdx.x & 63;
    const int q    = lane >> 4;          // 4-way edge parity
    const int l16  = lane & 15;
    const int d = blockIdx.x * 4 + wave;
    const int f8 = l16 * 8;              // 8 features per lane

    const int b0 = rp[d], b1 = rp[d + 1];

    uint4  rv  = {0, 0, 0, 0};
    float4 bva = {0.f, 0.f, 0.f, 0.f}, bvb = {0.f, 0.f, 0.f, 0.f};
    if (q == 0) {
        rv  = *(const uint4*)(root + (size_t)d * 128 + f8);
        bva = *(const float4*)(bias + f8);
        bvb = *(const float4*)(bias + f8 + 4);
    }

    float a[8] = {0.f, 0.f, 0.f, 0.f, 0.f, 0.f, 0.f, 0.f};

    int rem = b1 - b0 - q;
    int cnt = (rem > 0) ? ((rem + 3) >> 2) : 0;
    int e = b0 + q;
    while (cnt >= 2) {
        const int s0 = ei[e];
        const int s1 = ei[e + 4];
        const uint4 z0 = *(const uint4*)(Z + (size_t)s0 * 128 + f8);
        const uint4 z1 = *(const uint4*)(Z + (size_t)s1 * 128 + f8);
        acc8(a, z0);
        acc8(a, z1);
        e += 8; cnt -= 2;
    }
    if (cnt) {
        const int s0 = ei[e];
        const uint4 z0 = *(const uint4*)(Z + (size_t)s0 * 128 + f8);
        acc8(a, z0);
    }

    #pragma unroll
    for (int j = 0; j < 8; ++j) {
        a[j] += __shfl_xor(a[j], 16, 64);
        a[j] += __shfl_xor(a[j], 32, 64);
    }

    if (q == 0) {
        float v0 = a[0] + __uint_as_float(rv.x << 16)         + bva.x;
        float v1 = a[1] + __uint_as_float(rv.x & 0xFFFF0000u) + bva.y;
        float v2 = a[2] + __uint_as_float(rv.y << 16)         + bva.z;
        float v3 = a[3] + __uint_as_float(rv.y & 0xFFFF0000u) + bva.w;
        float v4 = a[4] + __uint_as_float(rv.z << 16)         + bvb.x;
        float v5 = a[5] + __uint_as_float(rv.z & 0xFFFF0000u) + bvb.y;
        float v6 = a[6] + __uint_as_float(rv.w << 16)         + bvb.z;
        float v7 = a[7] + __uint_as_float(rv.w & 0xFFFF0000u) + bvb.w;
        if (do_relu) {
            v0 = fmaxf(v0, 0.f); v1 = fmaxf(v1, 0.f); v2 = fmaxf(v2, 0.f); v3 = fmaxf(v3, 0.f);
            v4 = fmaxf(v4, 0.f); v5 = fmaxf(v5, 0.f); v6 = fmaxf(v6, 0.f); v7 = fmaxf(v7, 0.f);
        }
        uint4 o;
        o.x = (unsigned)f2bf(v0) | ((unsigned)f2bf(v1) << 16);
        o.y = (unsigned)f2bf(v2) | ((unsigned)f2bf(v3) << 16);
        o.z = (unsigned)f2bf(v4) | ((unsigned)f2bf(v5) << 16);
        o.w = (unsigned)f2bf(v6) | ((unsigned)f2bf(v7) << 16);
        *(uint4*)(Xout + (size_t)d * 128 + f8) = o;
    }
}

// host dst: out[d][0:128] = sum f2h Z[src][0:128]  (f32 out)
// Same 4-way-split structure, 4 dsts/block, uint4 gathers.
__global__ __launch_bounds__(256) void k_agg_host(
    const unsigned short* __restrict__ Z, const int* __restrict__ rp,
    const int* __restrict__ ei, float* __restrict__ out)
{
    const int wave = threadIdx.x >> 6;
    const int lane = threadIdx.x & 63;
    const int q    = lane >> 4;
    const int l16  = lane & 15;
    const int d = blockIdx.x * 4 + wave;
    const int f8 = l16 * 8;

    const int b0 = rp[d], b1 = rp[d + 1];

    float a[8] = {0.f, 0.f, 0.f, 0.f, 0.f, 0.f, 0.f, 0.f};
    int rem = b1 - b0 - q;
    int cnt = (rem > 0) ? ((rem + 3) >> 2) : 0;
    int e = b0 + q;
    while (cnt >= 2) {
        const int s0 = ei[e];
        const int s1 = ei[e + 4];
        const uint4 z0 = *(const uint4*)(Z + (size_t)s0 * 128 + f8);
        const uint4 z1 = *(const uint4*)(Z + (size_t)s1 * 128 + f8);
        acc8(a, z0);
        acc8(a, z1);
        e += 8; cnt -= 2;
    }
    if (cnt) {
        const int s0 = ei[e];
        const uint4 z0 = *(const uint4*)(Z + (size_t)s0 * 128 + f8);
        acc8(a, z0);
    }

    #pragma unroll
    for (int j = 0; j < 8; ++j) {
        a[j] += __shfl_xor(a[j], 16, 64);
        a[j] += __shfl_xor(a[j], 32, 64);
    }

    if (q == 0) {
        float4 oa, ob;
        oa.x = a[0]; oa.y = a[1]; oa.z = a[2]; oa.w = a[3];
        ob.x = a[4]; ob.y = a[5]; ob.z = a[6]; ob.w = a[7];
        *(float4*)(out + (size_t)d * 128 + f8)     = oa;
        *(float4*)(out + (size_t)d * 128 + f8 + 4) = ob;
    }
}

// ---------------- pooling over sorted batch (bf16 input) ----------------
#define PCHUNK 128
__global__ __launch_bounds__(128) void k_pool2(const unsigned short* xf, const int* batch,
                                               unsigned* bits){
    const int t = threadIdx.x;
    const int i0 = blockIdx.x * PCHUNK;
    const int iend = min(i0 + PCHUNK, N_FLOWN);
    if (i0 >= N_FLOWN) return;
    float cur = -3.4e38f;
    int curg = batch[i0];
    for (int i = i0; i < iend; ++i) {
        int g = batch[i];
        if (g != curg) {
            unsigned u = __float_as_uint(cur);
            unsigned ord = (u & 0x80000000u) ? ~u : (u | 0x80000000u);
            atomicMax(&bits[(size_t)curg * 128 + t], ord);
            cur = -3.4e38f; curg = g;
        }
        cur = fmaxf(cur, bf2f(xf[(size_t)i * 128 + t]));
    }
    unsigned u = __float_as_uint(cur);
    unsigned ord = (u & 0x80000000u) ? ~u : (u | 0x80000000u);
    atomicMax(&bits[(size_t)curg * 128 + t], ord);
}

// ---------------- classifier ----------------
__global__ __launch_bounds__(128) void k_classifier(
    const unsigned* bits,
    const void* Wc1, const void* bc1, const void* Wc2, const void* bc2,
    const void* Wc3, const void* bc3, void* out, const int* flagp)
{
    const int g = blockIdx.x, t = threadIdx.x;
    const int isbf = *flagp;
    __shared__ float sp[128], sh1[64], sh2[128];
    {
        unsigned ord = bits[(size_t)g * HH + t];
        unsigned u = (ord & 0x80000000u) ? (ord & 0x7FFFFFFFu) : ~ord;
        sp[t] = __uint_as_float(u);
    }
    __syncthreads();
    if (t < 64) {
        float a = loadf(bc1, t, isbf);
        #pragma unroll 4
        for (int k = 0; k < 128; ++k) a = fmaf(sp[k], loadf(Wc1, k * 64 + t, isbf), a);
        sh1[t] = fmaxf(a, 0.f);
    }
    __syncthreads();
    {
        float a = loadf(bc2, t, isbf);
        #pragma unroll 4
        for (int k = 0; k < 64; ++k) a = fmaf(sh1[k], loadf(Wc2, k * 128 + t, isbf), a);
        sh2[t] = fmaxf(a, 0.f);
    }
    __syncthreads();
    if (t < NCN) {
        float a = loadf(bc3, t, isbf);
        #pragma unroll 4
        for (int k = 0; k < 128; ++k) a = fmaf(sh2[k], loadf(Wc3, k * NCN + t, isbf), a);
        if (isbf) ((unsigned short*)out)[(size_t)g * NCN + t] = f2bf(a);
        else      ((float*)out)[(size_t)g * NCN + t] = a;
    }
}

extern "C" void kernel_launch(void* const* d_in, const int* in_sizes, int n_in,
                              void* d_out, int out_size, void* d_ws, size_t ws_size,
                              hipStream_t stream)
{
    const int*  host_ids   = (const int*) d_in[0];
    const void* flow_x     = d_in[1];
    const int*  h2f_src    = (const int*) d_in[2];
    const int*  h2f_dst    = (const int*) d_in[3];
    const int*  f2h_src    = (const int*) d_in[4];
    const int*  f2h_dst    = (const int*) d_in[5];
    const int*  rel_src    = (const int*) d_in[6];
    const int*  rel_dst    = (const int*) d_in[7];
    const int*  flow_batch = (const int*) d_in[8];
    const void* host_embed = d_in[9];
    const void* Wr0_h2f = d_in[10]; const void* br0_h2f = d_in[11]; const void* Wo0_h2f = d_in[12];
    const void* Wr0_f2h = d_in[13]; const void* br0_f2h = d_in[14]; const void* Wo0_f2h = d_in[15];
    const void* Wr0_rel = d_in[16]; const void* br0_rel = d_in[17]; const void* Wo0_rel = d_in[18];
    const void* Wr_all  = d_in[19];
    const void* br_all  = d_in[20];
    const void* Wo_all  = d_in[21];
    const void* Wc1 = d_in[22]; const void* bc1 = d_in[23];
    const void* Wc2 = d_in[24]; const void* bc2 = d_in[25];
    const void* Wc3 = d_in[26]; const void* bc3 = d_in[27];

    // -------- workspace (~199 MB) --------
    size_t off = 0;
    auto alloc = [&](size_t bytes) -> char* {
        char* p = (char*)d_ws + off;
        off += (bytes + 255) & ~(size_t)255;
        return p;
    };
    unsigned short* F1bf  = (unsigned short*)alloc((size_t)N_FLOWN * HH * 2);  // state
    unsigned short* Froot = (unsigned short*)alloc((size_t)N_FLOWN * HH * 2);  // root term
    // ZALL: flow-transformed rows [0,200k) followed by host-transformed rows [200k,220k)
    unsigned short* ZALL  = (unsigned short*)alloc((size_t)(N_FLOWN + N_HOSTN) * HH * 2);
    unsigned short* F2bf  = ZALL;                                   // z_rel
    unsigned short* HCbf  = ZALL + (size_t)N_FLOWN * HH;            // z_h
    float* HA = (float*)alloc((size_t)N_HOSTN * HH * 4);
    float* HB = (float*)alloc((size_t)N_HOSTN * HH * 4);
    float* HD = (float*)alloc((size_t)N_HOSTN * HH * 4);
    unsigned short* WBT0 = (unsigned short*)alloc(256 * 128 * 2);
    unsigned short* WBT1 = (unsigned short*)alloc(256 * 128 * 2);
    unsigned short* WBT2 = (unsigned short*)alloc(256 * 128 * 2);
    float* w_h2f0  = (float*)alloc(128 * 128 * 4);
    float* w_h2f1  = (float*)alloc(128 * 128 * 4);
    float* w_h2f2  = (float*)alloc(128 * 128 * 4);
    float* w_f2h0  = (float*)alloc(128 * 128 * 4);
    float* w_f2h1  = (float*)alloc(128 * 128 * 4);
    float* w_of2h0 = (float*)alloc(128 * 128 * 4);
    float* w_of2h1 = (float*)alloc(128 * 128 * 4);
    float* b_comb0 = (float*)alloc(128 * 4);
    float* b_comb1 = (float*)alloc(128 * 4);
    float* b_comb2 = (float*)alloc(128 * 4);
    float* b_f2h0  = (float*)alloc(128 * 4);
    float* b_f2h1  = (float*)alloc(128 * 4);
    unsigned* poolbits = (unsigned*)alloc(GG * HH * 4);
    int* flagp = (int*)alloc(256);
    int* rp_cmb = (int*)alloc((N_FLOWN + 1) * 4);
    int* ei_cmb = (int*)alloc((size_t)E_CMBN * 4);
    int* rp_f2h = (int*)alloc((N_HOSTN + 1) * 4);
    int* ei_f2h = (int*)alloc((size_t)E_HFN * 4);
    int* wr_cmb = (int*)alloc((size_t)N_FLOWN * 4);
    int* wr_f2h = (int*)alloc((size_t)N_HOSTN * 4);
    int* bs0 = (int*)alloc(1024 * 4);
    int* bs2 = (int*)alloc(256 * 4);

    const int T = 256;
    #define GRID1(n) dim3(cdiv((long long)(n), T)), dim3(T), 0, stream

    if (off > ws_size) {
        k_flag_us<<<GRID1(out_size)>>>((unsigned short*)d_out, out_size, (unsigned short)0x4000);
        return;
    }

    k_detect<<<dim3(1), dim3(256), 0, stream>>>((const unsigned short*)flow_x, flagp);

    // -------- CSR builds (combined flow CSR + f2h CSR) --------
    k_zero2 <<<dim3(NB_CMB_N + NB_F2H_N), dim3(256), 0, stream>>>(wr_cmb, wr_f2h);
    k_hist3 <<<dim3(NB_REL_E + 2*NB_HF_E), dim3(256), 0, stream>>>(rel_dst, h2f_dst, f2h_dst,
                                                                    wr_cmb, wr_f2h);
    k_scan1_2<<<dim3(NB_CMB_N + NB_F2H_N), dim3(256), 0, stream>>>(
        wr_cmb, rp_cmb, bs0, wr_f2h, rp_f2h, bs2);
    k_scan2_2<<<dim3(2), dim3(256), 0, stream>>>(bs0, bs2);
    k_scan3_2<<<dim3(NB_CMB_N + NB_F2H_N), dim3(256), 0, stream>>>(
        rp_cmb, bs0, wr_cmb, rp_f2h, bs2, wr_f2h);
    k_place3c<<<dim3(PLC_ALL), dim3(256), 0, stream>>>(
        rel_src, rel_dst, h2f_src, h2f_dst, f2h_src, f2h_dst,
        wr_cmb, ei_cmb, wr_f2h, ei_f2h);

    // -------- weight prep (1 launch) --------
    k_wprep_all<<<dim3(833), dim3(256), 0, stream>>>(
        Wr0_h2f, br0_h2f, Wo0_h2f, Wr0_f2h, br0_f2h, Wo0_f2h, Wr0_rel, br0_rel, Wo0_rel,
        Wr_all, br_all, Wo_all,
        WBT0, WBT1, WBT2, w_h2f0, w_h2f1, w_h2f2,
        w_f2h0, w_f2h1, w_of2h0, w_of2h1,
        b_comb0, b_comb1, b_comb2, b_f2h0, b_f2h1, flagp);

    // ================= layer 0 =================
    k_gather_embed<<<GRID1(N_HOSTN * HH)>>>(host_ids, host_embed, HA, flagp);
    k_pad_cast<<<GRID1((size_t)N_FLOWN * 128)>>>(flow_x, F1bf, flagp);
    // host path: gather bf16 input features (K padded to 128); fused dual GEMM + relu
    k_agg_host<<<dim3(N_HOSTN/4), dim3(256), 0, stream>>>(F1bf, rp_f2h, ei_f2h, HD);
    k_gemm2in<<<dim3(cdiv(N_HOSTN,16)), dim3(256), 0, stream>>>(HD, HA, w_f2h0, w_of2h0, b_f2h0, HB, N_HOSTN);
    // flow path
    k_gemm128<<<dim3(cdiv(N_HOSTN,16)), dim3(256), 0, stream>>>(HA, 0, w_h2f0, nullptr, HCbf, 1, N_HOSTN, 128, 0, 0, flagp);
    k_gemm_mfma<<<dim3(N_FLOWN/32), dim3(256), 0, stream>>>(F1bf, WBT0, Froot, F2bf, N_FLOWN);
    k_agg_flow<<<dim3(N_FLOWN/4), dim3(256), 0, stream>>>(ZALL, rp_cmb, ei_cmb,
                                                          Froot, b_comb0, F1bf, 1);

    // ================= stacked layer 0 =================
    k_agg_host<<<dim3(N_HOSTN/4), dim3(256), 0, stream>>>(F1bf, rp_f2h, ei_f2h, HD);
    k_gemm128<<<dim3(cdiv(N_HOSTN,16)), dim3(256), 0, stream>>>(HB, 0, w_h2f1, nullptr, HCbf, 1, N_HOSTN, 128, 0, 0, flagp);
    k_gemm_mfma<<<dim3(N_FLOWN/32), dim3(256), 0, stream>>>(F1bf, WBT1, Froot, F2bf, N_FLOWN);
    k_agg_flow<<<dim3(N_FLOWN/4), dim3(256), 0, stream>>>(ZALL, rp_cmb, ei_cmb,
                                                          Froot, b_comb1, F1bf, 1);
    k_gemm2in<<<dim3(cdiv(N_HOSTN,16)), dim3(256), 0, stream>>>(HD, HB, w_f2h1, w_of2h1, b_f2h1, HA, N_HOSTN);

    // ================= stacked layer 1 (last; no host update, no relu) =================
    k_gemm128<<<dim3(cdiv(N_HOSTN,16)), dim3(256), 0, stream>>>(HA, 0, w_h2f2, nullptr, HCbf, 1, N_HOSTN, 128, 0, 0, flagp);
    k_gemm_mfma<<<dim3(N_FLOWN/32), dim3(256), 0, stream>>>(F1bf, WBT2, Froot, F2bf, N_FLOWN);
    k_agg_flow<<<dim3(N_FLOWN/4), dim3(256), 0, stream>>>(ZALL, rp_cmb, ei_cmb,
                                                          Froot, b_comb2, F1bf, 0);

    // ================= pool + classifier =================
    k_zero<<<GRID1(GG * HH)>>>((float*)poolbits, (size_t)GG * HH);
    k_pool2<<<dim3(cdiv(N_FLOWN, PCHUNK)), dim3(128), 0, stream>>>(F1bf, flow_batch, poolbits);
    k_classifier<<<dim3(GG), dim3(128), 0, stream>>>(poolbits, Wc1, bc1, Wc2, bc2, Wc3, bc3,
                                                     d_out, flagp);
    #undef GRID1
}

// Round 3
// 1118.632 us; speedup vs baseline: 1.0610x; 1.0201x over previous
//
#include <hip/hip_runtime.h>
#include <hip/hip_bf16.h>

using bf16 = __hip_bfloat16;

#define N_HOSTN 20000
#define N_FLOWN 200000
#define E_HFN   400000
#define E_RELN  800000
#define E_CMBN  1200000  // rel + h2f combined
#define GG      64
#define HH      128
#define FIN     97
#define NCN     10

// CSR region block counts (256 threads/block)
#define NB_REL_E 3125   // 800000/256
#define NB_HF_E  1563   // ceil(400000/256)
#define NB_CMB_N 782    // ceil(200000/256)
#define NB_F2H_N 79     // ceil(20000/256)
// class-partitioned placement: 2048-edge chunks x 8 classes
#define NCH_REL 391     // ceil(800000/2048)
#define NCH_HF  196     // ceil(400000/2048)
#define PLC_REL (NCH_REL*8)            // 3128
#define PLC_H2F (PLC_REL + NCH_HF*8)   // 4696
#define PLC_ALL (PLC_H2F + NCH_HF*8)   // 6264

// persistent-wave aggregation geometry
#define AGG_CAP    768   // staged indices per wave (fallback to global beyond)
#define AGGF_BLK   2048  // 8192 waves * 25 dsts >= 200000
#define AGGF_DPW   25
#define AGGH_BLK   512   // 2048 waves * 10 dsts >= 20000
#define AGGH_DPW   10

static inline int cdiv(long long a, long long b){ return (int)((a + b - 1) / b); }

__device__ __forceinline__ float bf2f(unsigned short u){
    return __uint_as_float(((unsigned)u) << 16);
}
__device__ __forceinline__ unsigned short f2bf(float f){
    unsigned u = __float_as_uint(f);
    unsigned r = u + 0x7FFFu + ((u >> 16) & 1u);   // RNE
    return (unsigned short)(r >> 16);
}
__device__ __forceinline__ float loadf(const void* p, size_t i, int isbf){
    return isbf ? bf2f(((const unsigned short*)p)[i]) : ((const float*)p)[i];
}
// unpack 8 bf16 (uint4) and accumulate into 8 f32
__device__ __forceinline__ void acc8(float* a, uint4 z){
    a[0] += __uint_as_float(z.x << 16);
    a[1] += __uint_as_float(z.x & 0xFFFF0000u);
    a[2] += __uint_as_float(z.y << 16);
    a[3] += __uint_as_float(z.y & 0xFFFF0000u);
    a[4] += __uint_as_float(z.z << 16);
    a[5] += __uint_as_float(z.z & 0xFFFF0000u);
    a[6] += __uint_as_float(z.w << 16);
    a[7] += __uint_as_float(z.w & 0xFFFF0000u);
}

// ---------------- dtype detection ----------------
__global__ void k_detect(const unsigned short* x, int* flag){
    __shared__ int bad;
    if (threadIdx.x == 0) bad = 0;
    __syncthreads();
    int b = 0;
    for (int i = threadIdx.x; i < 4096; i += 256) {
        unsigned e = (x[i] >> 7) & 0xFFu;
        if (e >= 0x90u) b++;
    }
    if (b) atomicAdd(&bad, b);
    __syncthreads();
    if (threadIdx.x == 0) *flag = (bad == 0) ? 1 : 0;   // 1 = bf16, 0 = f32
}

// ---------------- misc ----------------
__global__ void k_zero(float* p, size_t n){
    size_t i = (size_t)blockIdx.x * 256 + threadIdx.x;
    if (i < n) p[i] = 0.f;
}
__global__ void k_flag_us(unsigned short* out, int n, unsigned short val){
    int i = blockIdx.x * 256 + threadIdx.x;
    if (i < n) out[i] = val;
}
__global__ void k_gather_embed(const int* ids, const void* emb, float* out, const int* flagp){
    int i = blockIdx.x * 256 + threadIdx.x;
    if (i >= N_HOSTN * HH) return;
    int isbf = *flagp;
    int node = i >> 7, f = i & 127;
    out[i] = loadf(emb, (size_t)ids[node] * HH + f, isbf);
}
// flow_x [N,97] (flag dtype) -> bf16 padded [N,128]
__global__ void k_pad_cast(const void* x, unsigned short* o, const int* flagp){
    size_t i = (size_t)blockIdx.x * 256 + threadIdx.x;
    if (i >= (size_t)N_FLOWN * 128) return;
    int isbf = *flagp;
    int row = (int)(i >> 7), c = (int)i & 127;
    o[i] = (c < FIN) ? f2bf(loadf(x, (size_t)row * FIN + c, isbf)) : (unsigned short)0;
}

// ---------------- one-shot weight prep (833 blocks, region dispatch) ----------------
__global__ __launch_bounds__(256) void k_wprep_all(
    const void* Wr0_h2f, const void* br0_h2f, const void* Wo0_h2f,
    const void* Wr0_f2h, const void* br0_f2h, const void* Wo0_f2h,
    const void* Wr0_rel, const void* br0_rel, const void* Wo0_rel,
    const void* Wr_all, const void* br_all, const void* Wo_all,
    unsigned short* WBT0, unsigned short* WBT1, unsigned short* WBT2,
    float* w_h2f0, float* w_h2f1, float* w_h2f2,
    float* w_f2h0, float* w_f2h1, float* w_of2h0, float* w_of2h1,
    float* b_comb0, float* b_comb1, float* b_comb2, float* b_f2h0, float* b_f2h1,
    const int* flagp)
{
    const int bb = blockIdx.x, t = threadIdx.x;
    const int isbf = *flagp;
    if (bb < 384) {
        int layer = bb >> 7;
        int i = ((bb & 127) << 8) + t;   // 0..32767
        int nn = i >> 7, k = i & 127;
        float v = 0.f;
        if (layer == 0) {
            if (k < FIN) {
                if (nn < 128) v = loadf(Wo0_h2f, (size_t)k*128+nn, isbf) + loadf(Wo0_rel, (size_t)k*128+nn, isbf);
                else          v = loadf(Wr0_rel, (size_t)k*128+(nn-128), isbf);
            }
        } else {
            size_t oW = (size_t)((layer - 1) * 3) * 16384;
            if (nn < 128) v = loadf(Wo_all, oW + (size_t)k*128+nn, isbf)
                            + loadf(Wo_all, oW + 2*16384 + (size_t)k*128+nn, isbf);
            else          v = loadf(Wr_all, oW + 2*16384 + (size_t)k*128+(nn-128), isbf);
        }
        unsigned short* W = (layer == 0) ? WBT0 : ((layer == 1) ? WBT1 : WBT2);
        W[(size_t)nn*128 + k] = f2bf(v);
    } else if (bb < 576) {
        int r = bb - 384; int layer = r >> 6; int i = ((r & 63) << 8) + t;
        float v;
        if (layer == 0) v = loadf(Wr0_h2f, (size_t)i, isbf);
        else            v = loadf(Wr_all, (size_t)((layer-1)*3)*16384 + i, isbf);
        ((layer == 0) ? w_h2f0 : ((layer == 1) ? w_h2f1 : w_h2f2))[i] = v;
    } else if (bb < 640) {
        // w_f2h0 padded to [128][128]: rows k>=97 zero
        int i = ((bb - 576) << 8) + t;
        int k = i >> 7;
        w_f2h0[i] = (k < FIN) ? loadf(Wr0_f2h, (size_t)i, isbf) : 0.f;
    } else if (bb < 704) {
        int i = ((bb - 640) << 8) + t;
        w_f2h1[i] = loadf(Wr_all, (size_t)1*16384 + i, isbf);
    } else if (bb < 768) {
        int i = ((bb - 704) << 8) + t;
        w_of2h0[i] = loadf(Wo0_f2h, (size_t)i, isbf);
    } else if (bb < 832) {
        int i = ((bb - 768) << 8) + t;
        w_of2h1[i] = loadf(Wo_all, (size_t)1*16384 + i, isbf);
    } else {
        if (t < 128) {
            b_comb0[t] = loadf(br0_h2f, t, isbf) + loadf(br0_rel, t, isbf);
            b_comb1[t] = loadf(br_all, 0*128 + t, isbf) + loadf(br_all, 2*128 + t, isbf);
            b_comb2[t] = loadf(br_all, 3*128 + t, isbf) + loadf(br_all, 5*128 + t, isbf);
            b_f2h0[t]  = loadf(br0_f2h, t, isbf);
            b_f2h1[t]  = loadf(br_all, 1*128 + t, isbf);
        }
    }
}

// ---------------- CSR build (combined flow CSR + f2h CSR) ----------------
__global__ void k_zero2(int* c0, int* c1){
    int bb = blockIdx.x, t = threadIdx.x;
    if (bb < NB_CMB_N) { int i = bb * 256 + t; if (i < N_FLOWN) c0[i] = 0; }
    else               { int i = (bb - NB_CMB_N) * 256 + t; if (i < N_HOSTN) c1[i] = 0; }
}
// rel and h2f edges both count into c_cmb; f2h into c_f2h
__global__ void k_hist3(const int* drel, const int* dh2f, const int* df2h,
                        int* c_cmb, int* c_f2h){
    int bb = blockIdx.x, t = threadIdx.x;
    const int* dst; int* cnt; int E; int base;
    if (bb < NB_REL_E)                   { dst = drel; cnt = c_cmb; E = E_RELN; base = bb; }
    else if (bb < NB_REL_E + NB_HF_E)    { dst = dh2f; cnt = c_cmb; E = E_HFN;  base = bb - NB_REL_E; }
    else                                 { dst = df2h; cnt = c_f2h; E = E_HFN;  base = bb - NB_REL_E - NB_HF_E; }
    int e = base * 256 + t;
    if (e < E) atomicAdd(&cnt[dst[e]], 1);
}
__global__ __launch_bounds__(256) void k_scan1_2(
    const int* c0, int* rp0, int* bs0,
    const int* c1, int* rp1, int* bs1)
{
    __shared__ int s[256];
    int bb = blockIdx.x, t = threadIdx.x;
    const int* cnt; int* rp; int* bsum; int n; int base;
    if (bb < NB_CMB_N) { cnt = c0; rp = rp0; bsum = bs0; n = N_FLOWN; base = bb; }
    else               { cnt = c1; rp = rp1; bsum = bs1; n = N_HOSTN; base = bb - NB_CMB_N; }
    int i = base * 256 + t;
    int v = (i < n) ? cnt[i] : 0;
    s[t] = v; __syncthreads();
    for (int off = 1; off < 256; off <<= 1) {
        int x = (t >= off) ? s[t - off] : 0;
        __syncthreads();
        s[t] += x;
        __syncthreads();
    }
    if (i < n) rp[i] = s[t] - v;
    if (t == 255) bsum[base] = s[255];
}
__global__ __launch_bounds__(256) void k_scan2_2(int* bs0, int* bs1){
    __shared__ int s[256];
    __shared__ int carry;
    int t = threadIdx.x;
    int* bsum; int nb;
    if (blockIdx.x == 0) { bsum = bs0; nb = NB_CMB_N; }
    else                 { bsum = bs1; nb = NB_F2H_N; }
    if (t == 0) carry = 0;
    __syncthreads();
    for (int base = 0; base < nb; base += 256) {
        int i = base + t;
        int v = (i < nb) ? bsum[i] : 0;
        s[t] = v; __syncthreads();
        for (int off = 1; off < 256; off <<= 1) {
            int x = (t >= off) ? s[t - off] : 0;
            __syncthreads();
            s[t] += x;
            __syncthreads();
        }
        int excl = s[t] - v + carry;
        if (i < nb) bsum[i] = excl;
        __syncthreads();
        if (t == 255) carry += s[255];
        __syncthreads();
    }
}
__global__ void k_scan3_2(int* rp0, const int* bs0, int* w0,
                          int* rp1, const int* bs1, int* w1)
{
    int bb = blockIdx.x, t = threadIdx.x;
    int* rp; const int* bsum; int* wr; int n, E, base;
    if (bb < NB_CMB_N) { rp = rp0; bsum = bs0; wr = w0; n = N_FLOWN; E = E_CMBN; base = bb; }
    else               { rp = rp1; bsum = bs1; wr = w1; n = N_HOSTN; E = E_HFN;  base = bb - NB_CMB_N; }
    int i = base * 256 + t;
    if (i < n) { int v = rp[i] + bsum[base]; rp[i] = v; wr[i] = v; }
    if (i == 0) rp[n] = E;
}
// class-partitioned placement: class = blockIdx%8 (round-robins onto XCDs);
// rel + h2f both place into the combined flow CSR; h2f srcs get +N_FLOWN so
// the gather reads the host rows appended after the flow rows in ZALL.
__global__ __launch_bounds__(256) void k_place3c(
    const int* s0, const int* d0,
    const int* s1, const int* d1,
    const int* s2, const int* d2,
    int* w_cmb, int* e_cmb, int* w_f2h, int* e_f2h)
{
    const int bb = blockIdx.x;
    const int *src, *dst; int *wr, *ei; int E, divc, rb, soff;
    if (bb < PLC_REL)      { src=s0; dst=d0; wr=w_cmb; ei=e_cmb; E=E_RELN; divc=25000; rb=bb;          soff=0; }
    else if (bb < PLC_H2F) { src=s1; dst=d1; wr=w_cmb; ei=e_cmb; E=E_HFN;  divc=25000; rb=bb-PLC_REL;  soff=N_FLOWN; }
    else                   { src=s2; dst=d2; wr=w_f2h; ei=e_f2h; E=E_HFN;  divc=2500;  rb=bb-PLC_H2F;  soff=0; }
    const int cls  = rb & 7;
    const int base = (rb >> 3) * 2048;
    const int t = threadIdx.x;
    #pragma unroll
    for (int i = 0; i < 8; ++i) {
        const int e = base + t + i * 256;
        if (e < E) {
            const int d = dst[e];
            if (d / divc == cls) {
                const int pos = atomicAdd(&wr[d], 1);
                ei[pos] = src[e] + soff;
            }
        }
    }
}

// ---------------- host-sized VALU GEMM: Y[M,128] (+)= X[M,K]@W[K,128]+b ---------
__global__ __launch_bounds__(256) void k_gemm128(
    const void* X, int xmode, const float* W, const float* bias,
    void* Y, int ybf, int M, int K, int accum, int dorelu, const int* flagp)
{
    const int isbf = (xmode == 2) ? *flagp : xmode;
    const int tid  = threadIdx.x;
    const int row0 = blockIdx.x * 16;
    __shared__ float sX[16][130];
    const int total = 16 * K;
    for (int i = tid; i < total; i += 256) {
        int r = i / K, c = i - r * K;
        int gr = row0 + r;
        sX[r][c] = (gr < M) ? loadf(X, (size_t)gr * K + c, isbf) : 0.f;
    }
    __syncthreads();

    const int c4 = (tid & 31) * 4;
    const int rb = tid >> 5;
    float a0x=0,a0y=0,a0z=0,a0w=0, a1x=0,a1y=0,a1z=0,a1w=0;
    #pragma unroll 4
    for (int k = 0; k < K; ++k) {
        const float4 w = *(const float4*)(W + (size_t)k * 128 + c4);
        const float x0 = sX[rb][k];
        const float x1 = sX[rb + 8][k];
        a0x = fmaf(x0, w.x, a0x); a0y = fmaf(x0, w.y, a0y);
        a0z = fmaf(x0, w.z, a0z); a0w = fmaf(x0, w.w, a0w);
        a1x = fmaf(x1, w.x, a1x); a1y = fmaf(x1, w.y, a1y);
        a1z = fmaf(x1, w.z, a1z); a1w = fmaf(x1, w.w, a1w);
    }
    float bx=0, by=0, bz=0, bw=0;
    if (bias) { const float4 b = *(const float4*)(bias + c4); bx=b.x; by=b.y; bz=b.z; bw=b.w; }

    #pragma unroll
    for (int h = 0; h < 2; ++h) {
        const int rr = row0 + rb + (h ? 8 : 0);
        if (rr >= M) continue;
        float v0 = (h?a1x:a0x)+bx, v1 = (h?a1y:a0y)+by;
        float v2 = (h?a1z:a0z)+bz, v3 = (h?a1w:a0w)+bw;
        if (ybf) {
            unsigned short* p = (unsigned short*)Y + (size_t)rr * 128 + c4;
            ushort4 o; o.x=f2bf(v0); o.y=f2bf(v1); o.z=f2bf(v2); o.w=f2bf(v3);
            *(ushort4*)p = o;
        } else {
            float* p = (float*)Y + (size_t)rr * 128 + c4;
            if (accum) { v0+=p[0]; v1+=p[1]; v2+=p[2]; v3+=p[3]; }
            if (dorelu) { v0=fmaxf(v0,0.f); v1=fmaxf(v1,0.f); v2=fmaxf(v2,0.f); v3=fmaxf(v3,0.f); }
            float4 o; o.x=v0; o.y=v1; o.z=v2; o.w=v3;
            *(float4*)p = o;
        }
    }
}

// ---------------- fused dual-input host GEMM: Y = relu(X1@W1 + X2@W2 + b) ------
__global__ __launch_bounds__(256) void k_gemm2in(
    const float* __restrict__ X1, const float* __restrict__ X2,
    const float* __restrict__ W1, const float* __restrict__ W2,
    const float* __restrict__ bias, float* __restrict__ Y, int M)
{
    const int tid  = threadIdx.x;
    const int row0 = blockIdx.x * 16;
    __shared__ float sX1[16][130];
    __shared__ float sX2[16][130];
    for (int i = tid; i < 16 * 128; i += 256) {
        int r = i >> 7, c = i & 127;
        int gr = row0 + r;
        sX1[r][c] = (gr < M) ? X1[(size_t)gr * 128 + c] : 0.f;
        sX2[r][c] = (gr < M) ? X2[(size_t)gr * 128 + c] : 0.f;
    }
    __syncthreads();

    const int c4 = (tid & 31) * 4;
    const int rb = tid >> 5;
    float a0x=0,a0y=0,a0z=0,a0w=0, a1x=0,a1y=0,a1z=0,a1w=0;
    #pragma unroll 4
    for (int k = 0; k < 128; ++k) {
        const float4 w = *(const float4*)(W1 + (size_t)k * 128 + c4);
        const float x0 = sX1[rb][k];
        const float x1 = sX1[rb + 8][k];
        a0x = fmaf(x0, w.x, a0x); a0y = fmaf(x0, w.y, a0y);
        a0z = fmaf(x0, w.z, a0z); a0w = fmaf(x0, w.w, a0w);
        a1x = fmaf(x1, w.x, a1x); a1y = fmaf(x1, w.y, a1y);
        a1z = fmaf(x1, w.z, a1z); a1w = fmaf(x1, w.w, a1w);
    }
    #pragma unroll 4
    for (int k = 0; k < 128; ++k) {
        const float4 w = *(const float4*)(W2 + (size_t)k * 128 + c4);
        const float x0 = sX2[rb][k];
        const float x1 = sX2[rb + 8][k];
        a0x = fmaf(x0, w.x, a0x); a0y = fmaf(x0, w.y, a0y);
        a0z = fmaf(x0, w.z, a0z); a0w = fmaf(x0, w.w, a0w);
        a1x = fmaf(x1, w.x, a1x); a1y = fmaf(x1, w.y, a1y);
        a1z = fmaf(x1, w.z, a1z); a1w = fmaf(x1, w.w, a1w);
    }
    const float4 b = *(const float4*)(bias + c4);
    #pragma unroll
    for (int h = 0; h < 2; ++h) {
        const int rr = row0 + rb + (h ? 8 : 0);
        if (rr >= M) continue;
        float4 o;
        o.x = fmaxf((h?a1x:a0x) + b.x, 0.f);
        o.y = fmaxf((h?a1y:a0y) + b.y, 0.f);
        o.z = fmaxf((h?a1z:a0z) + b.z, 0.f);
        o.w = fmaxf((h?a1w:a0w) + b.w, 0.f);
        *(float4*)(Y + (size_t)rr * 128 + c4) = o;
    }
}

// ---------------- MFMA dual flow GEMM: both outputs bf16, no bias ----------------
// Operands swapped (mfma(b, a) == D^T) so each lane's 4 acc regs are 4 CONSECUTIVE
// output columns -> 8 ushort4 stores/lane epilogue.
typedef __attribute__((ext_vector_type(8))) short bfrag;
typedef __attribute__((ext_vector_type(4))) float f32x4;

__global__ __launch_bounds__(256) void k_gemm_mfma(
    const unsigned short* __restrict__ Abf, const unsigned short* __restrict__ WBT,
    unsigned short* __restrict__ Y1, unsigned short* __restrict__ Y2, int M)
{
    const int tid  = threadIdx.x;
    const int wave = tid >> 6;
    const int lane = tid & 63;
    const int quad = lane >> 4;
    const int l16  = lane & 15;
    const int m0   = blockIdx.x * 32;

    __shared__ unsigned short sA[32 * 128];   // 8 KB, XOR-swizzled 16B units

    {
        const uint4* gsrc = (const uint4*)(Abf + (size_t)m0 * 128);
        uint4* sdst = (uint4*)sA;
        #pragma unroll
        for (int p = 0; p < 2; ++p) {
            int g = tid + p * 256;
            int row = g >> 4, u = g & 15;
            sdst[row * 16 + (u ^ (row & 15))] = gsrc[g];
        }
    }
    __syncthreads();

    f32x4 acc[2][4] = {};
    const int nbase = wave * 64;

    #pragma unroll
    for (int c = 0; c < 4; ++c) {
        const int un = (c * 4 + quad) ^ l16;
        bfrag a0 = *(const bfrag*)(sA + ((size_t)(l16)      * 128 + un * 8));
        bfrag a1 = *(const bfrag*)(sA + ((size_t)(16 + l16) * 128 + un * 8));
        #pragma unroll
        for (int j = 0; j < 4; ++j) {
            const bfrag b = *(const bfrag*)(WBT + (size_t)(nbase + j * 16 + l16) * 128
                                                 + c * 32 + quad * 8);
            acc[0][j] = __builtin_amdgcn_mfma_f32_16x16x32_bf16(b, a0, acc[0][j], 0, 0, 0);
            acc[1][j] = __builtin_amdgcn_mfma_f32_16x16x32_bf16(b, a1, acc[1][j], 0, 0, 0);
        }
    }

    unsigned short* Yd = (nbase < 128) ? Y1 : Y2;
    const int colb = nbase & 127;
    #pragma unroll
    for (int i = 0; i < 2; ++i) {
        const int row = m0 + i * 16 + l16;
        #pragma unroll
        for (int j = 0; j < 4; ++j) {
            const int col = colb + j * 16 + quad * 4;
            ushort4 o;
            o.x = f2bf(acc[i][j][0]); o.y = f2bf(acc[i][j][1]);
            o.z = f2bf(acc[i][j][2]); o.w = f2bf(acc[i][j][3]);
            *(ushort4*)(Yd + (size_t)row * 128 + col) = o;
        }
    }
}

// ---------------- persistent-wave combined CSR aggregation (flow dsts) ----------
// Each wave owns AGGF_DPW CONTIGUOUS dsts. rp for the whole range loaded once
// (one coalesced vector load; per-dst bounds via __shfl). The wave's edge-index
// window (contiguous in the CSR!) is bulk-loaded coalesced into LDS once, so the
// per-dst critical path is ONLY the gather. 4-way quarter split, uint4 gathers
// (4 rows / wave instruction), shfl_xor reduce, quarter 0 stores.
__global__ __launch_bounds__(256) void k_agg_flow(
    const unsigned short* __restrict__ Z,
    const int* __restrict__ rp, const int* __restrict__ ei,
    const unsigned short* __restrict__ root, const float* __restrict__ bias,
    unsigned short* __restrict__ Xout, int do_relu)
{
    __shared__ int sIdx[4][AGG_CAP];
    const int wave = threadIdx.x >> 6;
    const int lane = threadIdx.x & 63;
    const int q    = lane >> 4;
    const int l16  = lane & 15;
    const int f8   = l16 * 8;
    const int gw   = blockIdx.x * 4 + wave;
    const int d0   = gw * AGGF_DPW;
    const int d1   = min(d0 + AGGF_DPW, N_FLOWN);

    int rpv = 0, W0 = 0, Wn = 0;
    if (d0 < N_FLOWN) {
        rpv = (lane <= d1 - d0) ? rp[d0 + lane] : 0;
        W0 = __shfl(rpv, 0, 64);
        Wn = __shfl(rpv, d1 - d0, 64);
        const int cw = min(Wn - W0, AGG_CAP);
        for (int i = lane; i < cw; i += 64) sIdx[wave][i] = ei[W0 + i];
    }
    __syncthreads();
    if (d0 >= N_FLOWN) return;
    const int Wcap = W0 + min(Wn - W0, AGG_CAP);

    // loop-invariant bias slice
    const float4 bva = *(const float4*)(bias + f8);
    const float4 bvb = *(const float4*)(bias + f8 + 4);

    for (int i = 0; i < d1 - d0; ++i) {
        const int d  = d0 + i;
        const int b0 = __shfl(rpv, i, 64);
        const int b1 = __shfl(rpv, i + 1, 64);

        uint4 rv = {0, 0, 0, 0};
        if (q == 0) rv = *(const uint4*)(root + (size_t)d * 128 + f8);

        float a[8] = {0.f, 0.f, 0.f, 0.f, 0.f, 0.f, 0.f, 0.f};
        int e = b0 + q;
        while (e + 4 < b1) {
            const int s0 = (e     < Wcap) ? sIdx[wave][e     - W0] : ei[e];
            const int s1 = (e + 4 < Wcap) ? sIdx[wave][e + 4 - W0] : ei[e + 4];
            const uint4 z0 = *(const uint4*)(Z + (size_t)s0 * 128 + f8);
            const uint4 z1 = *(const uint4*)(Z + (size_t)s1 * 128 + f8);
            acc8(a, z0);
            acc8(a, z1);
            e += 8;
        }
        if (e < b1) {
            const int s0 = (e < Wcap) ? sIdx[wave][e - W0] : ei[e];
            const uint4 z0 = *(const uint4*)(Z + (size_t)s0 * 128 + f8);
            acc8(a, z0);
        }

        #pragma unroll
        for (int j = 0; j < 8; ++j) {
            a[j] += __shfl_xor(a[j], 16, 64);
            a[j] += __shfl_xor(a[j], 32, 64);
        }

        if (q == 0) {
            float v0 = a[0] + __uint_as_float(rv.x << 16)         + bva.x;
            float v1 = a[1] + __uint_as_float(rv.x & 0xFFFF0000u) + bva.y;
            float v2 = a[2] + __uint_as_float(rv.y << 16)         + bva.z;
            float v3 = a[3] + __uint_as_float(rv.y & 0xFFFF0000u) + bva.w;
            float v4 = a[4] + __uint_as_float(rv.z << 16)         + bvb.x;
            float v5 = a[5] + __uint_as_float(rv.z & 0xFFFF0000u) + bvb.y;
            float v6 = a[6] + __uint_as_float(rv.w << 16)         + bvb.z;
            float v7 = a[7] + __uint_as_float(rv.w & 0xFFFF0000u) + bvb.w;
            if (do_relu) {
                v0 = fmaxf(v0, 0.f); v1 = fmaxf(v1, 0.f); v2 = fmaxf(v2, 0.f); v3 = fmaxf(v3, 0.f);
                v4 = fmaxf(v4, 0.f); v5 = fmaxf(v5, 0.f); v6 = fmaxf(v6, 0.f); v7 = fmaxf(v7, 0.f);
            }
            uint4 o;
            o.x = (unsigned)f2bf(v0) | ((unsigned)f2bf(v1) << 16);
            o.y = (unsigned)f2bf(v2) | ((unsigned)f2bf(v3) << 16);
            o.z = (unsigned)f2bf(v4) | ((unsigned)f2bf(v5) << 16);
            o.w = (unsigned)f2bf(v6) | ((unsigned)f2bf(v7) << 16);
            *(uint4*)(Xout + (size_t)d * 128 + f8) = o;
        }
    }
}

// host dst: out[d][0:128] = sum f2h Z[src][0:128]  (f32 out)
// Same persistent-wave / staged-index structure.
__global__ __launch_bounds__(256) void k_agg_host(
    const unsigned short* __restrict__ Z, const int* __restrict__ rp,
    const int* __restrict__ ei, float* __restrict__ out)
{
    __shared__ int sIdx[4][AGG_CAP];
    const int wave = threadIdx.x >> 6;
    const int lane = threadIdx.x & 63;
    const int q    = lane >> 4;
    const int l16  = lane & 15;
    const int f8   = l16 * 8;
    const int gw   = blockIdx.x * 4 + wave;
    const int d0   = gw * AGGH_DPW;
    const int d1   = min(d0 + AGGH_DPW, N_HOSTN);

    int rpv = 0, W0 = 0, Wn = 0;
    if (d0 < N_HOSTN) {
        rpv = (lane <= d1 - d0) ? rp[d0 + lane] : 0;
        W0 = __shfl(rpv, 0, 64);
        Wn = __shfl(rpv, d1 - d0, 64);
        const int cw = min(Wn - W0, AGG_CAP);
        for (int i = lane; i < cw; i += 64) sIdx[wave][i] = ei[W0 + i];
    }
    __syncthreads();
    if (d0 >= N_HOSTN) return;
    const int Wcap = W0 + min(Wn - W0, AGG_CAP);

    for (int i = 0; i < d1 - d0; ++i) {
        const int d  = d0 + i;
        const int b0 = __shfl(rpv, i, 64);
        const int b1 = __shfl(rpv, i + 1, 64);

        float a[8] = {0.f, 0.f, 0.f, 0.f, 0.f, 0.f, 0.f, 0.f};
        int e = b0 + q;
        while (e + 4 < b1) {
            const int s0 = (e     < Wcap) ? sIdx[wave][e     - W0] : ei[e];
            const int s1 = (e + 4 < Wcap) ? sIdx[wave][e + 4 - W0] : ei[e + 4];
            const uint4 z0 = *(const uint4*)(Z + (size_t)s0 * 128 + f8);
            const uint4 z1 = *(const uint4*)(Z + (size_t)s1 * 128 + f8);
            acc8(a, z0);
            acc8(a, z1);
            e += 8;
        }
        if (e < b1) {
            const int s0 = (e < Wcap) ? sIdx[wave][e - W0] : ei[e];
            const uint4 z0 = *(const uint4*)(Z + (size_t)s0 * 128 + f8);
            acc8(a, z0);
        }

        #pragma unroll
        for (int j = 0; j < 8; ++j) {
            a[j] += __shfl_xor(a[j], 16, 64);
            a[j] += __shfl_xor(a[j], 32, 64);
        }

        if (q == 0) {
            float4 oa, ob;
            oa.x = a[0]; oa.y = a[1]; oa.z = a[2]; oa.w = a[3];
            ob.x = a[4]; ob.y = a[5]; ob.z = a[6]; ob.w = a[7];
            *(float4*)(out + (size_t)d * 128 + f8)     = oa;
            *(float4*)(out + (size_t)d * 128 + f8 + 4) = ob;
        }
    }
}

// ---------------- pooling over sorted batch (bf16 input) ----------------
#define PCHUNK 128
__global__ __launch_bounds__(128) void k_pool2(const unsigned short* xf, const int* batch,
                                               unsigned* bits){
    const int t = threadIdx.x;
    const int i0 = blockIdx.x * PCHUNK;
    const int iend = min(i0 + PCHUNK, N_FLOWN);
    if (i0 >= N_FLOWN) return;
    float cur = -3.4e38f;
    int curg = batch[i0];
    for (int i = i0; i < iend; ++i) {
        int g = batch[i];
        if (g != curg) {
            unsigned u = __float_as_uint(cur);
            unsigned ord = (u & 0x80000000u) ? ~u : (u | 0x80000000u);
            atomicMax(&bits[(size_t)curg * 128 + t], ord);
            cur = -3.4e38f; curg = g;
        }
        cur = fmaxf(cur, bf2f(xf[(size_t)i * 128 + t]));
    }
    unsigned u = __float_as_uint(cur);
    unsigned ord = (u & 0x80000000u) ? ~u : (u | 0x80000000u);
    atomicMax(&bits[(size_t)curg * 128 + t], ord);
}

// ---------------- classifier ----------------
__global__ __launch_bounds__(128) void k_classifier(
    const unsigned* bits,
    const void* Wc1, const void* bc1, const void* Wc2, const void* bc2,
    const void* Wc3, const void* bc3, void* out, const int* flagp)
{
    const int g = blockIdx.x, t = threadIdx.x;
    const int isbf = *flagp;
    __shared__ float sp[128], sh1[64], sh2[128];
    {
        unsigned ord = bits[(size_t)g * HH + t];
        unsigned u = (ord & 0x80000000u) ? (ord & 0x7FFFFFFFu) : ~ord;
        sp[t] = __uint_as_float(u);
    }
    __syncthreads();
    if (t < 64) {
        float a = loadf(bc1, t, isbf);
        #pragma unroll 4
        for (int k = 0; k < 128; ++k) a = fmaf(sp[k], loadf(Wc1, k * 64 + t, isbf), a);
        sh1[t] = fmaxf(a, 0.f);
    }
    __syncthreads();
    {
        float a = loadf(bc2, t, isbf);
        #pragma unroll 4
        for (int k = 0; k < 64; ++k) a = fmaf(sh1[k], loadf(Wc2, k * 128 + t, isbf), a);
        sh2[t] = fmaxf(a, 0.f);
    }
    __syncthreads();
    if (t < NCN) {
        float a = loadf(bc3, t, isbf);
        #pragma unroll 4
        for (int k = 0; k < 128; ++k) a = fmaf(sh2[k], loadf(Wc3, k * NCN + t, isbf), a);
        if (isbf) ((unsigned short*)out)[(size_t)g * NCN + t] = f2bf(a);
        else      ((float*)out)[(size_t)g * NCN + t] = a;
    }
}

extern "C" void kernel_launch(void* const* d_in, const int* in_sizes, int n_in,
                              void* d_out, int out_size, void* d_ws, size_t ws_size,
                              hipStream_t stream)
{
    const int*  host_ids   = (const int*) d_in[0];
    const void* flow_x     = d_in[1];
    const int*  h2f_src    = (const int*) d_in[2];
    const int*  h2f_dst    = (const int*) d_in[3];
    const int*  f2h_src    = (const int*) d_in[4];
    const int*  f2h_dst    = (const int*) d_in[5];
    const int*  rel_src    = (const int*) d_in[6];
    const int*  rel_dst    = (const int*) d_in[7];
    const int*  flow_batch = (const int*) d_in[8];
    const void* host_embed = d_in[9];
    const void* Wr0_h2f = d_in[10]; const void* br0_h2f = d_in[11]; const void* Wo0_h2f = d_in[12];
    const void* Wr0_f2h = d_in[13]; const void* br0_f2h = d_in[14]; const void* Wo0_f2h = d_in[15];
    const void* Wr0_rel = d_in[16]; const void* br0_rel = d_in[17]; const void* Wo0_rel = d_in[18];
    const void* Wr_all  = d_in[19];
    const void* br_all  = d_in[20];
    const void* Wo_all  = d_in[21];
    const void* Wc1 = d_in[22]; const void* bc1 = d_in[23];
    const void* Wc2 = d_in[24]; const void* bc2 = d_in[25];
    const void* Wc3 = d_in[26]; const void* bc3 = d_in[27];

    // -------- workspace (~199 MB) --------
    size_t off = 0;
    auto alloc = [&](size_t bytes) -> char* {
        char* p = (char*)d_ws + off;
        off += (bytes + 255) & ~(size_t)255;
        return p;
    };
    unsigned short* F1bf  = (unsigned short*)alloc((size_t)N_FLOWN * HH * 2);  // state
    unsigned short* Froot = (unsigned short*)alloc((size_t)N_FLOWN * HH * 2);  // root term
    // ZALL: flow-transformed rows [0,200k) followed by host-transformed rows [200k,220k)
    unsigned short* ZALL  = (unsigned short*)alloc((size_t)(N_FLOWN + N_HOSTN) * HH * 2);
    unsigned short* F2bf  = ZALL;                                   // z_rel
    unsigned short* HCbf  = ZALL + (size_t)N_FLOWN * HH;            // z_h
    float* HA = (float*)alloc((size_t)N_HOSTN * HH * 4);
    float* HB = (float*)alloc((size_t)N_HOSTN * HH * 4);
    float* HD = (float*)alloc((size_t)N_HOSTN * HH * 4);
    unsigned short* WBT0 = (unsigned short*)alloc(256 * 128 * 2);
    unsigned short* WBT1 = (unsigned short*)alloc(256 * 128 * 2);
    unsigned short* WBT2 = (unsigned short*)alloc(256 * 128 * 2);
    float* w_h2f0  = (float*)alloc(128 * 128 * 4);
    float* w_h2f1  = (float*)alloc(128 * 128 * 4);
    float* w_h2f2  = (float*)alloc(128 * 128 * 4);
    float* w_f2h0  = (float*)alloc(128 * 128 * 4);
    float* w_f2h1  = (float*)alloc(128 * 128 * 4);
    float* w_of2h0 = (float*)alloc(128 * 128 * 4);
    float* w_of2h1 = (float*)alloc(128 * 128 * 4);
    float* b_comb0 = (float*)alloc(128 * 4);
    float* b_comb1 = (float*)alloc(128 * 4);
    float* b_comb2 = (float*)alloc(128 * 4);
    float* b_f2h0  = (float*)alloc(128 * 4);
    float* b_f2h1  = (float*)alloc(128 * 4);
    unsigned* poolbits = (unsigned*)alloc(GG * HH * 4);
    int* flagp = (int*)alloc(256);
    int* rp_cmb = (int*)alloc((N_FLOWN + 1) * 4);
    int* ei_cmb = (int*)alloc((size_t)E_CMBN * 4);
    int* rp_f2h = (int*)alloc((N_HOSTN + 1) * 4);
    int* ei_f2h = (int*)alloc((size_t)E_HFN * 4);
    int* wr_cmb = (int*)alloc((size_t)N_FLOWN * 4);
    int* wr_f2h = (int*)alloc((size_t)N_HOSTN * 4);
    int* bs0 = (int*)alloc(1024 * 4);
    int* bs2 = (int*)alloc(256 * 4);

    const int T = 256;
    #define GRID1(n) dim3(cdiv((long long)(n), T)), dim3(T), 0, stream

    if (off > ws_size) {
        k_flag_us<<<GRID1(out_size)>>>((unsigned short*)d_out, out_size, (unsigned short)0x4000);
        return;
    }

    k_detect<<<dim3(1), dim3(256), 0, stream>>>((const unsigned short*)flow_x, flagp);

    // -------- CSR builds (combined flow CSR + f2h CSR) --------
    k_zero2 <<<dim3(NB_CMB_N + NB_F2H_N), dim3(256), 0, stream>>>(wr_cmb, wr_f2h);
    k_hist3 <<<dim3(NB_REL_E + 2*NB_HF_E), dim3(256), 0, stream>>>(rel_dst, h2f_dst, f2h_dst,
                                                                    wr_cmb, wr_f2h);
    k_scan1_2<<<dim3(NB_CMB_N + NB_F2H_N), dim3(256), 0, stream>>>(
        wr_cmb, rp_cmb, bs0, wr_f2h, rp_f2h, bs2);
    k_scan2_2<<<dim3(2), dim3(256), 0, stream>>>(bs0, bs2);
    k_scan3_2<<<dim3(NB_CMB_N + NB_F2H_N), dim3(256), 0, stream>>>(
        rp_cmb, bs0, wr_cmb, rp_f2h, bs2, wr_f2h);
    k_place3c<<<dim3(PLC_ALL), dim3(256), 0, stream>>>(
        rel_src, rel_dst, h2f_src, h2f_dst, f2h_src, f2h_dst,
        wr_cmb, ei_cmb, wr_f2h, ei_f2h);

    // -------- weight prep (1 launch) --------
    k_wprep_all<<<dim3(833), dim3(256), 0, stream>>>(
        Wr0_h2f, br0_h2f, Wo0_h2f, Wr0_f2h, br0_f2h, Wo0_f2h, Wr0_rel, br0_rel, Wo0_rel,
        Wr_all, br_all, Wo_all,
        WBT0, WBT1, WBT2, w_h2f0, w_h2f1, w_h2f2,
        w_f2h0, w_f2h1, w_of2h0, w_of2h1,
        b_comb0, b_comb1, b_comb2, b_f2h0, b_f2h1, flagp);

    // ================= layer 0 =================
    k_gather_embed<<<GRID1(N_HOSTN * HH)>>>(host_ids, host_embed, HA, flagp);
    k_pad_cast<<<GRID1((size_t)N_FLOWN * 128)>>>(flow_x, F1bf, flagp);
    // host path: gather bf16 input features (K padded to 128); fused dual GEMM + relu
    k_agg_host<<<dim3(AGGH_BLK), dim3(256), 0, stream>>>(F1bf, rp_f2h, ei_f2h, HD);
    k_gemm2in<<<dim3(cdiv(N_HOSTN,16)), dim3(256), 0, stream>>>(HD, HA, w_f2h0, w_of2h0, b_f2h0, HB, N_HOSTN);
    // flow path
    k_gemm128<<<dim3(cdiv(N_HOSTN,16)), dim3(256), 0, stream>>>(HA, 0, w_h2f0, nullptr, HCbf, 1, N_HOSTN, 128, 0, 0, flagp);
    k_gemm_mfma<<<dim3(N_FLOWN/32), dim3(256), 0, stream>>>(F1bf, WBT0, Froot, F2bf, N_FLOWN);
    k_agg_flow<<<dim3(AGGF_BLK), dim3(256), 0, stream>>>(ZALL, rp_cmb, ei_cmb,
                                                         Froot, b_comb0, F1bf, 1);

    // ================= stacked layer 0 =================
    k_agg_host<<<dim3(AGGH_BLK), dim3(256), 0, stream>>>(F1bf, rp_f2h, ei_f2h, HD);
    k_gemm128<<<dim3(cdiv(N_HOSTN,16)), dim3(256), 0, stream>>>(HB, 0, w_h2f1, nullptr, HCbf, 1, N_HOSTN, 128, 0, 0, flagp);
    k_gemm_mfma<<<dim3(N_FLOWN/32), dim3(256), 0, stream>>>(F1bf, WBT1, Froot, F2bf, N_FLOWN);
    k_agg_flow<<<dim3(AGGF_BLK), dim3(256), 0, stream>>>(ZALL, rp_cmb, ei_cmb,
                                                         Froot, b_comb1, F1bf, 1);
    k_gemm2in<<<dim3(cdiv(N_HOSTN,16)), dim3(256), 0, stream>>>(HD, HB, w_f2h1, w_of2h1, b_f2h1, HA, N_HOSTN);

    // ================= stacked layer 1 (last; no host update, no relu) =================
    k_gemm128<<<dim3(cdiv(N_HOSTN,16)), dim3(256), 0, stream>>>(HA, 0, w_h2f2, nullptr, HCbf, 1, N_HOSTN, 128, 0, 0, flagp);
    k_gemm_mfma<<<dim3(N_FLOWN/32), dim3(256), 0, stream>>>(F1bf, WBT2, Froot, F2bf, N_FLOWN);
    k_agg_flow<<<dim3(AGGF_BLK), dim3(256), 0, stream>>>(ZALL, rp_cmb, ei_cmb,
                                                         Froot, b_comb2, F1bf, 0);

    // ================= pool + classifier =================
    k_zero<<<GRID1(GG * HH)>>>((float*)poolbits, (size_t)GG * HH);
    k_pool2<<<dim3(cdiv(N_FLOWN, PCHUNK)), dim3(128), 0, stream>>>(F1bf, flow_batch, poolbits);
    k_classifier<<<dim3(GG), dim3(128), 0, stream>>>(poolbits, Wc1, bc1, Wc2, bc2, Wc3, bc3,
                                                     d_out, flagp);
    #undef GRID1
}

// Round 4
// 1058.117 us; speedup vs baseline: 1.1217x; 1.0572x over previous
//
#include <hip/hip_runtime.h>
#include <hip/hip_bf16.h>

using bf16 = __hip_bfloat16;

#define N_HOSTN 20000
#define N_FLOWN 200000
#define E_HFN   400000
#define E_RELN  800000
#define E_CMBN  1200000  // rel + h2f combined
#define GG      64
#define HH      128
#define FIN     97
#define NCN     10

// CSR region block counts (256 threads/block)
#define NB_REL_E 3125   // 800000/256
#define NB_HF_E  1563   // ceil(400000/256)
#define NB_CMB_N 782    // ceil(200000/256)
#define NB_F2H_N 79     // ceil(20000/256)
// class-partitioned placement: 2048-edge chunks x 8 classes
#define NCH_REL 391     // ceil(800000/2048)
#define NCH_HF  196     // ceil(400000/2048)
#define PLC_REL (NCH_REL*8)            // 3128
#define PLC_H2F (PLC_REL + NCH_HF*8)   // 4696
#define PLC_ALL (PLC_H2F + NCH_HF*8)   // 6264

// persistent-wave aggregation geometry
#define AGG_CAP    768   // staged indices per wave (fallback to global beyond)
#define AGGF_BLK   2048  // 8192 waves * 25 dsts >= 200000
#define AGGF_DPW   25
#define AGGH_BLK   512   // 2048 waves * 10 dsts >= 20000
#define AGGH_DPW   10

static inline int cdiv(long long a, long long b){ return (int)((a + b - 1) / b); }

__device__ __forceinline__ float bf2f(unsigned short u){
    return __uint_as_float(((unsigned)u) << 16);
}
__device__ __forceinline__ unsigned short f2bf(float f){
    unsigned u = __float_as_uint(f);
    unsigned r = u + 0x7FFFu + ((u >> 16) & 1u);   // RNE
    return (unsigned short)(r >> 16);
}
__device__ __forceinline__ float loadf(const void* p, size_t i, int isbf){
    return isbf ? bf2f(((const unsigned short*)p)[i]) : ((const float*)p)[i];
}
// unpack 8 bf16 (uint4) and accumulate into 8 f32
__device__ __forceinline__ void acc8(float* a, uint4 z){
    a[0] += __uint_as_float(z.x << 16);
    a[1] += __uint_as_float(z.x & 0xFFFF0000u);
    a[2] += __uint_as_float(z.y << 16);
    a[3] += __uint_as_float(z.y & 0xFFFF0000u);
    a[4] += __uint_as_float(z.z << 16);
    a[5] += __uint_as_float(z.z & 0xFFFF0000u);
    a[6] += __uint_as_float(z.w << 16);
    a[7] += __uint_as_float(z.w & 0xFFFF0000u);
}

// ---------------- dtype detection ----------------
__global__ void k_detect(const unsigned short* x, int* flag){
    __shared__ int bad;
    if (threadIdx.x == 0) bad = 0;
    __syncthreads();
    int b = 0;
    for (int i = threadIdx.x; i < 4096; i += 256) {
        unsigned e = (x[i] >> 7) & 0xFFu;
        if (e >= 0x90u) b++;
    }
    if (b) atomicAdd(&bad, b);
    __syncthreads();
    if (threadIdx.x == 0) *flag = (bad == 0) ? 1 : 0;   // 1 = bf16, 0 = f32
}

// ---------------- misc ----------------
__global__ void k_zero(float* p, size_t n){
    size_t i = (size_t)blockIdx.x * 256 + threadIdx.x;
    if (i < n) p[i] = 0.f;
}
__global__ void k_flag_us(unsigned short* out, int n, unsigned short val){
    int i = blockIdx.x * 256 + threadIdx.x;
    if (i < n) out[i] = val;
}
__global__ void k_gather_embed(const int* ids, const void* emb, float* out, const int* flagp){
    int i = blockIdx.x * 256 + threadIdx.x;
    if (i >= N_HOSTN * HH) return;
    int isbf = *flagp;
    int node = i >> 7, f = i & 127;
    out[i] = loadf(emb, (size_t)ids[node] * HH + f, isbf);
}
// flow_x [N,97] (flag dtype) -> bf16 padded [N,128]; 8 output cols per thread
__global__ void k_pad_cast(const void* x, unsigned short* o, const int* flagp){
    int i = blockIdx.x * 256 + threadIdx.x;           // 0 .. N_FLOWN*16
    if (i >= N_FLOWN * 16) return;
    int isbf = *flagp;
    int row = i >> 4, c0 = (i & 15) * 8;
    unsigned short v[8];
    #pragma unroll
    for (int j = 0; j < 8; ++j) {
        int c = c0 + j;
        v[j] = (c < FIN) ? f2bf(loadf(x, (size_t)row * FIN + c, isbf)) : (unsigned short)0;
    }
    uint4 ov;
    ov.x = (unsigned)v[0] | ((unsigned)v[1] << 16);
    ov.y = (unsigned)v[2] | ((unsigned)v[3] << 16);
    ov.z = (unsigned)v[4] | ((unsigned)v[5] << 16);
    ov.w = (unsigned)v[6] | ((unsigned)v[7] << 16);
    *(uint4*)(o + (size_t)row * 128 + c0) = ov;
}

// ---------------- one-shot weight prep (833 blocks, region dispatch) ----------------
__global__ __launch_bounds__(256) void k_wprep_all(
    const void* Wr0_h2f, const void* br0_h2f, const void* Wo0_h2f,
    const void* Wr0_f2h, const void* br0_f2h, const void* Wo0_f2h,
    const void* Wr0_rel, const void* br0_rel, const void* Wo0_rel,
    const void* Wr_all, const void* br_all, const void* Wo_all,
    unsigned short* WBT0, unsigned short* WBT1, unsigned short* WBT2,
    float* w_h2f0, float* w_h2f1, float* w_h2f2,
    float* w_f2h0, float* w_f2h1, float* w_of2h0, float* w_of2h1,
    float* b_comb0, float* b_comb1, float* b_comb2, float* b_f2h0, float* b_f2h1,
    const int* flagp)
{
    const int bb = blockIdx.x, t = threadIdx.x;
    const int isbf = *flagp;
    if (bb < 384) {
        int layer = bb >> 7;
        int i = ((bb & 127) << 8) + t;   // 0..32767
        int nn = i >> 7, k = i & 127;
        float v = 0.f;
        if (layer == 0) {
            if (k < FIN) {
                if (nn < 128) v = loadf(Wo0_h2f, (size_t)k*128+nn, isbf) + loadf(Wo0_rel, (size_t)k*128+nn, isbf);
                else          v = loadf(Wr0_rel, (size_t)k*128+(nn-128), isbf);
            }
        } else {
            size_t oW = (size_t)((layer - 1) * 3) * 16384;
            if (nn < 128) v = loadf(Wo_all, oW + (size_t)k*128+nn, isbf)
                            + loadf(Wo_all, oW + 2*16384 + (size_t)k*128+nn, isbf);
            else          v = loadf(Wr_all, oW + 2*16384 + (size_t)k*128+(nn-128), isbf);
        }
        unsigned short* W = (layer == 0) ? WBT0 : ((layer == 1) ? WBT1 : WBT2);
        W[(size_t)nn*128 + k] = f2bf(v);
    } else if (bb < 576) {
        int r = bb - 384; int layer = r >> 6; int i = ((r & 63) << 8) + t;
        float v;
        if (layer == 0) v = loadf(Wr0_h2f, (size_t)i, isbf);
        else            v = loadf(Wr_all, (size_t)((layer-1)*3)*16384 + i, isbf);
        ((layer == 0) ? w_h2f0 : ((layer == 1) ? w_h2f1 : w_h2f2))[i] = v;
    } else if (bb < 640) {
        // w_f2h0 padded to [128][128]: rows k>=97 zero
        int i = ((bb - 576) << 8) + t;
        int k = i >> 7;
        w_f2h0[i] = (k < FIN) ? loadf(Wr0_f2h, (size_t)i, isbf) : 0.f;
    } else if (bb < 704) {
        int i = ((bb - 640) << 8) + t;
        w_f2h1[i] = loadf(Wr_all, (size_t)1*16384 + i, isbf);
    } else if (bb < 768) {
        int i = ((bb - 704) << 8) + t;
        w_of2h0[i] = loadf(Wo0_f2h, (size_t)i, isbf);
    } else if (bb < 832) {
        int i = ((bb - 768) << 8) + t;
        w_of2h1[i] = loadf(Wo_all, (size_t)1*16384 + i, isbf);
    } else {
        if (t < 128) {
            b_comb0[t] = loadf(br0_h2f, t, isbf) + loadf(br0_rel, t, isbf);
            b_comb1[t] = loadf(br_all, 0*128 + t, isbf) + loadf(br_all, 2*128 + t, isbf);
            b_comb2[t] = loadf(br_all, 3*128 + t, isbf) + loadf(br_all, 5*128 + t, isbf);
            b_f2h0[t]  = loadf(br0_f2h, t, isbf);
            b_f2h1[t]  = loadf(br_all, 1*128 + t, isbf);
        }
    }
}

// ---------------- CSR build (combined flow CSR + f2h CSR) ----------------
__global__ void k_zero2(int* c0, int* c1){
    int bb = blockIdx.x, t = threadIdx.x;
    if (bb < NB_CMB_N) { int i = bb * 256 + t; if (i < N_FLOWN) c0[i] = 0; }
    else               { int i = (bb - NB_CMB_N) * 256 + t; if (i < N_HOSTN) c1[i] = 0; }
}
// rel and h2f edges both count into c_cmb; f2h into c_f2h
__global__ void k_hist3(const int* drel, const int* dh2f, const int* df2h,
                        int* c_cmb, int* c_f2h){
    int bb = blockIdx.x, t = threadIdx.x;
    const int* dst; int* cnt; int E; int base;
    if (bb < NB_REL_E)                   { dst = drel; cnt = c_cmb; E = E_RELN; base = bb; }
    else if (bb < NB_REL_E + NB_HF_E)    { dst = dh2f; cnt = c_cmb; E = E_HFN;  base = bb - NB_REL_E; }
    else                                 { dst = df2h; cnt = c_f2h; E = E_HFN;  base = bb - NB_REL_E - NB_HF_E; }
    int e = base * 256 + t;
    if (e < E) atomicAdd(&cnt[dst[e]], 1);
}
__global__ __launch_bounds__(256) void k_scan1_2(
    const int* c0, int* rp0, int* bs0,
    const int* c1, int* rp1, int* bs1)
{
    __shared__ int s[256];
    int bb = blockIdx.x, t = threadIdx.x;
    const int* cnt; int* rp; int* bsum; int n; int base;
    if (bb < NB_CMB_N) { cnt = c0; rp = rp0; bsum = bs0; n = N_FLOWN; base = bb; }
    else               { cnt = c1; rp = rp1; bsum = bs1; n = N_HOSTN; base = bb - NB_CMB_N; }
    int i = base * 256 + t;
    int v = (i < n) ? cnt[i] : 0;
    s[t] = v; __syncthreads();
    for (int off = 1; off < 256; off <<= 1) {
        int x = (t >= off) ? s[t - off] : 0;
        __syncthreads();
        s[t] += x;
        __syncthreads();
    }
    if (i < n) rp[i] = s[t] - v;
    if (t == 255) bsum[base] = s[255];
}
__global__ __launch_bounds__(256) void k_scan2_2(int* bs0, int* bs1){
    __shared__ int s[256];
    __shared__ int carry;
    int t = threadIdx.x;
    int* bsum; int nb;
    if (blockIdx.x == 0) { bsum = bs0; nb = NB_CMB_N; }
    else                 { bsum = bs1; nb = NB_F2H_N; }
    if (t == 0) carry = 0;
    __syncthreads();
    for (int base = 0; base < nb; base += 256) {
        int i = base + t;
        int v = (i < nb) ? bsum[i] : 0;
        s[t] = v; __syncthreads();
        for (int off = 1; off < 256; off <<= 1) {
            int x = (t >= off) ? s[t - off] : 0;
            __syncthreads();
            s[t] += x;
            __syncthreads();
        }
        int excl = s[t] - v + carry;
        if (i < nb) bsum[i] = excl;
        __syncthreads();
        if (t == 255) carry += s[255];
        __syncthreads();
    }
}
__global__ void k_scan3_2(int* rp0, const int* bs0, int* w0,
                          int* rp1, const int* bs1, int* w1)
{
    int bb = blockIdx.x, t = threadIdx.x;
    int* rp; const int* bsum; int* wr; int n, E, base;
    if (bb < NB_CMB_N) { rp = rp0; bsum = bs0; wr = w0; n = N_FLOWN; E = E_CMBN; base = bb; }
    else               { rp = rp1; bsum = bs1; wr = w1; n = N_HOSTN; E = E_HFN;  base = bb - NB_CMB_N; }
    int i = base * 256 + t;
    if (i < n) { int v = rp[i] + bsum[base]; rp[i] = v; wr[i] = v; }
    if (i == 0) rp[n] = E;
}
// class-partitioned placement: class = blockIdx%8 (round-robins onto XCDs);
// rel + h2f both place into the combined flow CSR; h2f srcs get +N_FLOWN so
// the gather reads the host rows appended after the flow rows in ZALL.
__global__ __launch_bounds__(256) void k_place3c(
    const int* s0, const int* d0,
    const int* s1, const int* d1,
    const int* s2, const int* d2,
    int* w_cmb, int* e_cmb, int* w_f2h, int* e_f2h)
{
    const int bb = blockIdx.x;
    const int *src, *dst; int *wr, *ei; int E, divc, rb, soff;
    if (bb < PLC_REL)      { src=s0; dst=d0; wr=w_cmb; ei=e_cmb; E=E_RELN; divc=25000; rb=bb;          soff=0; }
    else if (bb < PLC_H2F) { src=s1; dst=d1; wr=w_cmb; ei=e_cmb; E=E_HFN;  divc=25000; rb=bb-PLC_REL;  soff=N_FLOWN; }
    else                   { src=s2; dst=d2; wr=w_f2h; ei=e_f2h; E=E_HFN;  divc=2500;  rb=bb-PLC_H2F;  soff=0; }
    const int cls  = rb & 7;
    const int base = (rb >> 3) * 2048;
    const int t = threadIdx.x;
    #pragma unroll
    for (int i = 0; i < 8; ++i) {
        const int e = base + t + i * 256;
        if (e < E) {
            const int d = dst[e];
            if (d / divc == cls) {
                const int pos = atomicAdd(&wr[d], 1);
                ei[pos] = src[e] + soff;
            }
        }
    }
}

// ---------------- host-sized VALU GEMM: Y[M,128] (+)= X[M,K]@W[K,128]+b ---------
__global__ __launch_bounds__(256) void k_gemm128(
    const void* X, int xmode, const float* W, const float* bias,
    void* Y, int ybf, int M, int K, int accum, int dorelu, const int* flagp)
{
    const int isbf = (xmode == 2) ? *flagp : xmode;
    const int tid  = threadIdx.x;
    const int row0 = blockIdx.x * 16;
    __shared__ float sX[16][130];
    const int total = 16 * K;
    for (int i = tid; i < total; i += 256) {
        int r = i / K, c = i - r * K;
        int gr = row0 + r;
        sX[r][c] = (gr < M) ? loadf(X, (size_t)gr * K + c, isbf) : 0.f;
    }
    __syncthreads();

    const int c4 = (tid & 31) * 4;
    const int rb = tid >> 5;
    float a0x=0,a0y=0,a0z=0,a0w=0, a1x=0,a1y=0,a1z=0,a1w=0;
    #pragma unroll 4
    for (int k = 0; k < K; ++k) {
        const float4 w = *(const float4*)(W + (size_t)k * 128 + c4);
        const float x0 = sX[rb][k];
        const float x1 = sX[rb + 8][k];
        a0x = fmaf(x0, w.x, a0x); a0y = fmaf(x0, w.y, a0y);
        a0z = fmaf(x0, w.z, a0z); a0w = fmaf(x0, w.w, a0w);
        a1x = fmaf(x1, w.x, a1x); a1y = fmaf(x1, w.y, a1y);
        a1z = fmaf(x1, w.z, a1z); a1w = fmaf(x1, w.w, a1w);
    }
    float bx=0, by=0, bz=0, bw=0;
    if (bias) { const float4 b = *(const float4*)(bias + c4); bx=b.x; by=b.y; bz=b.z; bw=b.w; }

    #pragma unroll
    for (int h = 0; h < 2; ++h) {
        const int rr = row0 + rb + (h ? 8 : 0);
        if (rr >= M) continue;
        float v0 = (h?a1x:a0x)+bx, v1 = (h?a1y:a0y)+by;
        float v2 = (h?a1z:a0z)+bz, v3 = (h?a1w:a0w)+bw;
        if (ybf) {
            unsigned short* p = (unsigned short*)Y + (size_t)rr * 128 + c4;
            ushort4 o; o.x=f2bf(v0); o.y=f2bf(v1); o.z=f2bf(v2); o.w=f2bf(v3);
            *(ushort4*)p = o;
        } else {
            float* p = (float*)Y + (size_t)rr * 128 + c4;
            if (accum) { v0+=p[0]; v1+=p[1]; v2+=p[2]; v3+=p[3]; }
            if (dorelu) { v0=fmaxf(v0,0.f); v1=fmaxf(v1,0.f); v2=fmaxf(v2,0.f); v3=fmaxf(v3,0.f); }
            float4 o; o.x=v0; o.y=v1; o.z=v2; o.w=v3;
            *(float4*)p = o;
        }
    }
}

// ---------------- fused dual-input host GEMM: Y = relu(X1@W1 + X2@W2 + b) ------
__global__ __launch_bounds__(256) void k_gemm2in(
    const float* __restrict__ X1, const float* __restrict__ X2,
    const float* __restrict__ W1, const float* __restrict__ W2,
    const float* __restrict__ bias, float* __restrict__ Y, int M)
{
    const int tid  = threadIdx.x;
    const int row0 = blockIdx.x * 16;
    __shared__ float sX1[16][130];
    __shared__ float sX2[16][130];
    for (int i = tid; i < 16 * 128; i += 256) {
        int r = i >> 7, c = i & 127;
        int gr = row0 + r;
        sX1[r][c] = (gr < M) ? X1[(size_t)gr * 128 + c] : 0.f;
        sX2[r][c] = (gr < M) ? X2[(size_t)gr * 128 + c] : 0.f;
    }
    __syncthreads();

    const int c4 = (tid & 31) * 4;
    const int rb = tid >> 5;
    float a0x=0,a0y=0,a0z=0,a0w=0, a1x=0,a1y=0,a1z=0,a1w=0;
    #pragma unroll 4
    for (int k = 0; k < 128; ++k) {
        const float4 w = *(const float4*)(W1 + (size_t)k * 128 + c4);
        const float x0 = sX1[rb][k];
        const float x1 = sX1[rb + 8][k];
        a0x = fmaf(x0, w.x, a0x); a0y = fmaf(x0, w.y, a0y);
        a0z = fmaf(x0, w.z, a0z); a0w = fmaf(x0, w.w, a0w);
        a1x = fmaf(x1, w.x, a1x); a1y = fmaf(x1, w.y, a1y);
        a1z = fmaf(x1, w.z, a1z); a1w = fmaf(x1, w.w, a1w);
    }
    #pragma unroll 4
    for (int k = 0; k < 128; ++k) {
        const float4 w = *(const float4*)(W2 + (size_t)k * 128 + c4);
        const float x0 = sX2[rb][k];
        const float x1 = sX2[rb + 8][k];
        a0x = fmaf(x0, w.x, a0x); a0y = fmaf(x0, w.y, a0y);
        a0z = fmaf(x0, w.z, a0z); a0w = fmaf(x0, w.w, a0w);
        a1x = fmaf(x1, w.x, a1x); a1y = fmaf(x1, w.y, a1y);
        a1z = fmaf(x1, w.z, a1z); a1w = fmaf(x1, w.w, a1w);
    }
    const float4 b = *(const float4*)(bias + c4);
    #pragma unroll
    for (int h = 0; h < 2; ++h) {
        const int rr = row0 + rb + (h ? 8 : 0);
        if (rr >= M) continue;
        float4 o;
        o.x = fmaxf((h?a1x:a0x) + b.x, 0.f);
        o.y = fmaxf((h?a1y:a0y) + b.y, 0.f);
        o.z = fmaxf((h?a1z:a0z) + b.z, 0.f);
        o.w = fmaxf((h?a1w:a0w) + b.w, 0.f);
        *(float4*)(Y + (size_t)rr * 128 + c4) = o;
    }
}

// ---------------- MFMA dual flow GEMM: both outputs bf16, no bias ----------------
// v4: B (WBT, 256x128 = 64KB) kept ENTIRELY in registers per wave (16 bfrags =
// 64 VGPR for the wave's 64-col slice), loaded once. Each block processes 8
// row-chunks of 32 (256 rows), A fragments read DIRECT from global (lane l16
// reads A[m0+l16][c*32+quad*8..+8] -- same logical mapping the old LDS swizzle
// produced). No LDS, no barriers: per chunk = 8 indep loads -> 32 MFMA -> 8
// vector stores, software-pipelined across chunks by the compiler.
// Operands swapped (mfma(b, a) == D^T) so each lane's 4 acc regs are 4
// CONSECUTIVE output columns -> ushort4 stores.
typedef __attribute__((ext_vector_type(8))) short bfrag;
typedef __attribute__((ext_vector_type(4))) float f32x4;

#define GEMM_CHUNKS 8

__global__ __launch_bounds__(256) void k_gemm_mfma(
    const unsigned short* __restrict__ Abf, const unsigned short* __restrict__ WBT,
    unsigned short* __restrict__ Y1, unsigned short* __restrict__ Y2, int M)
{
    const int tid  = threadIdx.x;
    const int wave = tid >> 6;
    const int lane = tid & 63;
    const int quad = lane >> 4;
    const int l16  = lane & 15;
    const int nbase = wave * 64;

    // B slice for this wave's 64 output cols: breg[c][j], all compile-time indexed
    bfrag breg[4][4];
    #pragma unroll
    for (int c = 0; c < 4; ++c)
        #pragma unroll
        for (int j = 0; j < 4; ++j)
            breg[c][j] = *(const bfrag*)(WBT + (size_t)(nbase + j * 16 + l16) * 128
                                              + c * 32 + quad * 8);

    unsigned short* __restrict__ Yd = (nbase < 128) ? Y1 : Y2;
    const int colb = nbase & 127;
    const f32x4 zero = {0.f, 0.f, 0.f, 0.f};

    #pragma unroll
    for (int chunk = 0; chunk < GEMM_CHUNKS; ++chunk) {
        const int m0 = blockIdx.x * (32 * GEMM_CHUNKS) + chunk * 32;
        if (m0 < M) {
            // A fragments direct from global (16 rows x 64B per load instruction)
            bfrag a0[4], a1[4];
            #pragma unroll
            for (int c = 0; c < 4; ++c) {
                a0[c] = *(const bfrag*)(Abf + (size_t)(m0      + l16) * 128 + c * 32 + quad * 8);
                a1[c] = *(const bfrag*)(Abf + (size_t)(m0 + 16 + l16) * 128 + c * 32 + quad * 8);
            }
            f32x4 acc[2][4];
            #pragma unroll
            for (int j = 0; j < 4; ++j) {
                acc[0][j] = __builtin_amdgcn_mfma_f32_16x16x32_bf16(breg[0][j], a0[0], zero, 0, 0, 0);
                acc[1][j] = __builtin_amdgcn_mfma_f32_16x16x32_bf16(breg[0][j], a1[0], zero, 0, 0, 0);
            }
            #pragma unroll
            for (int c = 1; c < 4; ++c)
                #pragma unroll
                for (int j = 0; j < 4; ++j) {
                    acc[0][j] = __builtin_amdgcn_mfma_f32_16x16x32_bf16(breg[c][j], a0[c], acc[0][j], 0, 0, 0);
                    acc[1][j] = __builtin_amdgcn_mfma_f32_16x16x32_bf16(breg[c][j], a1[c], acc[1][j], 0, 0, 0);
                }
            // D' layout: col(lane&15) = X-row m (within 16-block i), row(quad*4+r) = WBT-row n
            #pragma unroll
            for (int i = 0; i < 2; ++i) {
                const int row = m0 + i * 16 + l16;
                #pragma unroll
                for (int j = 0; j < 4; ++j) {
                    const int col = colb + j * 16 + quad * 4;
                    ushort4 o;
                    o.x = f2bf(acc[i][j][0]); o.y = f2bf(acc[i][j][1]);
                    o.z = f2bf(acc[i][j][2]); o.w = f2bf(acc[i][j][3]);
                    *(ushort4*)(Yd + (size_t)row * 128 + col) = o;
                }
            }
        }
    }
}

// ---------------- persistent-wave combined CSR aggregation (flow dsts) ----------
// Each wave owns AGGF_DPW CONTIGUOUS dsts. rp for the whole range loaded once
// (one coalesced vector load; per-dst bounds via __shfl). The wave's edge-index
// window (contiguous in the CSR!) is bulk-loaded coalesced into LDS once, so the
// per-dst critical path is ONLY the gather. 4-way quarter split, uint4 gathers
// (4 rows / wave instruction), shfl_xor reduce, quarter 0 stores.
__global__ __launch_bounds__(256) void k_agg_flow(
    const unsigned short* __restrict__ Z,
    const int* __restrict__ rp, const int* __restrict__ ei,
    const unsigned short* __restrict__ root, const float* __restrict__ bias,
    unsigned short* __restrict__ Xout, int do_relu)
{
    __shared__ int sIdx[4][AGG_CAP];
    const int wave = threadIdx.x >> 6;
    const int lane = threadIdx.x & 63;
    const int q    = lane >> 4;
    const int l16  = lane & 15;
    const int f8   = l16 * 8;
    const int gw   = blockIdx.x * 4 + wave;
    const int d0   = gw * AGGF_DPW;
    const int d1   = min(d0 + AGGF_DPW, N_FLOWN);

    int rpv = 0, W0 = 0, Wn = 0;
    if (d0 < N_FLOWN) {
        rpv = (lane <= d1 - d0) ? rp[d0 + lane] : 0;
        W0 = __shfl(rpv, 0, 64);
        Wn = __shfl(rpv, d1 - d0, 64);
        const int cw = min(Wn - W0, AGG_CAP);
        for (int i = lane; i < cw; i += 64) sIdx[wave][i] = ei[W0 + i];
    }
    __syncthreads();
    if (d0 >= N_FLOWN) return;
    const int Wcap = W0 + min(Wn - W0, AGG_CAP);

    // loop-invariant bias slice
    const float4 bva = *(const float4*)(bias + f8);
    const float4 bvb = *(const float4*)(bias + f8 + 4);

    for (int i = 0; i < d1 - d0; ++i) {
        const int d  = d0 + i;
        const int b0 = __shfl(rpv, i, 64);
        const int b1 = __shfl(rpv, i + 1, 64);

        uint4 rv = {0, 0, 0, 0};
        if (q == 0) rv = *(const uint4*)(root + (size_t)d * 128 + f8);

        float a[8] = {0.f, 0.f, 0.f, 0.f, 0.f, 0.f, 0.f, 0.f};
        int e = b0 + q;
        while (e + 4 < b1) {
            const int s0 = (e     < Wcap) ? sIdx[wave][e     - W0] : ei[e];
            const int s1 = (e + 4 < Wcap) ? sIdx[wave][e + 4 - W0] : ei[e + 4];
            const uint4 z0 = *(const uint4*)(Z + (size_t)s0 * 128 + f8);
            const uint4 z1 = *(const uint4*)(Z + (size_t)s1 * 128 + f8);
            acc8(a, z0);
            acc8(a, z1);
            e += 8;
        }
        if (e < b1) {
            const int s0 = (e < Wcap) ? sIdx[wave][e - W0] : ei[e];
            const uint4 z0 = *(const uint4*)(Z + (size_t)s0 * 128 + f8);
            acc8(a, z0);
        }

        #pragma unroll
        for (int j = 0; j < 8; ++j) {
            a[j] += __shfl_xor(a[j], 16, 64);
            a[j] += __shfl_xor(a[j], 32, 64);
        }

        if (q == 0) {
            float v0 = a[0] + __uint_as_float(rv.x << 16)         + bva.x;
            float v1 = a[1] + __uint_as_float(rv.x & 0xFFFF0000u) + bva.y;
            float v2 = a[2] + __uint_as_float(rv.y << 16)         + bva.z;
            float v3 = a[3] + __uint_as_float(rv.y & 0xFFFF0000u) + bva.w;
            float v4 = a[4] + __uint_as_float(rv.z << 16)         + bvb.x;
            float v5 = a[5] + __uint_as_float(rv.z & 0xFFFF0000u) + bvb.y;
            float v6 = a[6] + __uint_as_float(rv.w << 16)         + bvb.z;
            float v7 = a[7] + __uint_as_float(rv.w & 0xFFFF0000u) + bvb.w;
            if (do_relu) {
                v0 = fmaxf(v0, 0.f); v1 = fmaxf(v1, 0.f); v2 = fmaxf(v2, 0.f); v3 = fmaxf(v3, 0.f);
                v4 = fmaxf(v4, 0.f); v5 = fmaxf(v5, 0.f); v6 = fmaxf(v6, 0.f); v7 = fmaxf(v7, 0.f);
            }
            uint4 o;
            o.x = (unsigned)f2bf(v0) | ((unsigned)f2bf(v1) << 16);
            o.y = (unsigned)f2bf(v2) | ((unsigned)f2bf(v3) << 16);
            o.z = (unsigned)f2bf(v4) | ((unsigned)f2bf(v5) << 16);
            o.w = (unsigned)f2bf(v6) | ((unsigned)f2bf(v7) << 16);
            *(uint4*)(Xout + (size_t)d * 128 + f8) = o;
        }
    }
}

// host dst: out[d][0:128] = sum f2h Z[src][0:128]  (f32 out)
// Same persistent-wave / staged-index structure.
__global__ __launch_bounds__(256) void k_agg_host(
    const unsigned short* __restrict__ Z, const int* __restrict__ rp,
    const int* __restrict__ ei, float* __restrict__ out)
{
    __shared__ int sIdx[4][AGG_CAP];
    const int wave = threadIdx.x >> 6;
    const int lane = threadIdx.x & 63;
    const int q    = lane >> 4;
    const int l16  = lane & 15;
    const int f8   = l16 * 8;
    const int gw   = blockIdx.x * 4 + wave;
    const int d0   = gw * AGGH_DPW;
    const int d1   = min(d0 + AGGH_DPW, N_HOSTN);

    int rpv = 0, W0 = 0, Wn = 0;
    if (d0 < N_HOSTN) {
        rpv = (lane <= d1 - d0) ? rp[d0 + lane] : 0;
        W0 = __shfl(rpv, 0, 64);
        Wn = __shfl(rpv, d1 - d0, 64);
        const int cw = min(Wn - W0, AGG_CAP);
        for (int i = lane; i < cw; i += 64) sIdx[wave][i] = ei[W0 + i];
    }
    __syncthreads();
    if (d0 >= N_HOSTN) return;
    const int Wcap = W0 + min(Wn - W0, AGG_CAP);

    for (int i = 0; i < d1 - d0; ++i) {
        const int d  = d0 + i;
        const int b0 = __shfl(rpv, i, 64);
        const int b1 = __shfl(rpv, i + 1, 64);

        float a[8] = {0.f, 0.f, 0.f, 0.f, 0.f, 0.f, 0.f, 0.f};
        int e = b0 + q;
        while (e + 4 < b1) {
            const int s0 = (e     < Wcap) ? sIdx[wave][e     - W0] : ei[e];
            const int s1 = (e + 4 < Wcap) ? sIdx[wave][e + 4 - W0] : ei[e + 4];
            const uint4 z0 = *(const uint4*)(Z + (size_t)s0 * 128 + f8);
            const uint4 z1 = *(const uint4*)(Z + (size_t)s1 * 128 + f8);
            acc8(a, z0);
            acc8(a, z1);
            e += 8;
        }
        if (e < b1) {
            const int s0 = (e < Wcap) ? sIdx[wave][e - W0] : ei[e];
            const uint4 z0 = *(const uint4*)(Z + (size_t)s0 * 128 + f8);
            acc8(a, z0);
        }

        #pragma unroll
        for (int j = 0; j < 8; ++j) {
            a[j] += __shfl_xor(a[j], 16, 64);
            a[j] += __shfl_xor(a[j], 32, 64);
        }

        if (q == 0) {
            float4 oa, ob;
            oa.x = a[0]; oa.y = a[1]; oa.z = a[2]; oa.w = a[3];
            ob.x = a[4]; ob.y = a[5]; ob.z = a[6]; ob.w = a[7];
            *(float4*)(out + (size_t)d * 128 + f8)     = oa;
            *(float4*)(out + (size_t)d * 128 + f8 + 4) = ob;
        }
    }
}

// ---------------- pooling over sorted batch (bf16 input) ----------------
#define PCHUNK 128
__global__ __launch_bounds__(128) void k_pool2(const unsigned short* xf, const int* batch,
                                               unsigned* bits){
    const int t = threadIdx.x;
    const int i0 = blockIdx.x * PCHUNK;
    const int iend = min(i0 + PCHUNK, N_FLOWN);
    if (i0 >= N_FLOWN) return;
    float cur = -3.4e38f;
    int curg = batch[i0];
    for (int i = i0; i < iend; ++i) {
        int g = batch[i];
        if (g != curg) {
            unsigned u = __float_as_uint(cur);
            unsigned ord = (u & 0x80000000u) ? ~u : (u | 0x80000000u);
            atomicMax(&bits[(size_t)curg * 128 + t], ord);
            cur = -3.4e38f; curg = g;
        }
        cur = fmaxf(cur, bf2f(xf[(size_t)i * 128 + t]));
    }
    unsigned u = __float_as_uint(cur);
    unsigned ord = (u & 0x80000000u) ? ~u : (u | 0x80000000u);
    atomicMax(&bits[(size_t)curg * 128 + t], ord);
}

// ---------------- classifier ----------------
__global__ __launch_bounds__(128) void k_classifier(
    const unsigned* bits,
    const void* Wc1, const void* bc1, const void* Wc2, const void* bc2,
    const void* Wc3, const void* bc3, void* out, const int* flagp)
{
    const int g = blockIdx.x, t = threadIdx.x;
    const int isbf = *flagp;
    __shared__ float sp[128], sh1[64], sh2[128];
    {
        unsigned ord = bits[(size_t)g * HH + t];
        unsigned u = (ord & 0x80000000u) ? (ord & 0x7FFFFFFFu) : ~ord;
        sp[t] = __uint_as_float(u);
    }
    __syncthreads();
    if (t < 64) {
        float a = loadf(bc1, t, isbf);
        #pragma unroll 4
        for (int k = 0; k < 128; ++k) a = fmaf(sp[k], loadf(Wc1, k * 64 + t, isbf), a);
        sh1[t] = fmaxf(a, 0.f);
    }
    __syncthreads();
    {
        float a = loadf(bc2, t, isbf);
        #pragma unroll 4
        for (int k = 0; k < 64; ++k) a = fmaf(sh1[k], loadf(Wc2, k * 128 + t, isbf), a);
        sh2[t] = fmaxf(a, 0.f);
    }
    __syncthreads();
    if (t < NCN) {
        float a = loadf(bc3, t, isbf);
        #pragma unroll 4
        for (int k = 0; k < 128; ++k) a = fmaf(sh2[k], loadf(Wc3, k * NCN + t, isbf), a);
        if (isbf) ((unsigned short*)out)[(size_t)g * NCN + t] = f2bf(a);
        else      ((float*)out)[(size_t)g * NCN + t] = a;
    }
}

extern "C" void kernel_launch(void* const* d_in, const int* in_sizes, int n_in,
                              void* d_out, int out_size, void* d_ws, size_t ws_size,
                              hipStream_t stream)
{
    const int*  host_ids   = (const int*) d_in[0];
    const void* flow_x     = d_in[1];
    const int*  h2f_src    = (const int*) d_in[2];
    const int*  h2f_dst    = (const int*) d_in[3];
    const int*  f2h_src    = (const int*) d_in[4];
    const int*  f2h_dst    = (const int*) d_in[5];
    const int*  rel_src    = (const int*) d_in[6];
    const int*  rel_dst    = (const int*) d_in[7];
    const int*  flow_batch = (const int*) d_in[8];
    const void* host_embed = d_in[9];
    const void* Wr0_h2f = d_in[10]; const void* br0_h2f = d_in[11]; const void* Wo0_h2f = d_in[12];
    const void* Wr0_f2h = d_in[13]; const void* br0_f2h = d_in[14]; const void* Wo0_f2h = d_in[15];
    const void* Wr0_rel = d_in[16]; const void* br0_rel = d_in[17]; const void* Wo0_rel = d_in[18];
    const void* Wr_all  = d_in[19];
    const void* br_all  = d_in[20];
    const void* Wo_all  = d_in[21];
    const void* Wc1 = d_in[22]; const void* bc1 = d_in[23];
    const void* Wc2 = d_in[24]; const void* bc2 = d_in[25];
    const void* Wc3 = d_in[26]; const void* bc3 = d_in[27];

    // -------- workspace (~199 MB) --------
    size_t off = 0;
    auto alloc = [&](size_t bytes) -> char* {
        char* p = (char*)d_ws + off;
        off += (bytes + 255) & ~(size_t)255;
        return p;
    };
    unsigned short* F1bf  = (unsigned short*)alloc((size_t)N_FLOWN * HH * 2);  // state
    unsigned short* Froot = (unsigned short*)alloc((size_t)N_FLOWN * HH * 2);  // root term
    // ZALL: flow-transformed rows [0,200k) followed by host-transformed rows [200k,220k)
    unsigned short* ZALL  = (unsigned short*)alloc((size_t)(N_FLOWN + N_HOSTN) * HH * 2);
    unsigned short* F2bf  = ZALL;                                   // z_rel
    unsigned short* HCbf  = ZALL + (size_t)N_FLOWN * HH;            // z_h
    float* HA = (float*)alloc((size_t)N_HOSTN * HH * 4);
    float* HB = (float*)alloc((size_t)N_HOSTN * HH * 4);
    float* HD = (float*)alloc((size_t)N_HOSTN * HH * 4);
    unsigned short* WBT0 = (unsigned short*)alloc(256 * 128 * 2);
    unsigned short* WBT1 = (unsigned short*)alloc(256 * 128 * 2);
    unsigned short* WBT2 = (unsigned short*)alloc(256 * 128 * 2);
    float* w_h2f0  = (float*)alloc(128 * 128 * 4);
    float* w_h2f1  = (float*)alloc(128 * 128 * 4);
    float* w_h2f2  = (float*)alloc(128 * 128 * 4);
    float* w_f2h0  = (float*)alloc(128 * 128 * 4);
    float* w_f2h1  = (float*)alloc(128 * 128 * 4);
    float* w_of2h0 = (float*)alloc(128 * 128 * 4);
    float* w_of2h1 = (float*)alloc(128 * 128 * 4);
    float* b_comb0 = (float*)alloc(128 * 4);
    float* b_comb1 = (float*)alloc(128 * 4);
    float* b_comb2 = (float*)alloc(128 * 4);
    float* b_f2h0  = (float*)alloc(128 * 4);
    float* b_f2h1  = (float*)alloc(128 * 4);
    unsigned* poolbits = (unsigned*)alloc(GG * HH * 4);
    int* flagp = (int*)alloc(256);
    int* rp_cmb = (int*)alloc((N_FLOWN + 1) * 4);
    int* ei_cmb = (int*)alloc((size_t)E_CMBN * 4);
    int* rp_f2h = (int*)alloc((N_HOSTN + 1) * 4);
    int* ei_f2h = (int*)alloc((size_t)E_HFN * 4);
    int* wr_cmb = (int*)alloc((size_t)N_FLOWN * 4);
    int* wr_f2h = (int*)alloc((size_t)N_HOSTN * 4);
    int* bs0 = (int*)alloc(1024 * 4);
    int* bs2 = (int*)alloc(256 * 4);

    const int T = 256;
    #define GRID1(n) dim3(cdiv((long long)(n), T)), dim3(T), 0, stream

    if (off > ws_size) {
        k_flag_us<<<GRID1(out_size)>>>((unsigned short*)d_out, out_size, (unsigned short)0x4000);
        return;
    }

    k_detect<<<dim3(1), dim3(256), 0, stream>>>((const unsigned short*)flow_x, flagp);

    // -------- CSR builds (combined flow CSR + f2h CSR) --------
    k_zero2 <<<dim3(NB_CMB_N + NB_F2H_N), dim3(256), 0, stream>>>(wr_cmb, wr_f2h);
    k_hist3 <<<dim3(NB_REL_E + 2*NB_HF_E), dim3(256), 0, stream>>>(rel_dst, h2f_dst, f2h_dst,
                                                                    wr_cmb, wr_f2h);
    k_scan1_2<<<dim3(NB_CMB_N + NB_F2H_N), dim3(256), 0, stream>>>(
        wr_cmb, rp_cmb, bs0, wr_f2h, rp_f2h, bs2);
    k_scan2_2<<<dim3(2), dim3(256), 0, stream>>>(bs0, bs2);
    k_scan3_2<<<dim3(NB_CMB_N + NB_F2H_N), dim3(256), 0, stream>>>(
        rp_cmb, bs0, wr_cmb, rp_f2h, bs2, wr_f2h);
    k_place3c<<<dim3(PLC_ALL), dim3(256), 0, stream>>>(
        rel_src, rel_dst, h2f_src, h2f_dst, f2h_src, f2h_dst,
        wr_cmb, ei_cmb, wr_f2h, ei_f2h);

    // -------- weight prep (1 launch) --------
    k_wprep_all<<<dim3(833), dim3(256), 0, stream>>>(
        Wr0_h2f, br0_h2f, Wo0_h2f, Wr0_f2h, br0_f2h, Wo0_f2h, Wr0_rel, br0_rel, Wo0_rel,
        Wr_all, br_all, Wo_all,
        WBT0, WBT1, WBT2, w_h2f0, w_h2f1, w_h2f2,
        w_f2h0, w_f2h1, w_of2h0, w_of2h1,
        b_comb0, b_comb1, b_comb2, b_f2h0, b_f2h1, flagp);

    // ================= layer 0 =================
    k_gather_embed<<<GRID1(N_HOSTN * HH)>>>(host_ids, host_embed, HA, flagp);
    k_pad_cast<<<GRID1(N_FLOWN * 16)>>>(flow_x, F1bf, flagp);
    // host path: gather bf16 input features (K padded to 128); fused dual GEMM + relu
    k_agg_host<<<dim3(AGGH_BLK), dim3(256), 0, stream>>>(F1bf, rp_f2h, ei_f2h, HD);
    k_gemm2in<<<dim3(cdiv(N_HOSTN,16)), dim3(256), 0, stream>>>(HD, HA, w_f2h0, w_of2h0, b_f2h0, HB, N_HOSTN);
    // flow path
    k_gemm128<<<dim3(cdiv(N_HOSTN,16)), dim3(256), 0, stream>>>(HA, 0, w_h2f0, nullptr, HCbf, 1, N_HOSTN, 128, 0, 0, flagp);
    k_gemm_mfma<<<dim3(cdiv(N_FLOWN, 32*GEMM_CHUNKS)), dim3(256), 0, stream>>>(F1bf, WBT0, Froot, F2bf, N_FLOWN);
    k_agg_flow<<<dim3(AGGF_BLK), dim3(256), 0, stream>>>(ZALL, rp_cmb, ei_cmb,
                                                         Froot, b_comb0, F1bf, 1);

    // ================= stacked layer 0 =================
    k_agg_host<<<dim3(AGGH_BLK), dim3(256), 0, stream>>>(F1bf, rp_f2h, ei_f2h, HD);
    k_gemm128<<<dim3(cdiv(N_HOSTN,16)), dim3(256), 0, stream>>>(HB, 0, w_h2f1, nullptr, HCbf, 1, N_HOSTN, 128, 0, 0, flagp);
    k_gemm_mfma<<<dim3(cdiv(N_FLOWN, 32*GEMM_CHUNKS)), dim3(256), 0, stream>>>(F1bf, WBT1, Froot, F2bf, N_FLOWN);
    k_agg_flow<<<dim3(AGGF_BLK), dim3(256), 0, stream>>>(ZALL, rp_cmb, ei_cmb,
                                                         Froot, b_comb1, F1bf, 1);
    k_gemm2in<<<dim3(cdiv(N_HOSTN,16)), dim3(256), 0, stream>>>(HD, HB, w_f2h1, w_of2h1, b_f2h1, HA, N_HOSTN);

    // ================= stacked layer 1 (last; no host update, no relu) =================
    k_gemm128<<<dim3(cdiv(N_HOSTN,16)), dim3(256), 0, stream>>>(HA, 0, w_h2f2, nullptr, HCbf, 1, N_HOSTN, 128, 0, 0, flagp);
    k_gemm_mfma<<<dim3(cdiv(N_FLOWN, 32*GEMM_CHUNKS)), dim3(256), 0, stream>>>(F1bf, WBT2, Froot, F2bf, N_FLOWN);
    k_agg_flow<<<dim3(AGGF_BLK), dim3(256), 0, stream>>>(ZALL, rp_cmb, ei_cmb,
                                                         Froot, b_comb2, F1bf, 0);

    // ================= pool + classifier =================
    k_zero<<<GRID1(GG * HH)>>>((float*)poolbits, (size_t)GG * HH);
    k_pool2<<<dim3(cdiv(N_FLOWN, PCHUNK)), dim3(128), 0, stream>>>(F1bf, flow_batch, poolbits);
    k_classifier<<<dim3(GG), dim3(128), 0, stream>>>(poolbits, Wc1, bc1, Wc2, bc2, Wc3, bc3,
                                                     d_out, flagp);
    #undef GRID1
}

// Round 5
// 1026.949 us; speedup vs baseline: 1.1557x; 1.0304x over previous
//
#include <hip/hip_runtime.h>
#include <hip/hip_bf16.h>

using bf16 = __hip_bfloat16;

#define N_HOSTN 20000
#define N_FLOWN 200000
#define E_HFN   400000
#define E_RELN  800000
#define E_CMBN  1200000  // rel + h2f combined
#define GG      64
#define HH      128
#define FIN     97
#define NCN     10

// CSR region block counts (256 threads/block)
#define NB_REL_E 3125   // 800000/256
#define NB_HF_E  1563   // ceil(400000/256)
#define NB_CMB_N 782    // ceil(200000/256)
#define NB_F2H_N 79     // ceil(20000/256)
// class-partitioned placement: 2048-edge chunks x 8 classes
#define NCH_REL 391     // ceil(800000/2048)
#define NCH_HF  196     // ceil(400000/2048)
#define PLC_REL (NCH_REL*8)            // 3128
#define PLC_H2F (PLC_REL + NCH_HF*8)   // 4696
#define PLC_ALL (PLC_H2F + NCH_HF*8)   // 6264

// persistent-wave aggregation geometry (quarter-per-dst)
#define AGG_CAP    768   // staged indices per wave (fallback to global beyond)
#define AGGF_DPW   24    // dsts per wave (multiple of 4)
#define AGGF_BLK   2084  // 2084 blk * 4 waves * 24 = 200064 >= 200000
#define AGGH_DPW   12
#define AGGH_BLK   417   // 417 * 4 * 12 = 20016 >= 20000

static inline int cdiv(long long a, long long b){ return (int)((a + b - 1) / b); }

__device__ __forceinline__ float bf2f(unsigned short u){
    return __uint_as_float(((unsigned)u) << 16);
}
__device__ __forceinline__ unsigned short f2bf(float f){
    unsigned u = __float_as_uint(f);
    unsigned r = u + 0x7FFFu + ((u >> 16) & 1u);   // RNE
    return (unsigned short)(r >> 16);
}
__device__ __forceinline__ float loadf(const void* p, size_t i, int isbf){
    return isbf ? bf2f(((const unsigned short*)p)[i]) : ((const float*)p)[i];
}
// unpack 8 bf16 (uint4) and accumulate into 8 f32
__device__ __forceinline__ void acc8(float* a, uint4 z){
    a[0] += __uint_as_float(z.x << 16);
    a[1] += __uint_as_float(z.x & 0xFFFF0000u);
    a[2] += __uint_as_float(z.y << 16);
    a[3] += __uint_as_float(z.y & 0xFFFF0000u);
    a[4] += __uint_as_float(z.z << 16);
    a[5] += __uint_as_float(z.z & 0xFFFF0000u);
    a[6] += __uint_as_float(z.w << 16);
    a[7] += __uint_as_float(z.w & 0xFFFF0000u);
}

// ---------------- dtype detection ----------------
__global__ void k_detect(const unsigned short* x, int* flag){
    __shared__ int bad;
    if (threadIdx.x == 0) bad = 0;
    __syncthreads();
    int b = 0;
    for (int i = threadIdx.x; i < 4096; i += 256) {
        unsigned e = (x[i] >> 7) & 0xFFu;
        if (e >= 0x90u) b++;
    }
    if (b) atomicAdd(&bad, b);
    __syncthreads();
    if (threadIdx.x == 0) *flag = (bad == 0) ? 1 : 0;   // 1 = bf16, 0 = f32
}

// ---------------- misc ----------------
__global__ void k_zero(float* p, size_t n){
    size_t i = (size_t)blockIdx.x * 256 + threadIdx.x;
    if (i < n) p[i] = 0.f;
}
__global__ void k_flag_us(unsigned short* out, int n, unsigned short val){
    int i = blockIdx.x * 256 + threadIdx.x;
    if (i < n) out[i] = val;
}
__global__ void k_gather_embed(const int* ids, const void* emb, float* out, const int* flagp){
    int i = blockIdx.x * 256 + threadIdx.x;
    if (i >= N_HOSTN * HH) return;
    int isbf = *flagp;
    int node = i >> 7, f = i & 127;
    out[i] = loadf(emb, (size_t)ids[node] * HH + f, isbf);
}
// flow_x [N,97] (flag dtype) -> bf16 padded [N,128]; 8 output cols per thread
__global__ void k_pad_cast(const void* x, unsigned short* o, const int* flagp){
    int i = blockIdx.x * 256 + threadIdx.x;           // 0 .. N_FLOWN*16
    if (i >= N_FLOWN * 16) return;
    int isbf = *flagp;
    int row = i >> 4, c0 = (i & 15) * 8;
    unsigned short v[8];
    #pragma unroll
    for (int j = 0; j < 8; ++j) {
        int c = c0 + j;
        v[j] = (c < FIN) ? f2bf(loadf(x, (size_t)row * FIN + c, isbf)) : (unsigned short)0;
    }
    uint4 ov;
    ov.x = (unsigned)v[0] | ((unsigned)v[1] << 16);
    ov.y = (unsigned)v[2] | ((unsigned)v[3] << 16);
    ov.z = (unsigned)v[4] | ((unsigned)v[5] << 16);
    ov.w = (unsigned)v[6] | ((unsigned)v[7] << 16);
    *(uint4*)(o + (size_t)row * 128 + c0) = ov;
}

// ---------------- one-shot weight prep (833 blocks, region dispatch) ----------------
__global__ __launch_bounds__(256) void k_wprep_all(
    const void* Wr0_h2f, const void* br0_h2f, const void* Wo0_h2f,
    const void* Wr0_f2h, const void* br0_f2h, const void* Wo0_f2h,
    const void* Wr0_rel, const void* br0_rel, const void* Wo0_rel,
    const void* Wr_all, const void* br_all, const void* Wo_all,
    unsigned short* WBT0, unsigned short* WBT1, unsigned short* WBT2,
    float* w_h2f0, float* w_h2f1, float* w_h2f2,
    float* w_f2h0, float* w_f2h1, float* w_of2h0, float* w_of2h1,
    float* b_comb0, float* b_comb1, float* b_comb2, float* b_f2h0, float* b_f2h1,
    const int* flagp)
{
    const int bb = blockIdx.x, t = threadIdx.x;
    const int isbf = *flagp;
    if (bb < 384) {
        int layer = bb >> 7;
        int i = ((bb & 127) << 8) + t;   // 0..32767
        int nn = i >> 7, k = i & 127;
        float v = 0.f;
        if (layer == 0) {
            if (k < FIN) {
                if (nn < 128) v = loadf(Wo0_h2f, (size_t)k*128+nn, isbf) + loadf(Wo0_rel, (size_t)k*128+nn, isbf);
                else          v = loadf(Wr0_rel, (size_t)k*128+(nn-128), isbf);
            }
        } else {
            size_t oW = (size_t)((layer - 1) * 3) * 16384;
            if (nn < 128) v = loadf(Wo_all, oW + (size_t)k*128+nn, isbf)
                            + loadf(Wo_all, oW + 2*16384 + (size_t)k*128+nn, isbf);
            else          v = loadf(Wr_all, oW + 2*16384 + (size_t)k*128+(nn-128), isbf);
        }
        unsigned short* W = (layer == 0) ? WBT0 : ((layer == 1) ? WBT1 : WBT2);
        W[(size_t)nn*128 + k] = f2bf(v);
    } else if (bb < 576) {
        int r = bb - 384; int layer = r >> 6; int i = ((r & 63) << 8) + t;
        float v;
        if (layer == 0) v = loadf(Wr0_h2f, (size_t)i, isbf);
        else            v = loadf(Wr_all, (size_t)((layer-1)*3)*16384 + i, isbf);
        ((layer == 0) ? w_h2f0 : ((layer == 1) ? w_h2f1 : w_h2f2))[i] = v;
    } else if (bb < 640) {
        // w_f2h0 padded to [128][128]: rows k>=97 zero
        int i = ((bb - 576) << 8) + t;
        int k = i >> 7;
        w_f2h0[i] = (k < FIN) ? loadf(Wr0_f2h, (size_t)i, isbf) : 0.f;
    } else if (bb < 704) {
        int i = ((bb - 640) << 8) + t;
        w_f2h1[i] = loadf(Wr_all, (size_t)1*16384 + i, isbf);
    } else if (bb < 768) {
        int i = ((bb - 704) << 8) + t;
        w_of2h0[i] = loadf(Wo0_f2h, (size_t)i, isbf);
    } else if (bb < 832) {
        int i = ((bb - 768) << 8) + t;
        w_of2h1[i] = loadf(Wo_all, (size_t)1*16384 + i, isbf);
    } else {
        if (t < 128) {
            b_comb0[t] = loadf(br0_h2f, t, isbf) + loadf(br0_rel, t, isbf);
            b_comb1[t] = loadf(br_all, 0*128 + t, isbf) + loadf(br_all, 2*128 + t, isbf);
            b_comb2[t] = loadf(br_all, 3*128 + t, isbf) + loadf(br_all, 5*128 + t, isbf);
            b_f2h0[t]  = loadf(br0_f2h, t, isbf);
            b_f2h1[t]  = loadf(br_all, 1*128 + t, isbf);
        }
    }
}

// ---------------- CSR build (combined flow CSR + f2h CSR) ----------------
__global__ void k_zero2(int* c0, int* c1){
    int bb = blockIdx.x, t = threadIdx.x;
    if (bb < NB_CMB_N) { int i = bb * 256 + t; if (i < N_FLOWN) c0[i] = 0; }
    else               { int i = (bb - NB_CMB_N) * 256 + t; if (i < N_HOSTN) c1[i] = 0; }
}
// rel and h2f edges both count into c_cmb; f2h into c_f2h
__global__ void k_hist3(const int* drel, const int* dh2f, const int* df2h,
                        int* c_cmb, int* c_f2h){
    int bb = blockIdx.x, t = threadIdx.x;
    const int* dst; int* cnt; int E; int base;
    if (bb < NB_REL_E)                   { dst = drel; cnt = c_cmb; E = E_RELN; base = bb; }
    else if (bb < NB_REL_E + NB_HF_E)    { dst = dh2f; cnt = c_cmb; E = E_HFN;  base = bb - NB_REL_E; }
    else                                 { dst = df2h; cnt = c_f2h; E = E_HFN;  base = bb - NB_REL_E - NB_HF_E; }
    int e = base * 256 + t;
    if (e < E) atomicAdd(&cnt[dst[e]], 1);
}
__global__ __launch_bounds__(256) void k_scan1_2(
    const int* c0, int* rp0, int* bs0,
    const int* c1, int* rp1, int* bs1)
{
    __shared__ int s[256];
    int bb = blockIdx.x, t = threadIdx.x;
    const int* cnt; int* rp; int* bsum; int n; int base;
    if (bb < NB_CMB_N) { cnt = c0; rp = rp0; bsum = bs0; n = N_FLOWN; base = bb; }
    else               { cnt = c1; rp = rp1; bsum = bs1; n = N_HOSTN; base = bb - NB_CMB_N; }
    int i = base * 256 + t;
    int v = (i < n) ? cnt[i] : 0;
    s[t] = v; __syncthreads();
    for (int off = 1; off < 256; off <<= 1) {
        int x = (t >= off) ? s[t - off] : 0;
        __syncthreads();
        s[t] += x;
        __syncthreads();
    }
    if (i < n) rp[i] = s[t] - v;
    if (t == 255) bsum[base] = s[255];
}
__global__ __launch_bounds__(256) void k_scan2_2(int* bs0, int* bs1){
    __shared__ int s[256];
    __shared__ int carry;
    int t = threadIdx.x;
    int* bsum; int nb;
    if (blockIdx.x == 0) { bsum = bs0; nb = NB_CMB_N; }
    else                 { bsum = bs1; nb = NB_F2H_N; }
    if (t == 0) carry = 0;
    __syncthreads();
    for (int base = 0; base < nb; base += 256) {
        int i = base + t;
        int v = (i < nb) ? bsum[i] : 0;
        s[t] = v; __syncthreads();
        for (int off = 1; off < 256; off <<= 1) {
            int x = (t >= off) ? s[t - off] : 0;
            __syncthreads();
            s[t] += x;
            __syncthreads();
        }
        int excl = s[t] - v + carry;
        if (i < nb) bsum[i] = excl;
        __syncthreads();
        if (t == 255) carry += s[255];
        __syncthreads();
    }
}
__global__ void k_scan3_2(int* rp0, const int* bs0, int* w0,
                          int* rp1, const int* bs1, int* w1)
{
    int bb = blockIdx.x, t = threadIdx.x;
    int* rp; const int* bsum; int* wr; int n, E, base;
    if (bb < NB_CMB_N) { rp = rp0; bsum = bs0; wr = w0; n = N_FLOWN; E = E_CMBN; base = bb; }
    else               { rp = rp1; bsum = bs1; wr = w1; n = N_HOSTN; E = E_HFN;  base = bb - NB_CMB_N; }
    int i = base * 256 + t;
    if (i < n) { int v = rp[i] + bsum[base]; rp[i] = v; wr[i] = v; }
    if (i == 0) rp[n] = E;
}
// class-partitioned placement: class = blockIdx%8 (round-robins onto XCDs);
// rel + h2f both place into the combined flow CSR; h2f srcs get +N_FLOWN so
// the gather reads the host rows appended after the flow rows in ZALL.
__global__ __launch_bounds__(256) void k_place3c(
    const int* s0, const int* d0,
    const int* s1, const int* d1,
    const int* s2, const int* d2,
    int* w_cmb, int* e_cmb, int* w_f2h, int* e_f2h)
{
    const int bb = blockIdx.x;
    const int *src, *dst; int *wr, *ei; int E, divc, rb, soff;
    if (bb < PLC_REL)      { src=s0; dst=d0; wr=w_cmb; ei=e_cmb; E=E_RELN; divc=25000; rb=bb;          soff=0; }
    else if (bb < PLC_H2F) { src=s1; dst=d1; wr=w_cmb; ei=e_cmb; E=E_HFN;  divc=25000; rb=bb-PLC_REL;  soff=N_FLOWN; }
    else                   { src=s2; dst=d2; wr=w_f2h; ei=e_f2h; E=E_HFN;  divc=2500;  rb=bb-PLC_H2F;  soff=0; }
    const int cls  = rb & 7;
    const int base = (rb >> 3) * 2048;
    const int t = threadIdx.x;
    #pragma unroll
    for (int i = 0; i < 8; ++i) {
        const int e = base + t + i * 256;
        if (e < E) {
            const int d = dst[e];
            if (d / divc == cls) {
                const int pos = atomicAdd(&wr[d], 1);
                ei[pos] = src[e] + soff;
            }
        }
    }
}

// ---------------- host-sized VALU GEMM: Y[M,128] (+)= X[M,K]@W[K,128]+b ---------
__global__ __launch_bounds__(256) void k_gemm128(
    const void* X, int xmode, const float* W, const float* bias,
    void* Y, int ybf, int M, int K, int accum, int dorelu, const int* flagp)
{
    const int isbf = (xmode == 2) ? *flagp : xmode;
    const int tid  = threadIdx.x;
    const int row0 = blockIdx.x * 16;
    __shared__ float sX[16][130];
    const int total = 16 * K;
    for (int i = tid; i < total; i += 256) {
        int r = i / K, c = i - r * K;
        int gr = row0 + r;
        sX[r][c] = (gr < M) ? loadf(X, (size_t)gr * K + c, isbf) : 0.f;
    }
    __syncthreads();

    const int c4 = (tid & 31) * 4;
    const int rb = tid >> 5;
    float a0x=0,a0y=0,a0z=0,a0w=0, a1x=0,a1y=0,a1z=0,a1w=0;
    #pragma unroll 4
    for (int k = 0; k < K; ++k) {
        const float4 w = *(const float4*)(W + (size_t)k * 128 + c4);
        const float x0 = sX[rb][k];
        const float x1 = sX[rb + 8][k];
        a0x = fmaf(x0, w.x, a0x); a0y = fmaf(x0, w.y, a0y);
        a0z = fmaf(x0, w.z, a0z); a0w = fmaf(x0, w.w, a0w);
        a1x = fmaf(x1, w.x, a1x); a1y = fmaf(x1, w.y, a1y);
        a1z = fmaf(x1, w.z, a1z); a1w = fmaf(x1, w.w, a1w);
    }
    float bx=0, by=0, bz=0, bw=0;
    if (bias) { const float4 b = *(const float4*)(bias + c4); bx=b.x; by=b.y; bz=b.z; bw=b.w; }

    #pragma unroll
    for (int h = 0; h < 2; ++h) {
        const int rr = row0 + rb + (h ? 8 : 0);
        if (rr >= M) continue;
        float v0 = (h?a1x:a0x)+bx, v1 = (h?a1y:a0y)+by;
        float v2 = (h?a1z:a0z)+bz, v3 = (h?a1w:a0w)+bw;
        if (ybf) {
            unsigned short* p = (unsigned short*)Y + (size_t)rr * 128 + c4;
            ushort4 o; o.x=f2bf(v0); o.y=f2bf(v1); o.z=f2bf(v2); o.w=f2bf(v3);
            *(ushort4*)p = o;
        } else {
            float* p = (float*)Y + (size_t)rr * 128 + c4;
            if (accum) { v0+=p[0]; v1+=p[1]; v2+=p[2]; v3+=p[3]; }
            if (dorelu) { v0=fmaxf(v0,0.f); v1=fmaxf(v1,0.f); v2=fmaxf(v2,0.f); v3=fmaxf(v3,0.f); }
            float4 o; o.x=v0; o.y=v1; o.z=v2; o.w=v3;
            *(float4*)p = o;
        }
    }
}

// ---------------- fused dual-input host GEMM: Y = relu(X1@W1 + X2@W2 + b) ------
__global__ __launch_bounds__(256) void k_gemm2in(
    const float* __restrict__ X1, const float* __restrict__ X2,
    const float* __restrict__ W1, const float* __restrict__ W2,
    const float* __restrict__ bias, float* __restrict__ Y, int M)
{
    const int tid  = threadIdx.x;
    const int row0 = blockIdx.x * 16;
    __shared__ float sX1[16][130];
    __shared__ float sX2[16][130];
    for (int i = tid; i < 16 * 128; i += 256) {
        int r = i >> 7, c = i & 127;
        int gr = row0 + r;
        sX1[r][c] = (gr < M) ? X1[(size_t)gr * 128 + c] : 0.f;
        sX2[r][c] = (gr < M) ? X2[(size_t)gr * 128 + c] : 0.f;
    }
    __syncthreads();

    const int c4 = (tid & 31) * 4;
    const int rb = tid >> 5;
    float a0x=0,a0y=0,a0z=0,a0w=0, a1x=0,a1y=0,a1z=0,a1w=0;
    #pragma unroll 4
    for (int k = 0; k < 128; ++k) {
        const float4 w = *(const float4*)(W1 + (size_t)k * 128 + c4);
        const float x0 = sX1[rb][k];
        const float x1 = sX1[rb + 8][k];
        a0x = fmaf(x0, w.x, a0x); a0y = fmaf(x0, w.y, a0y);
        a0z = fmaf(x0, w.z, a0z); a0w = fmaf(x0, w.w, a0w);
        a1x = fmaf(x1, w.x, a1x); a1y = fmaf(x1, w.y, a1y);
        a1z = fmaf(x1, w.z, a1z); a1w = fmaf(x1, w.w, a1w);
    }
    #pragma unroll 4
    for (int k = 0; k < 128; ++k) {
        const float4 w = *(const float4*)(W2 + (size_t)k * 128 + c4);
        const float x0 = sX2[rb][k];
        const float x1 = sX2[rb + 8][k];
        a0x = fmaf(x0, w.x, a0x); a0y = fmaf(x0, w.y, a0y);
        a0z = fmaf(x0, w.z, a0z); a0w = fmaf(x0, w.w, a0w);
        a1x = fmaf(x1, w.x, a1x); a1y = fmaf(x1, w.y, a1y);
        a1z = fmaf(x1, w.z, a1z); a1w = fmaf(x1, w.w, a1w);
    }
    const float4 b = *(const float4*)(bias + c4);
    #pragma unroll
    for (int h = 0; h < 2; ++h) {
        const int rr = row0 + rb + (h ? 8 : 0);
        if (rr >= M) continue;
        float4 o;
        o.x = fmaxf((h?a1x:a0x) + b.x, 0.f);
        o.y = fmaxf((h?a1y:a0y) + b.y, 0.f);
        o.z = fmaxf((h?a1z:a0z) + b.z, 0.f);
        o.w = fmaxf((h?a1w:a0w) + b.w, 0.f);
        *(float4*)(Y + (size_t)rr * 128 + c4) = o;
    }
}

// ---------------- MFMA dual flow GEMM: both outputs bf16, no bias ----------------
// B (WBT, 256x128 = 64KB) kept ENTIRELY in registers per wave (16 bfrags for the
// wave's 64-col slice), loaded once. 8 row-chunks of 32 per block, A direct from
// global, no LDS/barriers. Operands swapped (mfma(b,a) == D^T) -> ushort4 stores.
typedef __attribute__((ext_vector_type(8))) short bfrag;
typedef __attribute__((ext_vector_type(4))) float f32x4;

#define GEMM_CHUNKS 8

__global__ __launch_bounds__(256) void k_gemm_mfma(
    const unsigned short* __restrict__ Abf, const unsigned short* __restrict__ WBT,
    unsigned short* __restrict__ Y1, unsigned short* __restrict__ Y2, int M)
{
    const int tid  = threadIdx.x;
    const int wave = tid >> 6;
    const int lane = tid & 63;
    const int quad = lane >> 4;
    const int l16  = lane & 15;
    const int nbase = wave * 64;

    // B slice for this wave's 64 output cols: breg[c][j], all compile-time indexed
    bfrag breg[4][4];
    #pragma unroll
    for (int c = 0; c < 4; ++c)
        #pragma unroll
        for (int j = 0; j < 4; ++j)
            breg[c][j] = *(const bfrag*)(WBT + (size_t)(nbase + j * 16 + l16) * 128
                                              + c * 32 + quad * 8);

    unsigned short* __restrict__ Yd = (nbase < 128) ? Y1 : Y2;
    const int colb = nbase & 127;
    const f32x4 zero = {0.f, 0.f, 0.f, 0.f};

    #pragma unroll
    for (int chunk = 0; chunk < GEMM_CHUNKS; ++chunk) {
        const int m0 = blockIdx.x * (32 * GEMM_CHUNKS) + chunk * 32;
        if (m0 < M) {
            // A fragments direct from global (16 rows x 64B per load instruction)
            bfrag a0[4], a1[4];
            #pragma unroll
            for (int c = 0; c < 4; ++c) {
                a0[c] = *(const bfrag*)(Abf + (size_t)(m0      + l16) * 128 + c * 32 + quad * 8);
                a1[c] = *(const bfrag*)(Abf + (size_t)(m0 + 16 + l16) * 128 + c * 32 + quad * 8);
            }
            f32x4 acc[2][4];
            #pragma unroll
            for (int j = 0; j < 4; ++j) {
                acc[0][j] = __builtin_amdgcn_mfma_f32_16x16x32_bf16(breg[0][j], a0[0], zero, 0, 0, 0);
                acc[1][j] = __builtin_amdgcn_mfma_f32_16x16x32_bf16(breg[0][j], a1[0], zero, 0, 0, 0);
            }
            #pragma unroll
            for (int c = 1; c < 4; ++c)
                #pragma unroll
                for (int j = 0; j < 4; ++j) {
                    acc[0][j] = __builtin_amdgcn_mfma_f32_16x16x32_bf16(breg[c][j], a0[c], acc[0][j], 0, 0, 0);
                    acc[1][j] = __builtin_amdgcn_mfma_f32_16x16x32_bf16(breg[c][j], a1[c], acc[1][j], 0, 0, 0);
                }
            // D' layout: col(lane&15) = X-row m (within 16-block i), row(quad*4+r) = WBT-row n
            #pragma unroll
            for (int i = 0; i < 2; ++i) {
                const int row = m0 + i * 16 + l16;
                #pragma unroll
                for (int j = 0; j < 4; ++j) {
                    const int col = colb + j * 16 + quad * 4;
                    ushort4 o;
                    o.x = f2bf(acc[i][j][0]); o.y = f2bf(acc[i][j][1]);
                    o.z = f2bf(acc[i][j][2]); o.w = f2bf(acc[i][j][3]);
                    *(ushort4*)(Yd + (size_t)row * 128 + col) = o;
                }
            }
        }
    }
}

// ---------------- persistent-wave combined CSR aggregation (flow dsts) ----------
// QUARTER-PER-DST: each 16-lane quarter owns one dst entirely (16 lanes x 8
// features = 128). Per outer iteration the wave processes 4 CONSECUTIVE dsts in
// parallel: no cross-quarter reduce (shfl_xor eliminated), epilogue amortized 4x,
// root loads / stores are 4 consecutive rows = 1 KiB contiguous per instruction.
// Edge-index window staged to LDS once per wave (contiguous CSR range).
__global__ __launch_bounds__(256) void k_agg_flow(
    const unsigned short* __restrict__ Z,
    const int* __restrict__ rp, const int* __restrict__ ei,
    const unsigned short* __restrict__ root, const float* __restrict__ bias,
    unsigned short* __restrict__ Xout, int do_relu)
{
    __shared__ int sIdx[4][AGG_CAP];
    const int wave = threadIdx.x >> 6;
    const int lane = threadIdx.x & 63;
    const int q    = lane >> 4;
    const int l16  = lane & 15;
    const int f8   = l16 * 8;
    const int gw   = blockIdx.x * 4 + wave;
    const int d0   = gw * AGGF_DPW;
    const int nd   = min(AGGF_DPW, N_FLOWN - d0);   // may be <= 0 for tail waves

    int rpv = 0, W0 = 0, Wcap = 0;
    if (nd > 0) {
        rpv = (lane <= nd) ? rp[d0 + lane] : 0;
        W0 = __shfl(rpv, 0, 64);
        const int Wn = __shfl(rpv, nd, 64);
        const int cw = min(Wn - W0, AGG_CAP);
        for (int i = lane; i < cw; i += 64) sIdx[wave][i] = ei[W0 + i];
        Wcap = W0 + cw;
    }
    __syncthreads();
    if (nd <= 0) return;

    // loop-invariant bias slice
    const float4 bva = *(const float4*)(bias + f8);
    const float4 bvb = *(const float4*)(bias + f8 + 4);

    #pragma unroll 2
    for (int i = 0; i < AGGF_DPW / 4; ++i) {
        const int dqi = i * 4 + q;              // this quarter's dst offset
        const bool act = dqi < nd;
        const int srcl = act ? dqi : 0;
        const int b0 = __shfl(rpv, srcl, 64);
        const int b1 = __shfl(rpv, srcl + 1, 64);
        const int d  = d0 + dqi;

        uint4 rv = {0, 0, 0, 0};
        if (act) rv = *(const uint4*)(root + (size_t)d * 128 + f8);

        float a[8] = {0.f, 0.f, 0.f, 0.f, 0.f, 0.f, 0.f, 0.f};
        int n = act ? (b1 - b0) : 0;
        int e = b0;
        while (n >= 4) {
            const int s0 = (e     < Wcap) ? sIdx[wave][e     - W0] : ei[e];
            const int s1 = (e + 1 < Wcap) ? sIdx[wave][e + 1 - W0] : ei[e + 1];
            const int s2 = (e + 2 < Wcap) ? sIdx[wave][e + 2 - W0] : ei[e + 2];
            const int s3 = (e + 3 < Wcap) ? sIdx[wave][e + 3 - W0] : ei[e + 3];
            const uint4 z0 = *(const uint4*)(Z + (size_t)s0 * 128 + f8);
            const uint4 z1 = *(const uint4*)(Z + (size_t)s1 * 128 + f8);
            const uint4 z2 = *(const uint4*)(Z + (size_t)s2 * 128 + f8);
            const uint4 z3 = *(const uint4*)(Z + (size_t)s3 * 128 + f8);
            acc8(a, z0); acc8(a, z1); acc8(a, z2); acc8(a, z3);
            e += 4; n -= 4;
        }
        if (n & 2) {
            const int s0 = (e     < Wcap) ? sIdx[wave][e     - W0] : ei[e];
            const int s1 = (e + 1 < Wcap) ? sIdx[wave][e + 1 - W0] : ei[e + 1];
            const uint4 z0 = *(const uint4*)(Z + (size_t)s0 * 128 + f8);
            const uint4 z1 = *(const uint4*)(Z + (size_t)s1 * 128 + f8);
            acc8(a, z0); acc8(a, z1);
            e += 2;
        }
        if (n & 1) {
            const int s0 = (e < Wcap) ? sIdx[wave][e - W0] : ei[e];
            const uint4 z0 = *(const uint4*)(Z + (size_t)s0 * 128 + f8);
            acc8(a, z0);
        }

        if (act) {
            float v0 = a[0] + __uint_as_float(rv.x << 16)         + bva.x;
            float v1 = a[1] + __uint_as_float(rv.x & 0xFFFF0000u) + bva.y;
            float v2 = a[2] + __uint_as_float(rv.y << 16)         + bva.z;
            float v3 = a[3] + __uint_as_float(rv.y & 0xFFFF0000u) + bva.w;
            float v4 = a[4] + __uint_as_float(rv.z << 16)         + bvb.x;
            float v5 = a[5] + __uint_as_float(rv.z & 0xFFFF0000u) + bvb.y;
            float v6 = a[6] + __uint_as_float(rv.w << 16)         + bvb.z;
            float v7 = a[7] + __uint_as_float(rv.w & 0xFFFF0000u) + bvb.w;
            if (do_relu) {
                v0 = fmaxf(v0, 0.f); v1 = fmaxf(v1, 0.f); v2 = fmaxf(v2, 0.f); v3 = fmaxf(v3, 0.f);
                v4 = fmaxf(v4, 0.f); v5 = fmaxf(v5, 0.f); v6 = fmaxf(v6, 0.f); v7 = fmaxf(v7, 0.f);
            }
            uint4 o;
            o.x = (unsigned)f2bf(v0) | ((unsigned)f2bf(v1) << 16);
            o.y = (unsigned)f2bf(v2) | ((unsigned)f2bf(v3) << 16);
            o.z = (unsigned)f2bf(v4) | ((unsigned)f2bf(v5) << 16);
            o.w = (unsigned)f2bf(v6) | ((unsigned)f2bf(v7) << 16);
            *(uint4*)(Xout + (size_t)d * 128 + f8) = o;
        }
    }
}

// host dst: out[d][0:128] = sum f2h Z[src][0:128]  (f32 out)
// Same quarter-per-dst persistent structure.
__global__ __launch_bounds__(256) void k_agg_host(
    const unsigned short* __restrict__ Z, const int* __restrict__ rp,
    const int* __restrict__ ei, float* __restrict__ out)
{
    __shared__ int sIdx[4][AGG_CAP];
    const int wave = threadIdx.x >> 6;
    const int lane = threadIdx.x & 63;
    const int q    = lane >> 4;
    const int l16  = lane & 15;
    const int f8   = l16 * 8;
    const int gw   = blockIdx.x * 4 + wave;
    const int d0   = gw * AGGH_DPW;
    const int nd   = min(AGGH_DPW, N_HOSTN - d0);

    int rpv = 0, W0 = 0, Wcap = 0;
    if (nd > 0) {
        rpv = (lane <= nd) ? rp[d0 + lane] : 0;
        W0 = __shfl(rpv, 0, 64);
        const int Wn = __shfl(rpv, nd, 64);
        const int cw = min(Wn - W0, AGG_CAP);
        for (int i = lane; i < cw; i += 64) sIdx[wave][i] = ei[W0 + i];
        Wcap = W0 + cw;
    }
    __syncthreads();
    if (nd <= 0) return;

    #pragma unroll
    for (int i = 0; i < AGGH_DPW / 4; ++i) {
        const int dqi = i * 4 + q;
        const bool act = dqi < nd;
        const int srcl = act ? dqi : 0;
        const int b0 = __shfl(rpv, srcl, 64);
        const int b1 = __shfl(rpv, srcl + 1, 64);
        const int d  = d0 + dqi;

        float a[8] = {0.f, 0.f, 0.f, 0.f, 0.f, 0.f, 0.f, 0.f};
        int n = act ? (b1 - b0) : 0;
        int e = b0;
        while (n >= 4) {
            const int s0 = (e     < Wcap) ? sIdx[wave][e     - W0] : ei[e];
            const int s1 = (e + 1 < Wcap) ? sIdx[wave][e + 1 - W0] : ei[e + 1];
            const int s2 = (e + 2 < Wcap) ? sIdx[wave][e + 2 - W0] : ei[e + 2];
            const int s3 = (e + 3 < Wcap) ? sIdx[wave][e + 3 - W0] : ei[e + 3];
            const uint4 z0 = *(const uint4*)(Z + (size_t)s0 * 128 + f8);
            const uint4 z1 = *(const uint4*)(Z + (size_t)s1 * 128 + f8);
            const uint4 z2 = *(const uint4*)(Z + (size_t)s2 * 128 + f8);
            const uint4 z3 = *(const uint4*)(Z + (size_t)s3 * 128 + f8);
            acc8(a, z0); acc8(a, z1); acc8(a, z2); acc8(a, z3);
            e += 4; n -= 4;
        }
        if (n & 2) {
            const int s0 = (e     < Wcap) ? sIdx[wave][e     - W0] : ei[e];
            const int s1 = (e + 1 < Wcap) ? sIdx[wave][e + 1 - W0] : ei[e + 1];
            const uint4 z0 = *(const uint4*)(Z + (size_t)s0 * 128 + f8);
            const uint4 z1 = *(const uint4*)(Z + (size_t)s1 * 128 + f8);
            acc8(a, z0); acc8(a, z1);
            e += 2;
        }
        if (n & 1) {
            const int s0 = (e < Wcap) ? sIdx[wave][e - W0] : ei[e];
            const uint4 z0 = *(const uint4*)(Z + (size_t)s0 * 128 + f8);
            acc8(a, z0);
        }

        if (act) {
            float4 oa, ob;
            oa.x = a[0]; oa.y = a[1]; oa.z = a[2]; oa.w = a[3];
            ob.x = a[4]; ob.y = a[5]; ob.z = a[6]; ob.w = a[7];
            *(float4*)(out + (size_t)d * 128 + f8)     = oa;
            *(float4*)(out + (size_t)d * 128 + f8 + 4) = ob;
        }
    }
}

// ---------------- pooling over sorted batch (bf16 input) ----------------
#define PCHUNK 128
__global__ __launch_bounds__(128) void k_pool2(const unsigned short* xf, const int* batch,
                                               unsigned* bits){
    const int t = threadIdx.x;
    const int i0 = blockIdx.x * PCHUNK;
    const int iend = min(i0 + PCHUNK, N_FLOWN);
    if (i0 >= N_FLOWN) return;
    float cur = -3.4e38f;
    int curg = batch[i0];
    for (int i = i0; i < iend; ++i) {
        int g = batch[i];
        if (g != curg) {
            unsigned u = __float_as_uint(cur);
            unsigned ord = (u & 0x80000000u) ? ~u : (u | 0x80000000u);
            atomicMax(&bits[(size_t)curg * 128 + t], ord);
            cur = -3.4e38f; curg = g;
        }
        cur = fmaxf(cur, bf2f(xf[(size_t)i * 128 + t]));
    }
    unsigned u = __float_as_uint(cur);
    unsigned ord = (u & 0x80000000u) ? ~u : (u | 0x80000000u);
    atomicMax(&bits[(size_t)curg * 128 + t], ord);
}

// ---------------- classifier ----------------
__global__ __launch_bounds__(128) void k_classifier(
    const unsigned* bits,
    const void* Wc1, const void* bc1, const void* Wc2, const void* bc2,
    const void* Wc3, const void* bc3, void* out, const int* flagp)
{
    const int g = blockIdx.x, t = threadIdx.x;
    const int isbf = *flagp;
    __shared__ float sp[128], sh1[64], sh2[128];
    {
        unsigned ord = bits[(size_t)g * HH + t];
        unsigned u = (ord & 0x80000000u) ? (ord & 0x7FFFFFFFu) : ~ord;
        sp[t] = __uint_as_float(u);
    }
    __syncthreads();
    if (t < 64) {
        float a = loadf(bc1, t, isbf);
        #pragma unroll 4
        for (int k = 0; k < 128; ++k) a = fmaf(sp[k], loadf(Wc1, k * 64 + t, isbf), a);
        sh1[t] = fmaxf(a, 0.f);
    }
    __syncthreads();
    {
        float a = loadf(bc2, t, isbf);
        #pragma unroll 4
        for (int k = 0; k < 64; ++k) a = fmaf(sh1[k], loadf(Wc2, k * 128 + t, isbf), a);
        sh2[t] = fmaxf(a, 0.f);
    }
    __syncthreads();
    if (t < NCN) {
        float a = loadf(bc3, t, isbf);
        #pragma unroll 4
        for (int k = 0; k < 128; ++k) a = fmaf(sh2[k], loadf(Wc3, k * NCN + t, isbf), a);
        if (isbf) ((unsigned short*)out)[(size_t)g * NCN + t] = f2bf(a);
        else      ((float*)out)[(size_t)g * NCN + t] = a;
    }
}

extern "C" void kernel_launch(void* const* d_in, const int* in_sizes, int n_in,
                              void* d_out, int out_size, void* d_ws, size_t ws_size,
                              hipStream_t stream)
{
    const int*  host_ids   = (const int*) d_in[0];
    const void* flow_x     = d_in[1];
    const int*  h2f_src    = (const int*) d_in[2];
    const int*  h2f_dst    = (const int*) d_in[3];
    const int*  f2h_src    = (const int*) d_in[4];
    const int*  f2h_dst    = (const int*) d_in[5];
    const int*  rel_src    = (const int*) d_in[6];
    const int*  rel_dst    = (const int*) d_in[7];
    const int*  flow_batch = (const int*) d_in[8];
    const void* host_embed = d_in[9];
    const void* Wr0_h2f = d_in[10]; const void* br0_h2f = d_in[11]; const void* Wo0_h2f = d_in[12];
    const void* Wr0_f2h = d_in[13]; const void* br0_f2h = d_in[14]; const void* Wo0_f2h = d_in[15];
    const void* Wr0_rel = d_in[16]; const void* br0_rel = d_in[17]; const void* Wo0_rel = d_in[18];
    const void* Wr_all  = d_in[19];
    const void* br_all  = d_in[20];
    const void* Wo_all  = d_in[21];
    const void* Wc1 = d_in[22]; const void* bc1 = d_in[23];
    const void* Wc2 = d_in[24]; const void* bc2 = d_in[25];
    const void* Wc3 = d_in[26]; const void* bc3 = d_in[27];

    // -------- workspace (~199 MB) --------
    size_t off = 0;
    auto alloc = [&](size_t bytes) -> char* {
        char* p = (char*)d_ws + off;
        off += (bytes + 255) & ~(size_t)255;
        return p;
    };
    unsigned short* F1bf  = (unsigned short*)alloc((size_t)N_FLOWN * HH * 2);  // state
    unsigned short* Froot = (unsigned short*)alloc((size_t)N_FLOWN * HH * 2);  // root term
    // ZALL: flow-transformed rows [0,200k) followed by host-transformed rows [200k,220k)
    unsigned short* ZALL  = (unsigned short*)alloc((size_t)(N_FLOWN + N_HOSTN) * HH * 2);
    unsigned short* F2bf  = ZALL;                                   // z_rel
    unsigned short* HCbf  = ZALL + (size_t)N_FLOWN * HH;            // z_h
    float* HA = (float*)alloc((size_t)N_HOSTN * HH * 4);
    float* HB = (float*)alloc((size_t)N_HOSTN * HH * 4);
    float* HD = (float*)alloc((size_t)N_HOSTN * HH * 4);
    unsigned short* WBT0 = (unsigned short*)alloc(256 * 128 * 2);
    unsigned short* WBT1 = (unsigned short*)alloc(256 * 128 * 2);
    unsigned short* WBT2 = (unsigned short*)alloc(256 * 128 * 2);
    float* w_h2f0  = (float*)alloc(128 * 128 * 4);
    float* w_h2f1  = (float*)alloc(128 * 128 * 4);
    float* w_h2f2  = (float*)alloc(128 * 128 * 4);
    float* w_f2h0  = (float*)alloc(128 * 128 * 4);
    float* w_f2h1  = (float*)alloc(128 * 128 * 4);
    float* w_of2h0 = (float*)alloc(128 * 128 * 4);
    float* w_of2h1 = (float*)alloc(128 * 128 * 4);
    float* b_comb0 = (float*)alloc(128 * 4);
    float* b_comb1 = (float*)alloc(128 * 4);
    float* b_comb2 = (float*)alloc(128 * 4);
    float* b_f2h0  = (float*)alloc(128 * 4);
    float* b_f2h1  = (float*)alloc(128 * 4);
    unsigned* poolbits = (unsigned*)alloc(GG * HH * 4);
    int* flagp = (int*)alloc(256);
    int* rp_cmb = (int*)alloc((N_FLOWN + 1) * 4);
    int* ei_cmb = (int*)alloc((size_t)E_CMBN * 4);
    int* rp_f2h = (int*)alloc((N_HOSTN + 1) * 4);
    int* ei_f2h = (int*)alloc((size_t)E_HFN * 4);
    int* wr_cmb = (int*)alloc((size_t)N_FLOWN * 4);
    int* wr_f2h = (int*)alloc((size_t)N_HOSTN * 4);
    int* bs0 = (int*)alloc(1024 * 4);
    int* bs2 = (int*)alloc(256 * 4);

    const int T = 256;
    #define GRID1(n) dim3(cdiv((long long)(n), T)), dim3(T), 0, stream

    if (off > ws_size) {
        k_flag_us<<<GRID1(out_size)>>>((unsigned short*)d_out, out_size, (unsigned short)0x4000);
        return;
    }

    k_detect<<<dim3(1), dim3(256), 0, stream>>>((const unsigned short*)flow_x, flagp);

    // -------- CSR builds (combined flow CSR + f2h CSR) --------
    k_zero2 <<<dim3(NB_CMB_N + NB_F2H_N), dim3(256), 0, stream>>>(wr_cmb, wr_f2h);
    k_hist3 <<<dim3(NB_REL_E + 2*NB_HF_E), dim3(256), 0, stream>>>(rel_dst, h2f_dst, f2h_dst,
                                                                    wr_cmb, wr_f2h);
    k_scan1_2<<<dim3(NB_CMB_N + NB_F2H_N), dim3(256), 0, stream>>>(
        wr_cmb, rp_cmb, bs0, wr_f2h, rp_f2h, bs2);
    k_scan2_2<<<dim3(2), dim3(256), 0, stream>>>(bs0, bs2);
    k_scan3_2<<<dim3(NB_CMB_N + NB_F2H_N), dim3(256), 0, stream>>>(
        rp_cmb, bs0, wr_cmb, rp_f2h, bs2, wr_f2h);
    k_place3c<<<dim3(PLC_ALL), dim3(256), 0, stream>>>(
        rel_src, rel_dst, h2f_src, h2f_dst, f2h_src, f2h_dst,
        wr_cmb, ei_cmb, wr_f2h, ei_f2h);

    // -------- weight prep (1 launch) --------
    k_wprep_all<<<dim3(833), dim3(256), 0, stream>>>(
        Wr0_h2f, br0_h2f, Wo0_h2f, Wr0_f2h, br0_f2h, Wo0_f2h, Wr0_rel, br0_rel, Wo0_rel,
        Wr_all, br_all, Wo_all,
        WBT0, WBT1, WBT2, w_h2f0, w_h2f1, w_h2f2,
        w_f2h0, w_f2h1, w_of2h0, w_of2h1,
        b_comb0, b_comb1, b_comb2, b_f2h0, b_f2h1, flagp);

    // ================= layer 0 =================
    k_gather_embed<<<GRID1(N_HOSTN * HH)>>>(host_ids, host_embed, HA, flagp);
    k_pad_cast<<<GRID1(N_FLOWN * 16)>>>(flow_x, F1bf, flagp);
    // host path: gather bf16 input features (K padded to 128); fused dual GEMM + relu
    k_agg_host<<<dim3(AGGH_BLK), dim3(256), 0, stream>>>(F1bf, rp_f2h, ei_f2h, HD);
    k_gemm2in<<<dim3(cdiv(N_HOSTN,16)), dim3(256), 0, stream>>>(HD, HA, w_f2h0, w_of2h0, b_f2h0, HB, N_HOSTN);
    // flow path
    k_gemm128<<<dim3(cdiv(N_HOSTN,16)), dim3(256), 0, stream>>>(HA, 0, w_h2f0, nullptr, HCbf, 1, N_HOSTN, 128, 0, 0, flagp);
    k_gemm_mfma<<<dim3(cdiv(N_FLOWN, 32*GEMM_CHUNKS)), dim3(256), 0, stream>>>(F1bf, WBT0, Froot, F2bf, N_FLOWN);
    k_agg_flow<<<dim3(AGGF_BLK), dim3(256), 0, stream>>>(ZALL, rp_cmb, ei_cmb,
                                                         Froot, b_comb0, F1bf, 1);

    // ================= stacked layer 0 =================
    k_agg_host<<<dim3(AGGH_BLK), dim3(256), 0, stream>>>(F1bf, rp_f2h, ei_f2h, HD);
    k_gemm128<<<dim3(cdiv(N_HOSTN,16)), dim3(256), 0, stream>>>(HB, 0, w_h2f1, nullptr, HCbf, 1, N_HOSTN, 128, 0, 0, flagp);
    k_gemm_mfma<<<dim3(cdiv(N_FLOWN, 32*GEMM_CHUNKS)), dim3(256), 0, stream>>>(F1bf, WBT1, Froot, F2bf, N_FLOWN);
    k_agg_flow<<<dim3(AGGF_BLK), dim3(256), 0, stream>>>(ZALL, rp_cmb, ei_cmb,
                                                         Froot, b_comb1, F1bf, 1);
    k_gemm2in<<<dim3(cdiv(N_HOSTN,16)), dim3(256), 0, stream>>>(HD, HB, w_f2h1, w_of2h1, b_f2h1, HA, N_HOSTN);

    // ================= stacked layer 1 (last; no host update, no relu) =================
    k_gemm128<<<dim3(cdiv(N_HOSTN,16)), dim3(256), 0, stream>>>(HA, 0, w_h2f2, nullptr, HCbf, 1, N_HOSTN, 128, 0, 0, flagp);
    k_gemm_mfma<<<dim3(cdiv(N_FLOWN, 32*GEMM_CHUNKS)), dim3(256), 0, stream>>>(F1bf, WBT2, Froot, F2bf, N_FLOWN);
    k_agg_flow<<<dim3(AGGF_BLK), dim3(256), 0, stream>>>(ZALL, rp_cmb, ei_cmb,
                                                         Froot, b_comb2, F1bf, 0);

    // ================= pool + classifier =================
    k_zero<<<GRID1(GG * HH)>>>((float*)poolbits, (size_t)GG * HH);
    k_pool2<<<dim3(cdiv(N_FLOWN, PCHUNK)), dim3(128), 0, stream>>>(F1bf, flow_batch, poolbits);
    k_classifier<<<dim3(GG), dim3(128), 0, stream>>>(poolbits, Wc1, bc1, Wc2, bc2, Wc3, bc3,
                                                     d_out, flagp);
    #undef GRID1
}